// Round 7
// baseline (1006.410 us; speedup 1.0000x reference)
//
#include <hip/hip_runtime.h>
#include <hip/hip_bf16.h>

// ---------------- problem constants ----------------
#define NN 20000      // nodes
#define EE 640000     // edges
#define RR 65         // relations
#define FIN1 128      // input feat
#define HH1 64        // hidden1
#define HH2 32        // hidden2
#define BB 8192       // pairs

constexpr int BM = 128;                 // edge-tile rows per GEMM block
constexpr int MAXT = EE / BM + RR;      // 5065 upper bound on tiles per sort
constexpr int NBH = 256;                // histogram/placement blocks
constexpr int EPB = EE / NBH;           // 2500 edges per block
constexpr int NBT = (NN + BM - 1) / BM; // 157 node tiles

// classifier GEMM geometry (E[8192x448] @ clsW[448x65], padded)
constexpr int CLS_K  = 512;
constexpr int CLS_N  = 80;
constexpr int CLS_CK = 128;
constexpr int CLS_BM = 64;

typedef __attribute__((ext_vector_type(8))) short short8;   // 8 bf16 MFMA frag
typedef __attribute__((ext_vector_type(4))) float floatx4;  // 4 fp32 acc

// ---------------- workspace layout (bytes) ----------------
constexpr size_t aln(size_t x) { return (x + 255) & ~(size_t)255; }

constexpr size_t OFF_CSUM  = 0;                        // 32 f
constexpr size_t OFF_CNTS  = aln(OFF_CSUM + 32 * 4);  // NN int (src degree)
constexpr size_t OFF_CNTD  = OFF_CNTS + (size_t)NN * 4;
constexpr size_t OFF_CURS  = OFF_CNTD + (size_t)NN * 4;
constexpr size_t OFF_CURD  = OFF_CURS + (size_t)NN * 4;
constexpr size_t ZERO_BYTES = OFF_CURD + (size_t)NN * 4;   // memset [0, ZERO_BYTES)
constexpr size_t OFF_SRCOFF = aln(ZERO_BYTES);         // NN+1 int
constexpr size_t OFF_DSTOFF = OFF_SRCOFF + ((size_t)NN + 1) * 4;
constexpr size_t OFF_BH0   = aln(OFF_DSTOFF + ((size_t)NN + 1) * 4); // NBH*RR
constexpr size_t OFF_BH1   = OFF_BH0 + (size_t)NBH * RR * 4;
constexpr size_t OFF_BB0   = OFF_BH1 + (size_t)NBH * RR * 4;
constexpr size_t OFF_BB1   = OFF_BB0 + (size_t)NBH * RR * 4;
constexpr size_t OFF_OFF0  = aln(OFF_BB1 + (size_t)NBH * RR * 4);    // 66 int
constexpr size_t OFF_OFF1  = OFF_OFF0 + 66 * 4;
constexpr size_t OFF_TILR0 = aln(OFF_OFF1 + 66 * 4);   // MAXT int tile->relation
constexpr size_t OFF_TILT0 = OFF_TILR0 + (size_t)MAXT * 4;
constexpr size_t OFF_TILR1 = OFF_TILT0 + (size_t)MAXT * 4;
constexpr size_t OFF_TILT1 = OFF_TILR1 + (size_t)MAXT * 4;
constexpr size_t OFF_SRCJ  = aln(OFF_TILT1 + (size_t)MAXT * 4); // E int (j -> src)
constexpr size_t OFF_RSJ   = OFF_SRCJ + (size_t)EE * 4;         // E uint (j -> r0|r1<<16)
constexpr size_t OFF_POSDJ = OFF_RSJ + (size_t)EE * 4;          // E int (j -> dst pos)
constexpr size_t OFF_RDP   = OFF_POSDJ + (size_t)EE * 4;        // E uint (pos -> r0|r1<<16)
constexpr size_t OFF_WD0   = OFF_RDP + (size_t)EE * 4;          // E float (pos-space weights)
constexpr size_t OFF_WD1   = OFF_WD0 + (size_t)EE * 4;
constexpr size_t OFF_PERM0 = OFF_WD1 + (size_t)EE * 4;          // E int (stores j)
constexpr size_t OFF_PERM1 = OFF_PERM0 + (size_t)EE * 4;
constexpr size_t OFF_XOB   = aln(OFF_PERM1 + (size_t)EE * 4);   // N*F bf16
constexpr size_t OFF_XAB   = OFF_XOB + (size_t)NN * FIN1 * 2;
constexpr size_t OFF_H1    = aln(OFF_XAB + (size_t)NN * FIN1 * 2); // 3 * N*64 f
constexpr size_t OFF_H1B   = OFF_H1 + (size_t)3 * NN * HH1 * 4;    // 3 * N*64 bf16
constexpr size_t OFF_X2A   = OFF_H1B + (size_t)3 * NN * HH1 * 2;   // N*32 f
constexpr size_t OFF_X2AA  = OFF_X2A + (size_t)NN * HH2 * 4;
constexpr size_t OFF_W1BT  = OFF_X2AA + (size_t)NN * HH2 * 4;      // R*64*128 bf16
constexpr size_t OFF_W2BT  = OFF_W1BT + (size_t)RR * HH1 * FIN1 * 2;
constexpr size_t OFF_R1T   = OFF_W2BT + (size_t)RR * HH2 * HH1 * 2;
constexpr size_t OFF_R2T   = OFF_R1T + (size_t)HH1 * FIN1 * 2;
constexpr size_t OFF_CWT   = OFF_R2T + (size_t)HH2 * HH1 * 2;
constexpr size_t OFF_MSG   = aln(OFF_CWT + (size_t)CLS_N * CLS_K * 2); // E*64 bf16
constexpr size_t WS_END    = OFF_MSG + (size_t)EE * HH1 * 2;

// output offsets (floats)
constexpr size_t O_LOG  = 0;
constexpr size_t O_ROS  = (size_t)BB * RR;
constexpr size_t O_ROSA = O_ROS + (size_t)NN * 2;
constexpr size_t O_X2O  = O_ROSA + (size_t)NN * 2;

__device__ inline unsigned short f2bf(float f) {
    __hip_bfloat16 h = __float2bfloat16(f);
    return *reinterpret_cast<unsigned short*>(&h);
}
__device__ inline float bfbits2f(unsigned int hi_bits) {
    return __uint_as_float(hi_bits);
}

// ---------------- preprocessing ----------------
// per-src / per-dst degree counts (benign 20k-address scatter atomics)
// + fused bf16 conversions (features, relation/root/classifier weights).
__global__ void k_hist(const int* __restrict__ ei,
                       int* cntS, int* cntD,
                       const float* __restrict__ x_o, const float* __restrict__ x_a,
                       const float* __restrict__ W1, const float* __restrict__ W2,
                       const float* __restrict__ root1, const float* __restrict__ root2,
                       const float* __restrict__ clsW,
                       unsigned short* xob, unsigned short* xab,
                       unsigned short* w1t, unsigned short* w2t,
                       unsigned short* r1t, unsigned short* r2t,
                       unsigned short* cwt) {
    int t = threadIdx.x;
    int base = blockIdx.x * EPB;
    for (int i = t; i < EPB; i += 256) {
        atomicAdd(&cntS[ei[base + i]], 1);
        atomicAdd(&cntD[ei[EE + base + i]], 1);
    }
    // streaming conversions (grid-stride over 256-block grid)
    int stride = gridDim.x * 256;
    int i0 = blockIdx.x * 256 + t;
    const int NX = NN * FIN1;
    for (int i = i0; i < NX; i += stride) { xob[i] = f2bf(x_o[i]); xab[i] = f2bf(x_a[i]); }
    const int NW1 = RR * HH1 * FIN1;
    for (int i = i0; i < NW1; i += stride) {
        int k = i % FIN1; int rh = i / FIN1; int hh = rh % HH1; int r = rh / HH1;
        w1t[i] = f2bf(W1[((size_t)r * FIN1 + k) * HH1 + hh]);
    }
    const int NW2 = RR * HH2 * HH1;
    for (int i = i0; i < NW2; i += stride) {
        int k = i % HH1; int rh = i / HH1; int hh = rh % HH2; int r = rh / HH2;
        w2t[i] = f2bf(W2[((size_t)r * HH1 + k) * HH2 + hh]);
    }
    const int NR1 = HH1 * FIN1;
    for (int i = i0; i < NR1; i += stride) {
        int k = i % FIN1; int hh = i / FIN1;
        r1t[i] = f2bf(root1[(size_t)k * HH1 + hh]);
    }
    const int NR2 = HH2 * HH1;
    for (int i = i0; i < NR2; i += stride) {
        int k = i % HH1; int hh = i / HH1;
        r2t[i] = f2bf(root2[(size_t)k * HH2 + hh]);
    }
    const int NCW = CLS_N * CLS_K;
    for (int i = i0; i < NCW; i += stride) {
        int k = i % CLS_K; int n = i / CLS_K;
        cwt[i] = (n < RR && k < 448) ? f2bf(clsW[(size_t)k * RR + n]) : (unsigned short)0;
    }
}

// exclusive scans: cntS->srcOff and cntD->dstOff (single block)
__global__ void k_scanSD(const int* __restrict__ cntS, const int* __restrict__ cntD,
                         int* __restrict__ srcOff, int* __restrict__ dstOff) {
    __shared__ int sm[256];
    int t = threadIdx.x;
    constexpr int PER = (NN + 255) / 256;
    for (int pass = 0; pass < 2; pass++) {
        const int* c = pass ? cntD : cntS;
        int* o = pass ? dstOff : srcOff;
        int lo = t * PER, hi = min(NN, lo + PER);
        int sum = 0;
        for (int i = lo; i < hi; i++) sum += c[i];
        __syncthreads();
        sm[t] = sum;
        __syncthreads();
        for (int ofs = 1; ofs < 256; ofs <<= 1) {
            int v = 0;
            if (t >= ofs) v = sm[t - ofs];
            __syncthreads();
            if (t >= ofs) sm[t] += v;
            __syncthreads();
        }
        int run = sm[t] - sum;
        for (int i = lo; i < hi; i++) { o[i] = run; run += c[i]; }
        if (t == 255) o[NN] = run;
        __syncthreads();
    }
}

// assign each edge its src-sorted index j and dst-sorted pos; relabel metadata
// into j-space (srcJ, rsJ, posDJ) and pos-space (rdP). No small-array atomics.
__global__ void k_orderS(const int* __restrict__ ei, const int* __restrict__ et0,
                         const int* __restrict__ et1,
                         const int* __restrict__ srcOff, const int* __restrict__ dstOff,
                         int* curS, int* curD,
                         int* __restrict__ srcJ, unsigned int* __restrict__ rsJ,
                         int* __restrict__ posDJ, unsigned int* __restrict__ rdP) {
    int e = blockIdx.x * 256 + threadIdx.x;
    if (e < EE) {
        int s = ei[e], d = ei[EE + e];
        unsigned int rr = (unsigned)et0[e] | ((unsigned)et1[e] << 16);
        int j = srcOff[s] + atomicAdd(&curS[s], 1);
        int pos = dstOff[d] + atomicAdd(&curD[d], 1);
        srcJ[j] = s;
        rsJ[j] = rr;
        posDJ[j] = pos;
        rdP[pos] = rr;
    }
}

// per-block relation histograms over the src-sorted sequence (LDS only)
__global__ void k_histR(const unsigned int* __restrict__ rsJ,
                        int* __restrict__ bh0, int* __restrict__ bh1) {
    __shared__ int lh0[RR], lh1[RR];
    int t = threadIdx.x;
    if (t < RR) { lh0[t] = 0; lh1[t] = 0; }
    __syncthreads();
    int base = blockIdx.x * EPB;
    for (int i = t; i < EPB; i += 256) {
        unsigned int rr = rsJ[base + i];
        atomicAdd(&lh0[rr & 0xffffu], 1);
        atomicAdd(&lh1[rr >> 16], 1);
    }
    __syncthreads();
    if (t < RR) {
        bh0[blockIdx.x * RR + t] = lh0[t];
        bh1[blockIdx.x * RR + t] = lh1[t];
    }
}

// per-relation scan over blocks -> blockBase, bucket offsets, and the tile
// tables emitted in (src-octile, relation, tile) order for XCD L2 locality.
__global__ void k_scanR(const int* __restrict__ bh0, const int* __restrict__ bh1,
                        int* __restrict__ bb0, int* __restrict__ bb1,
                        int* off0, int* off1,
                        int* tilR0, int* tilT0, int* tilR1, int* tilT1) {
    __shared__ int h[2][RR];
    __shared__ int o[2][RR + 1];
    int t = threadIdx.x;
    if (t < 2 * RR) {
        int s = t / RR, r = t % RR;
        const int* bh = s ? bh1 : bh0;
        int* bb = s ? bb1 : bb0;
        int run = 0;
        for (int b = 0; b < NBH; b++) {
            bb[b * RR + r] = run;
            run += bh[b * RR + r];
        }
        h[s][r] = run;
    }
    __syncthreads();
    if (t < 2) {
        int s = t;
        int a = 0;
        for (int r = 0; r < RR; r++) { o[s][r] = a; a += h[s][r]; }
        o[s][RR] = a;
    }
    __syncthreads();
    if (t <= RR) { off0[t] = o[0][t]; off1[t] = o[1][t]; }
    if (t < 2) {
        int s = t;
        int* tr = s ? tilR1 : tilR0;
        int* tt = s ? tilT1 : tilT0;
        int idx = 0;
        for (int oct = 0; oct < 8; oct++) {
            for (int r = 0; r < RR; r++) {
                int Tr = (h[s][r] + BM - 1) / BM;
                int lo = (oct * Tr) / 8, hi = ((oct + 1) * Tr) / 8;
                for (int ti = lo; ti < hi; ti++) { tr[idx] = r; tt[idx] = ti; idx++; }
            }
        }
        for (; idx < MAXT; idx++) tr[idx] = -1;
    }
}

// relation-sorted perm placement over the src-sorted sequence; perm stores j.
__global__ void k_fillR(const unsigned int* __restrict__ rsJ,
                        const int* __restrict__ off0, const int* __restrict__ off1,
                        const int* __restrict__ bb0, const int* __restrict__ bb1,
                        int* perm0, int* perm1) {
    __shared__ int lc[2][RR];
    __shared__ int lb[2][RR];
    int t = threadIdx.x;
    if (t < RR) {
        lc[0][t] = 0; lc[1][t] = 0;
        lb[0][t] = off0[t] + bb0[blockIdx.x * RR + t];
        lb[1][t] = off1[t] + bb1[blockIdx.x * RR + t];
    }
    __syncthreads();
    int base = blockIdx.x * EPB;
    for (int i = t; i < EPB; i += 256) {
        int j = base + i;
        unsigned int rr = rsJ[j];
        int r0 = rr & 0xffffu, r1 = rr >> 16;
        int p0 = atomicAdd(&lc[0][r0], 1);
        int p1 = atomicAdd(&lc[1][r1], 1);
        perm0[lb[0][r0] + p0] = j;
        perm1[lb[1][r1] + p1] = j;
    }
}

// per-(relation,dst) mean weights inside each dst segment -> pos-space arrays
// (sequential writes; consumed sequentially by k_reduce).
__global__ void k_wts(const int* __restrict__ dstOff, const unsigned int* __restrict__ rdP,
                      float* __restrict__ wD0, float* __restrict__ wD1) {
    constexpr int CAP = 96;
    __shared__ unsigned int ld[4][CAP];
    int wave = threadIdx.x >> 6;
    int lane = threadIdx.x & 63;
    int d = blockIdx.x * 4 + wave;
    int j0 = 0, deg = 0;
    if (d < NN) { j0 = dstOff[d]; deg = dstOff[d + 1] - j0; }
    for (int j = lane; j < deg && j < CAP; j += 64) ld[wave][j] = rdP[j0 + j];
    __syncthreads();
    for (int j = lane; j < deg; j += 64) {
        unsigned int my = (j < CAP) ? ld[wave][j] : rdP[j0 + j];
        unsigned int m0 = my & 0xffffu, m1 = my >> 16;
        int c0 = 0, c1 = 0;
        for (int k = 0; k < deg; k++) {
            unsigned int p = (k < CAP) ? ld[wave][k] : rdP[j0 + k];
            c0 += ((p & 0xffffu) == m0);
            c1 += ((p >> 16) == m1);
        }
        wD0[j0 + j] = 1.0f / (float)c0;
        wD1[j0 + j] = 1.0f / (float)c1;
    }
}

// root-term GEMM via MFMA: O[n,h] = Xb[n,:] @ rootT[h,:] + bias[h]  (fp32 out)
template <int FIN, int HOUT>
__launch_bounds__(256, 3)
__global__ void k_bgemm(const unsigned short* __restrict__ X0,
                        const unsigned short* __restrict__ X1,
                        const unsigned short* __restrict__ X2,
                        const unsigned short* __restrict__ rootT,
                        const float* __restrict__ bias,
                        float* O0, float* O1, float* O2) {
    const int enc = blockIdx.y;
    const unsigned short* X = enc == 0 ? X0 : enc == 1 ? X1 : X2;
    float* O = enc == 0 ? O0 : enc == 1 ? O1 : O2;
    int n0 = blockIdx.x * BM;
    int mcount = min(BM, NN - n0);

    constexpr int LDK = FIN + 8;
    __shared__ unsigned short As[BM][LDK];
    __shared__ unsigned short Bs[HOUT][LDK];

    int tid = threadIdx.x;
    {
        constexpr int CHB = HOUT * FIN / 8;
        for (int c = tid; c < CHB; c += 256) {
            int row = c / (FIN / 8), cc = c % (FIN / 8);
            *(uint4*)&Bs[row][cc * 8] = *(const uint4*)&rootT[row * FIN + cc * 8];
        }
    }
    {
        constexpr int CHA = BM * FIN / 8;
        for (int c = tid; c < CHA; c += 256) {
            int row = c / (FIN / 8), cc = c % (FIN / 8);
            uint4 v = {0u, 0u, 0u, 0u};
            if (row < mcount) v = *(const uint4*)&X[(size_t)(n0 + row) * FIN + cc * 8];
            *(uint4*)&As[row][cc * 8] = v;
        }
    }
    __syncthreads();

    const int wave = tid >> 6;
    const int lane = tid & 63;
    const int q = lane >> 4;
    const int ln = lane & 15;
    constexpr int NT = HOUT / 16;
    constexpr int KS = FIN / 32;
    const int mbase = wave * 32;

    floatx4 acc[2][NT];
    #pragma unroll
    for (int a = 0; a < 2; a++)
        #pragma unroll
        for (int nt = 0; nt < NT; nt++) acc[a][nt] = floatx4{0.f, 0.f, 0.f, 0.f};

    for (int ks = 0; ks < KS; ks++) {
        int kk = ks * 32 + q * 8;
        short8 af0 = *(const short8*)&As[mbase + ln][kk];
        short8 af1 = *(const short8*)&As[mbase + 16 + ln][kk];
        #pragma unroll
        for (int nt = 0; nt < NT; nt++) {
            short8 bf = *(const short8*)&Bs[nt * 16 + ln][kk];
            acc[0][nt] = __builtin_amdgcn_mfma_f32_16x16x32_bf16(af0, bf, acc[0][nt], 0, 0, 0);
            acc[1][nt] = __builtin_amdgcn_mfma_f32_16x16x32_bf16(af1, bf, acc[1][nt], 0, 0, 0);
        }
    }

    #pragma unroll
    for (int mt = 0; mt < 2; mt++) {
        #pragma unroll
        for (int rr2 = 0; rr2 < 4; rr2++) {
            int i = mbase + mt * 16 + q * 4 + rr2;
            int n = n0 + i;
            if (i < mcount) {
                #pragma unroll
                for (int nt = 0; nt < NT; nt++)
                    O[(size_t)n * HOUT + nt * 16 + ln] = acc[mt][nt][rr2] + bias[nt * 16 + ln];
            }
        }
    }
}

// relation-grouped gather-GEMM with MFMA; tiles dispatched in src-octile-major
// order; A rows ascend in src within a tile (L2-resident gather). Epilogue
// writes unweighted bf16 msg rows to dst-sorted slots (full-line plain stores).
template <int FIN, int HOUT>
__launch_bounds__(256, (FIN == 128 ? 3 : 4))
__global__ void k_gemm(const unsigned short* __restrict__ X,
                       unsigned short* __restrict__ msg,
                       const int* __restrict__ perm, const int* __restrict__ off,
                       const int* __restrict__ tilR, const int* __restrict__ tilT,
                       const int* __restrict__ srcJ, const int* __restrict__ posDJ,
                       const unsigned short* __restrict__ WT) {
    int b = blockIdx.x;
    int r = tilR[b];
    if (r < 0) return;
    int t = tilT[b];
    int ebase = off[r] + t * BM;
    int mcount = min(BM, off[r + 1] - ebase);

    constexpr int LDK = FIN + 8;
    __shared__ unsigned short As[BM][LDK];
    __shared__ unsigned short Bs[HOUT][LDK];
    __shared__ int Sr[BM];
    __shared__ int Pd[BM];

    int tid = threadIdx.x;
    if (tid < BM) {
        if (tid < mcount) {
            int j = perm[ebase + tid];
            Sr[tid] = srcJ[j];
            Pd[tid] = posDJ[j];
        } else { Sr[tid] = -1; Pd[tid] = 0; }
    }
    __syncthreads();

    {
        const unsigned short* Wr = WT + (size_t)r * HOUT * FIN;
        constexpr int CHB = HOUT * FIN / 8;
        for (int c = tid; c < CHB; c += 256) {
            int row = c / (FIN / 8), cc = c % (FIN / 8);
            *(uint4*)&Bs[row][cc * 8] = *(const uint4*)&Wr[row * FIN + cc * 8];
        }
    }
    {
        constexpr int CHA = BM * FIN / 8;
        for (int c = tid; c < CHA; c += 256) {
            int row = c / (FIN / 8), cc = c % (FIN / 8);
            int s = Sr[row];
            uint4 v = {0u, 0u, 0u, 0u};
            if (s >= 0) v = *(const uint4*)&X[(size_t)s * FIN + cc * 8];
            *(uint4*)&As[row][cc * 8] = v;
        }
    }
    __syncthreads();

    const int wave = tid >> 6;
    const int lane = tid & 63;
    const int q = lane >> 4;
    const int ln = lane & 15;
    constexpr int NT = HOUT / 16;
    constexpr int KS = FIN / 32;
    const int mbase = wave * 32;

    floatx4 acc[2][NT];
    #pragma unroll
    for (int a = 0; a < 2; a++)
        #pragma unroll
        for (int nt = 0; nt < NT; nt++) acc[a][nt] = floatx4{0.f, 0.f, 0.f, 0.f};

    for (int ks = 0; ks < KS; ks++) {
        int kk = ks * 32 + q * 8;
        short8 af0 = *(const short8*)&As[mbase + ln][kk];
        short8 af1 = *(const short8*)&As[mbase + 16 + ln][kk];
        #pragma unroll
        for (int nt = 0; nt < NT; nt++) {
            short8 bf = *(const short8*)&Bs[nt * 16 + ln][kk];
            acc[0][nt] = __builtin_amdgcn_mfma_f32_16x16x32_bf16(af0, bf, acc[0][nt], 0, 0, 0);
            acc[1][nt] = __builtin_amdgcn_mfma_f32_16x16x32_bf16(af1, bf, acc[1][nt], 0, 0, 0);
        }
    }

    // epilogue: bf16 msgs through LDS (overlay As), coalesced full-line scatter
    __syncthreads();
    constexpr int LDM = HOUT + 8;
    unsigned short* Ms = &As[0][0];
    #pragma unroll
    for (int mt = 0; mt < 2; mt++) {
        #pragma unroll
        for (int rr2 = 0; rr2 < 4; rr2++) {
            int i = mbase + mt * 16 + q * 4 + rr2;
            #pragma unroll
            for (int nt = 0; nt < NT; nt++)
                Ms[i * LDM + nt * 16 + ln] = f2bf(acc[mt][nt][rr2]);
        }
    }
    __syncthreads();
    constexpr int CH = HOUT / 8;
    for (int c = tid; c < BM * CH; c += 256) {
        int row = c / CH, cc = c % CH;
        if (row < mcount)
            *(uint4*)&msg[(size_t)Pd[row] * HOUT + cc * 8] = *(const uint4*)&Ms[row * LDM + cc * 8];
    }
}

// weighted segment-sum of msg rows per dst + root base; optional relu+bf16.
template <int H, bool RELU>
__global__ void k_reduce(const unsigned short* __restrict__ msg,
                         const int* __restrict__ dstOff,
                         const float* __restrict__ wD,
                         float* __restrict__ base_io,
                         unsigned short* __restrict__ bfout) {
    int d = blockIdx.x * 4 + (threadIdx.x >> 6);
    if (d >= NN) return;
    int lane = threadIdx.x & 63;
    constexpr int HC = H / 4;
    constexpr int RPI = 64 / HC;
    int sub = lane / HC;
    int c4 = lane % HC;
    int j0 = dstOff[d], j1 = dstOff[d + 1];
    float a0 = 0.f, a1 = 0.f, a2 = 0.f, a3 = 0.f;
    for (int j = j0 + sub; j < j1; j += RPI) {
        float w = wD[j];
        uint2 v = *(const uint2*)&msg[(size_t)j * H + c4 * 4];
        a0 += w * bfbits2f(v.x << 16);
        a1 += w * bfbits2f(v.x & 0xffff0000u);
        a2 += w * bfbits2f(v.y << 16);
        a3 += w * bfbits2f(v.y & 0xffff0000u);
    }
    #pragma unroll
    for (int ofs = 32; ofs >= HC; ofs >>= 1) {
        a0 += __shfl_down(a0, ofs); a1 += __shfl_down(a1, ofs);
        a2 += __shfl_down(a2, ofs); a3 += __shfl_down(a3, ofs);
    }
    if (lane < HC) {
        size_t o = (size_t)d * H + c4 * 4;
        float v0 = base_io[o] + a0, v1 = base_io[o + 1] + a1;
        float v2 = base_io[o + 2] + a2, v3 = base_io[o + 3] + a3;
        if (RELU) {
            v0 = fmaxf(v0, 0.f); v1 = fmaxf(v1, 0.f);
            v2 = fmaxf(v2, 0.f); v3 = fmaxf(v3, 0.f);
        }
        base_io[o] = v0; base_io[o + 1] = v1; base_io[o + 2] = v2; base_io[o + 3] = v3;
        if (RELU) {
            bfout[o] = f2bf(v0); bfout[o + 1] = f2bf(v1);
            bfout[o + 2] = f2bf(v2); bfout[o + 3] = f2bf(v3);
        }
    }
}

// column sums of x2_o -> csum[32]
__global__ void k_mean(const float* __restrict__ x2o, float* csum) {
    __shared__ float s[256];
    int t = threadIdx.x; int hh = t & 31; int g = t >> 5;
    float acc = 0.f;
    for (int n = blockIdx.x * 8 + g; n < NN; n += gridDim.x * 8)
        acc += x2o[(size_t)n * 32 + hh];
    s[t] = acc;
    __syncthreads();
    if (t < 32) {
        float v = 0.f;
        for (int gg = 0; gg < 8; gg++) v += s[gg * 32 + t];
        unsafeAtomicAdd(&csum[t], v);
    }
}

// c = sigmoid(csum/N); v = disc_W @ c; bilinear scores
__global__ void k_disc(const float* __restrict__ x2o, const float* __restrict__ x2a,
                       const float* __restrict__ x2aa, const float* __restrict__ csum,
                       const float* __restrict__ discW, const float* __restrict__ discb,
                       float* ret_os, float* ret_osa) {
    __shared__ float c[32], v[32];
    int t = threadIdx.x;
    if (t < 32) c[t] = 1.f / (1.f + expf(-csum[t] * (1.f / NN)));
    __syncthreads();
    if (t < 32) {
        float a = 0.f;
        for (int j = 0; j < 32; j++) a += discW[t * 32 + j] * c[j];
        v[t] = a;
    }
    __syncthreads();
    float db = discb[0];
    int n = blockIdx.x * 256 + t;
    if (n < NN) {
        float s1 = 0.f, s2 = 0.f, s3 = 0.f;
        for (int j = 0; j < 32; j++) {
            float vj = v[j];
            s1 += x2o[(size_t)n * 32 + j] * vj;
            s2 += x2a[(size_t)n * 32 + j] * vj;
            s3 += x2aa[(size_t)n * 32 + j] * vj;
        }
        ret_os[n * 2] = s1 + db;  ret_os[n * 2 + 1] = s2 + db;
        ret_osa[n * 2] = s1 + db; ret_osa[n * 2 + 1] = s3 + db;
    }
}

// pair classifier as MFMA GEMM (K padded to 512, N padded to 80)
__launch_bounds__(256, 2)
__global__ void k_clsg(const float* __restrict__ h1o, const float* __restrict__ x2o,
                       const float* __restrict__ feat, const float* __restrict__ attt,
                       const int* __restrict__ idx,
                       const unsigned short* __restrict__ cwt,
                       const float* __restrict__ clsb, float* __restrict__ log_out) {
    constexpr int LDK = CLS_CK + 8;
    __shared__ unsigned short As[CLS_BM][LDK];
    __shared__ unsigned short Bs[CLS_N][LDK];
    __shared__ int nd[2][CLS_BM];

    int tid = threadIdx.x;
    int p0 = blockIdx.x * CLS_BM;
    if (tid < CLS_BM) {
        nd[0][tid] = idx[p0 + tid];
        nd[1][tid] = idx[BB + p0 + tid];
    }
    float a0 = attt[0], a1 = attt[1];

    const int wave = tid >> 6;
    const int lane = tid & 63;
    const int q = lane >> 4;
    const int ln = lane & 15;
    constexpr int NT = CLS_N / 16;
    const int mbase = wave * 16;

    floatx4 acc[NT];
    #pragma unroll
    for (int nt = 0; nt < NT; nt++) acc[nt] = floatx4{0.f, 0.f, 0.f, 0.f};

    for (int ch = 0; ch < CLS_K / CLS_CK; ch++) {
        int kbase = ch * CLS_CK;
        __syncthreads();
        for (int c = tid; c < CLS_N * CLS_CK / 8; c += 256) {
            int row = c / (CLS_CK / 8), cc = c % (CLS_CK / 8);
            *(uint4*)&Bs[row][cc * 8] = *(const uint4*)&cwt[(size_t)row * CLS_K + kbase + cc * 8];
        }
        for (int c = tid; c < CLS_BM * CLS_CK / 4; c += 256) {
            int row = c / (CLS_CK / 4);
            int j4 = (c % (CLS_CK / 4)) * 4;
            int j = kbase + j4;
            float4 v = {0.f, 0.f, 0.f, 0.f};
            if (j < 448) {
                int hseg = j / 224, jj = j % 224;
                int node = nd[hseg][row];
                if (jj < 64) {
                    v = *(const float4*)&h1o[(size_t)node * 64 + jj];
                    v.x *= a0; v.y *= a0; v.z *= a0; v.w *= a0;
                } else if (jj < 96) {
                    v = *(const float4*)&x2o[(size_t)node * 32 + (jj - 64)];
                    v.x *= a1; v.y *= a1; v.z *= a1; v.w *= a1;
                } else {
                    v = *(const float4*)&feat[(size_t)node * 128 + (jj - 96)];
                }
            }
            uint2 pk;
            pk.x = (unsigned)f2bf(v.x) | ((unsigned)f2bf(v.y) << 16);
            pk.y = (unsigned)f2bf(v.z) | ((unsigned)f2bf(v.w) << 16);
            *(uint2*)&As[row][j4] = pk;
        }
        __syncthreads();
        #pragma unroll
        for (int ks = 0; ks < CLS_CK / 32; ks++) {
            int kk = ks * 32 + q * 8;
            short8 af = *(const short8*)&As[mbase + ln][kk];
            #pragma unroll
            for (int nt = 0; nt < NT; nt++) {
                short8 bf = *(const short8*)&Bs[nt * 16 + ln][kk];
                acc[nt] = __builtin_amdgcn_mfma_f32_16x16x32_bf16(af, bf, acc[nt], 0, 0, 0);
            }
        }
    }

    #pragma unroll
    for (int rr2 = 0; rr2 < 4; rr2++) {
        int i = mbase + q * 4 + rr2;
        int pair = p0 + i;
        #pragma unroll
        for (int nt = 0; nt < NT; nt++) {
            int col = nt * 16 + ln;
            if (col < RR)
                log_out[(size_t)pair * RR + col] = acc[nt][rr2] + clsb[col];
        }
    }
}

extern "C" void kernel_launch(void* const* d_in, const int* in_sizes, int n_in,
                              void* d_out, int out_size, void* d_ws, size_t ws_size,
                              hipStream_t stream) {
    const float* x_o   = (const float*)d_in[0];
    const float* x_a   = (const float*)d_in[1];
    const float* feat  = (const float*)d_in[2];
    const float* W1    = (const float*)d_in[3];
    const float* root1 = (const float*)d_in[4];
    const float* b1    = (const float*)d_in[5];
    const float* W2    = (const float*)d_in[6];
    const float* root2 = (const float*)d_in[7];
    const float* b2    = (const float*)d_in[8];
    const float* attt  = (const float*)d_in[9];
    const float* discW = (const float*)d_in[10];
    const float* discb = (const float*)d_in[11];
    const float* clsW  = (const float*)d_in[12];
    const float* clsb  = (const float*)d_in[13];
    const int* ei      = (const int*)d_in[14];
    const int* et0     = (const int*)d_in[15];
    const int* et1     = (const int*)d_in[16];
    const int* idx     = (const int*)d_in[17];

    char* ws = (char*)d_ws;
    float* csum = (float*)(ws + OFF_CSUM);
    int* cntS  = (int*)(ws + OFF_CNTS);
    int* cntD  = (int*)(ws + OFF_CNTD);
    int* curS  = (int*)(ws + OFF_CURS);
    int* curD  = (int*)(ws + OFF_CURD);
    int* srcOff = (int*)(ws + OFF_SRCOFF);
    int* dstOff = (int*)(ws + OFF_DSTOFF);
    int* bh0   = (int*)(ws + OFF_BH0);
    int* bh1   = (int*)(ws + OFF_BH1);
    int* bb0   = (int*)(ws + OFF_BB0);
    int* bb1   = (int*)(ws + OFF_BB1);
    int* off0  = (int*)(ws + OFF_OFF0);
    int* off1  = (int*)(ws + OFF_OFF1);
    int* tilR0 = (int*)(ws + OFF_TILR0);
    int* tilT0 = (int*)(ws + OFF_TILT0);
    int* tilR1 = (int*)(ws + OFF_TILR1);
    int* tilT1 = (int*)(ws + OFF_TILT1);
    int* srcJ  = (int*)(ws + OFF_SRCJ);
    unsigned int* rsJ = (unsigned int*)(ws + OFF_RSJ);
    int* posDJ = (int*)(ws + OFF_POSDJ);
    unsigned int* rdP = (unsigned int*)(ws + OFF_RDP);
    float* wD0 = (float*)(ws + OFF_WD0);
    float* wD1 = (float*)(ws + OFF_WD1);
    int* perm0 = (int*)(ws + OFF_PERM0);
    int* perm1 = (int*)(ws + OFF_PERM1);
    unsigned short* xob = (unsigned short*)(ws + OFF_XOB);
    unsigned short* xab = (unsigned short*)(ws + OFF_XAB);
    float* h1o  = (float*)(ws + OFF_H1);
    float* h1a  = h1o + (size_t)NN * HH1;
    float* h1aa = h1a + (size_t)NN * HH1;
    unsigned short* h1bo  = (unsigned short*)(ws + OFF_H1B);
    unsigned short* h1ba  = h1bo + (size_t)NN * HH1;
    unsigned short* h1baa = h1ba + (size_t)NN * HH1;
    float* x2a  = (float*)(ws + OFF_X2A);
    float* x2aa = (float*)(ws + OFF_X2AA);
    unsigned short* w1t = (unsigned short*)(ws + OFF_W1BT);
    unsigned short* w2t = (unsigned short*)(ws + OFF_W2BT);
    unsigned short* r1t = (unsigned short*)(ws + OFF_R1T);
    unsigned short* r2t = (unsigned short*)(ws + OFF_R2T);
    unsigned short* cwt = (unsigned short*)(ws + OFF_CWT);
    unsigned short* msg = (unsigned short*)(ws + OFF_MSG);

    float* out = (float*)d_out;
    float* log_out = out + O_LOG;
    float* ret_os  = out + O_ROS;
    float* ret_osa = out + O_ROSA;
    float* x2o     = out + O_X2O;

    // 1) zero control block (csum + cntS/cntD/curS/curD) — ~320 KB
    hipMemsetAsync(ws, 0, ZERO_BYTES, stream);

    // 2) preprocessing: src/dst CSRs, src-sorted relabel, relation sort,
    //    octile-major tile tables, pos-space weights
    k_hist<<<NBH, 256, 0, stream>>>(ei, cntS, cntD,
                                    x_o, x_a, W1, W2, root1, root2, clsW,
                                    xob, xab, w1t, w2t, r1t, r2t, cwt);
    k_scanSD<<<1, 256, 0, stream>>>(cntS, cntD, srcOff, dstOff);
    k_orderS<<<2500, 256, 0, stream>>>(ei, et0, et1, srcOff, dstOff,
                                       curS, curD, srcJ, rsJ, posDJ, rdP);
    k_histR<<<NBH, 256, 0, stream>>>(rsJ, bh0, bh1);
    k_scanR<<<1, 256, 0, stream>>>(bh0, bh1, bb0, bb1, off0, off1,
                                   tilR0, tilT0, tilR1, tilT1);
    k_fillR<<<NBH, 256, 0, stream>>>(rsJ, off0, off1, bb0, bb1, perm0, perm1);
    k_wts<<<NN / 4, 256, 0, stream>>>(dstOff, rdP, wD0, wD1);

    // 3) layer 1: MFMA root GEMM + per-encoding (edge GEMM -> weighted reduce)
    {
        dim3 gb(NBT, 3);
        k_bgemm<FIN1, HH1><<<gb, 256, 0, stream>>>(xob, xab, xob, r1t, b1,
                                                   h1o, h1a, h1aa);
        const unsigned short* Xs[3] = {xob, xab, xob};
        float* Os[3] = {h1o, h1a, h1aa};
        unsigned short* Obs[3] = {h1bo, h1ba, h1baa};
        for (int enc = 0; enc < 3; enc++) {
            const int* perm = enc == 2 ? perm1 : perm0;
            const int* off  = enc == 2 ? off1 : off0;
            const int* tilR = enc == 2 ? tilR1 : tilR0;
            const int* tilT = enc == 2 ? tilT1 : tilT0;
            const float* wD = enc == 2 ? wD1 : wD0;
            k_gemm<FIN1, HH1><<<MAXT, 256, 0, stream>>>(Xs[enc], msg, perm, off,
                                                        tilR, tilT, srcJ, posDJ, w1t);
            k_reduce<HH1, true><<<NN / 4, 256, 0, stream>>>(msg, dstOff, wD,
                                                            Os[enc], Obs[enc]);
        }
    }

    // 4) layer 2: MFMA root GEMM + per-encoding (edge GEMM -> weighted reduce)
    {
        dim3 gb(NBT, 3);
        k_bgemm<HH1, HH2><<<gb, 256, 0, stream>>>(h1bo, h1ba, h1baa, r2t, b2,
                                                  x2o, x2a, x2aa);
        const unsigned short* Xs[3] = {h1bo, h1ba, h1baa};
        float* Os[3] = {x2o, x2a, x2aa};
        for (int enc = 0; enc < 3; enc++) {
            const int* perm = enc == 2 ? perm1 : perm0;
            const int* off  = enc == 2 ? off1 : off0;
            const int* tilR = enc == 2 ? tilR1 : tilR0;
            const int* tilT = enc == 2 ? tilT1 : tilT0;
            const float* wD = enc == 2 ? wD1 : wD0;
            k_gemm<HH1, HH2><<<MAXT, 256, 0, stream>>>(Xs[enc], msg, perm, off,
                                                       tilR, tilT, srcJ, posDJ, w2t);
            k_reduce<HH2, false><<<NN / 4, 256, 0, stream>>>(msg, dstOff, wD,
                                                             Os[enc], nullptr);
        }
    }

    // 5) readout + discriminator + classifier
    k_mean<<<256, 256, 0, stream>>>(x2o, csum);
    k_disc<<<(NN + 255) / 256, 256, 0, stream>>>(x2o, x2a, x2aa, csum, discW, discb,
                                                 ret_os, ret_osa);
    k_clsg<<<BB / CLS_BM, 256, 0, stream>>>(h1o, x2o, feat, attt, idx, cwt, clsb, log_out);
}

// Round 8
// 811.387 us; speedup vs baseline: 1.2404x; 1.2404x over previous
//
#include <hip/hip_runtime.h>
#include <hip/hip_bf16.h>

// ---------------- problem constants ----------------
#define NN 20000      // nodes
#define EE 640000     // edges
#define RR 65         // relations
#define FIN1 128      // input feat
#define HH1 64        // hidden1
#define HH2 32        // hidden2
#define BB 8192       // pairs

constexpr int BM = 128;                 // edge-tile rows per GEMM block
constexpr int MAXT = EE / BM + RR;      // 5065 upper bound on tiles per sort
constexpr int NBH = 256;                // histogram/placement blocks
constexpr int EPB = EE / NBH;           // 2500 edges per block
constexpr int NBT = (NN + BM - 1) / BM; // 157 node tiles

// classifier GEMM geometry (E[8192x448] @ clsW[448x65], padded)
constexpr int CLS_K  = 512;
constexpr int CLS_N  = 80;
constexpr int CLS_CK = 128;
constexpr int CLS_BM = 64;

typedef __attribute__((ext_vector_type(8))) short short8;   // 8 bf16 MFMA frag
typedef __attribute__((ext_vector_type(4))) float floatx4;  // 4 fp32 acc

// ---------------- workspace layout (bytes) ----------------
constexpr size_t aln(size_t x) { return (x + 255) & ~(size_t)255; }

constexpr size_t OFF_CSUM  = 0;                        // 32 f
constexpr size_t OFF_CNTS  = aln(OFF_CSUM + 32 * 4);  // NN int (src degree)
constexpr size_t OFF_CNTD  = OFF_CNTS + (size_t)NN * 4;
constexpr size_t OFF_CURS  = OFF_CNTD + (size_t)NN * 4;
constexpr size_t OFF_CURD  = OFF_CURS + (size_t)NN * 4;
constexpr size_t ZERO_BYTES = OFF_CURD + (size_t)NN * 4;   // memset [0, ZERO_BYTES)
constexpr size_t OFF_SRCOFF = aln(ZERO_BYTES);         // NN+1 int
constexpr size_t OFF_DSTOFF = OFF_SRCOFF + ((size_t)NN + 1) * 4;
constexpr size_t OFF_BH0   = aln(OFF_DSTOFF + ((size_t)NN + 1) * 4); // NBH*RR
constexpr size_t OFF_BH1   = OFF_BH0 + (size_t)NBH * RR * 4;
constexpr size_t OFF_BB0   = OFF_BH1 + (size_t)NBH * RR * 4;
constexpr size_t OFF_BB1   = OFF_BB0 + (size_t)NBH * RR * 4;
constexpr size_t OFF_OFF0  = aln(OFF_BB1 + (size_t)NBH * RR * 4);    // 66 int
constexpr size_t OFF_OFF1  = OFF_OFF0 + 66 * 4;
constexpr size_t OFF_TILR0 = aln(OFF_OFF1 + 66 * 4);   // MAXT int tile->relation
constexpr size_t OFF_TILT0 = OFF_TILR0 + (size_t)MAXT * 4;
constexpr size_t OFF_TILR1 = OFF_TILT0 + (size_t)MAXT * 4;
constexpr size_t OFF_TILT1 = OFF_TILR1 + (size_t)MAXT * 4;
constexpr size_t OFF_SRCJ  = aln(OFF_TILT1 + (size_t)MAXT * 4); // E int (j -> src)
constexpr size_t OFF_RSJ   = OFF_SRCJ + (size_t)EE * 4;         // E uint (j -> r0|r1<<16)
constexpr size_t OFF_POSDJ = OFF_RSJ + (size_t)EE * 4;          // E int (j -> dst pos)
constexpr size_t OFF_RDP   = OFF_POSDJ + (size_t)EE * 4;        // E uint (pos -> r0|r1<<16)
constexpr size_t OFF_WD0   = OFF_RDP + (size_t)EE * 4;          // E float (pos-space weights)
constexpr size_t OFF_WD1   = OFF_WD0 + (size_t)EE * 4;
constexpr size_t OFF_PERM0 = OFF_WD1 + (size_t)EE * 4;          // E int (stores j)
constexpr size_t OFF_PERM1 = OFF_PERM0 + (size_t)EE * 4;
constexpr size_t OFF_XOB   = aln(OFF_PERM1 + (size_t)EE * 4);   // N*F bf16
constexpr size_t OFF_XAB   = OFF_XOB + (size_t)NN * FIN1 * 2;
constexpr size_t OFF_H1    = aln(OFF_XAB + (size_t)NN * FIN1 * 2); // 3 * N*64 f
constexpr size_t OFF_H1B   = OFF_H1 + (size_t)3 * NN * HH1 * 4;    // 3 * N*64 bf16
constexpr size_t OFF_X2A   = OFF_H1B + (size_t)3 * NN * HH1 * 2;   // N*32 f
constexpr size_t OFF_X2AA  = OFF_X2A + (size_t)NN * HH2 * 4;
constexpr size_t OFF_W1BT  = OFF_X2AA + (size_t)NN * HH2 * 4;      // R*64*128 bf16
constexpr size_t OFF_W2BT  = OFF_W1BT + (size_t)RR * HH1 * FIN1 * 2;
constexpr size_t OFF_R1T   = OFF_W2BT + (size_t)RR * HH2 * HH1 * 2;
constexpr size_t OFF_R2T   = OFF_R1T + (size_t)HH1 * FIN1 * 2;
constexpr size_t OFF_CWT   = OFF_R2T + (size_t)HH2 * HH1 * 2;
constexpr size_t OFF_MSG   = aln(OFF_CWT + (size_t)CLS_N * CLS_K * 2); // E*64 bf16
constexpr size_t WS_END    = OFF_MSG + (size_t)EE * HH1 * 2;

// output offsets (floats)
constexpr size_t O_LOG  = 0;
constexpr size_t O_ROS  = (size_t)BB * RR;
constexpr size_t O_ROSA = O_ROS + (size_t)NN * 2;
constexpr size_t O_X2O  = O_ROSA + (size_t)NN * 2;

__device__ inline unsigned short f2bf(float f) {
    __hip_bfloat16 h = __float2bfloat16(f);
    return *reinterpret_cast<unsigned short*>(&h);
}
__device__ inline float bfbits2f(unsigned int hi_bits) {
    return __uint_as_float(hi_bits);
}

// ---------------- preprocessing ----------------
// per-src / per-dst degree counts (benign 20k-address scatter atomics)
// + fused bf16 conversions (features, relation/root/classifier weights).
__global__ void k_hist(const int* __restrict__ ei,
                       int* cntS, int* cntD,
                       const float* __restrict__ x_o, const float* __restrict__ x_a,
                       const float* __restrict__ W1, const float* __restrict__ W2,
                       const float* __restrict__ root1, const float* __restrict__ root2,
                       const float* __restrict__ clsW,
                       unsigned short* xob, unsigned short* xab,
                       unsigned short* w1t, unsigned short* w2t,
                       unsigned short* r1t, unsigned short* r2t,
                       unsigned short* cwt) {
    int t = threadIdx.x;
    int base = blockIdx.x * EPB;
    for (int i = t; i < EPB; i += 256) {
        atomicAdd(&cntS[ei[base + i]], 1);
        atomicAdd(&cntD[ei[EE + base + i]], 1);
    }
    // streaming conversions (grid-stride over 256-block grid)
    int stride = gridDim.x * 256;
    int i0 = blockIdx.x * 256 + t;
    const int NX = NN * FIN1;
    for (int i = i0; i < NX; i += stride) { xob[i] = f2bf(x_o[i]); xab[i] = f2bf(x_a[i]); }
    const int NW1 = RR * HH1 * FIN1;
    for (int i = i0; i < NW1; i += stride) {
        int k = i % FIN1; int rh = i / FIN1; int hh = rh % HH1; int r = rh / HH1;
        w1t[i] = f2bf(W1[((size_t)r * FIN1 + k) * HH1 + hh]);
    }
    const int NW2 = RR * HH2 * HH1;
    for (int i = i0; i < NW2; i += stride) {
        int k = i % HH1; int rh = i / HH1; int hh = rh % HH2; int r = rh / HH2;
        w2t[i] = f2bf(W2[((size_t)r * HH1 + k) * HH2 + hh]);
    }
    const int NR1 = HH1 * FIN1;
    for (int i = i0; i < NR1; i += stride) {
        int k = i % FIN1; int hh = i / FIN1;
        r1t[i] = f2bf(root1[(size_t)k * HH1 + hh]);
    }
    const int NR2 = HH2 * HH1;
    for (int i = i0; i < NR2; i += stride) {
        int k = i % HH1; int hh = i / HH1;
        r2t[i] = f2bf(root2[(size_t)k * HH2 + hh]);
    }
    const int NCW = CLS_N * CLS_K;
    for (int i = i0; i < NCW; i += stride) {
        int k = i % CLS_K; int n = i / CLS_K;
        cwt[i] = (n < RR && k < 448) ? f2bf(clsW[(size_t)k * RR + n]) : (unsigned short)0;
    }
}

// exclusive scans: cntS->srcOff and cntD->dstOff (single block)
__global__ void k_scanSD(const int* __restrict__ cntS, const int* __restrict__ cntD,
                         int* __restrict__ srcOff, int* __restrict__ dstOff) {
    __shared__ int sm[256];
    int t = threadIdx.x;
    constexpr int PER = (NN + 255) / 256;
    for (int pass = 0; pass < 2; pass++) {
        const int* c = pass ? cntD : cntS;
        int* o = pass ? dstOff : srcOff;
        int lo = t * PER, hi = min(NN, lo + PER);
        int sum = 0;
        for (int i = lo; i < hi; i++) sum += c[i];
        __syncthreads();
        sm[t] = sum;
        __syncthreads();
        for (int ofs = 1; ofs < 256; ofs <<= 1) {
            int v = 0;
            if (t >= ofs) v = sm[t - ofs];
            __syncthreads();
            if (t >= ofs) sm[t] += v;
            __syncthreads();
        }
        int run = sm[t] - sum;
        for (int i = lo; i < hi; i++) { o[i] = run; run += c[i]; }
        if (t == 255) o[NN] = run;
        __syncthreads();
    }
}

// assign each edge its src-sorted index j and dst-sorted pos; relabel metadata
// into j-space (srcJ, rsJ, posDJ) and pos-space (rdP). No small-array atomics.
__global__ void k_orderS(const int* __restrict__ ei, const int* __restrict__ et0,
                         const int* __restrict__ et1,
                         const int* __restrict__ srcOff, const int* __restrict__ dstOff,
                         int* curS, int* curD,
                         int* __restrict__ srcJ, unsigned int* __restrict__ rsJ,
                         int* __restrict__ posDJ, unsigned int* __restrict__ rdP) {
    int e = blockIdx.x * 256 + threadIdx.x;
    if (e < EE) {
        int s = ei[e], d = ei[EE + e];
        unsigned int rr = (unsigned)et0[e] | ((unsigned)et1[e] << 16);
        int j = srcOff[s] + atomicAdd(&curS[s], 1);
        int pos = dstOff[d] + atomicAdd(&curD[d], 1);
        srcJ[j] = s;
        rsJ[j] = rr;
        posDJ[j] = pos;
        rdP[pos] = rr;
    }
}

// per-block relation histograms over the src-sorted sequence (LDS only)
__global__ void k_histR(const unsigned int* __restrict__ rsJ,
                        int* __restrict__ bh0, int* __restrict__ bh1) {
    __shared__ int lh0[RR], lh1[RR];
    int t = threadIdx.x;
    if (t < RR) { lh0[t] = 0; lh1[t] = 0; }
    __syncthreads();
    int base = blockIdx.x * EPB;
    for (int i = t; i < EPB; i += 256) {
        unsigned int rr = rsJ[base + i];
        atomicAdd(&lh0[rr & 0xffffu], 1);
        atomicAdd(&lh1[rr >> 16], 1);
    }
    __syncthreads();
    if (t < RR) {
        bh0[blockIdx.x * RR + t] = lh0[t];
        bh1[blockIdx.x * RR + t] = lh1[t];
    }
}

// per-relation scan over blocks -> blockBase + bucket offsets + tile tables in
// (src-octile, relation, tile) order. Fully parallel: hierarchical LDS scan of
// the 2x520 per-(oct,rel) tile counts, then 256-thread binary-search emission.
__global__ void k_scanR(const int* __restrict__ bh0, const int* __restrict__ bh1,
                        int* __restrict__ bb0, int* __restrict__ bb1,
                        int* off0, int* off1,
                        int* tilR0, int* tilT0, int* tilR1, int* tilT1) {
    __shared__ int h[2][RR];
    __shared__ int o[2][RR + 1];
    __shared__ int ofs[2][8 * RR + 1];   // per-(oct,rel) exclusive tile offsets
    __shared__ int lotab[2][8 * RR];     // starting tile index per (oct,rel)
    __shared__ int octsum[2][9];
    int t = threadIdx.x;
    // per-relation block-base scan (130 threads, global)
    if (t < 2 * RR) {
        int s = t / RR, r = t % RR;
        const int* bh = s ? bh1 : bh0;
        int* bb = s ? bb1 : bb0;
        int run = 0;
        for (int b = 0; b < NBH; b++) {
            bb[b * RR + r] = run;
            run += bh[b * RR + r];
        }
        h[s][r] = run;
    }
    __syncthreads();
    if (t < 2) {
        int s = t;
        int a = 0;
        for (int r = 0; r < RR; r++) { o[s][r] = a; a += h[s][r]; }
        o[s][RR] = a;
    }
    __syncthreads();
    if (t <= RR) { off0[t] = o[0][t]; off1[t] = o[1][t]; }
    // per-(oct,rel) tile counts
    if (t < 2 * RR) {
        int s = t / RR, r = t % RR;
        int Tr = (h[s][r] + BM - 1) / BM;
        for (int oct = 0; oct < 8; oct++) {
            int lo = (oct * Tr) / 8, hi = ((oct + 1) * Tr) / 8;
            lotab[s][oct * RR + r] = lo;
            ofs[s][oct * RR + r] = hi - lo;
        }
    }
    __syncthreads();
    // hierarchical exclusive scan (all in LDS): within-octile, octile totals, base add
    if (t < 16) {
        int s = t / 8, oct = t % 8;
        int run = 0;
        for (int r = 0; r < RR; r++) {
            int c = ofs[s][oct * RR + r];
            ofs[s][oct * RR + r] = run;
            run += c;
        }
        octsum[s][oct] = run;
    }
    __syncthreads();
    if (t < 2) {
        int run = 0;
        for (int oct = 0; oct < 8; oct++) { int c = octsum[t][oct]; octsum[t][oct] = run; run += c; }
        octsum[t][8] = run;
    }
    __syncthreads();
    if (t < 2 * RR) {
        int s = t / RR, r = t % RR;
        for (int oct = 0; oct < 8; oct++) ofs[s][oct * RR + r] += octsum[s][oct];
    }
    if (t < 2) ofs[t][8 * RR] = octsum[t][8];
    __syncthreads();
    // emit tile tables: 256 threads, binary search over the 521-entry LDS table
    for (int i = t; i < MAXT; i += 256) {
        #pragma unroll
        for (int s = 0; s < 2; s++) {
            int total = ofs[s][8 * RR];
            int r = -1, ti = 0;
            if (i < total) {
                int lo = 0, hi = 8 * RR;
                while (hi - lo > 1) { int mid = (lo + hi) >> 1; if (ofs[s][mid] <= i) lo = mid; else hi = mid; }
                r = lo % RR;
                ti = lotab[s][lo] + (i - ofs[s][lo]);
            }
            if (s == 0) { tilR0[i] = r; tilT0[i] = ti; }
            else        { tilR1[i] = r; tilT1[i] = ti; }
        }
    }
}

// relation-sorted perm placement over the src-sorted sequence; perm stores j.
__global__ void k_fillR(const unsigned int* __restrict__ rsJ,
                        const int* __restrict__ off0, const int* __restrict__ off1,
                        const int* __restrict__ bb0, const int* __restrict__ bb1,
                        int* perm0, int* perm1) {
    __shared__ int lc[2][RR];
    __shared__ int lb[2][RR];
    int t = threadIdx.x;
    if (t < RR) {
        lc[0][t] = 0; lc[1][t] = 0;
        lb[0][t] = off0[t] + bb0[blockIdx.x * RR + t];
        lb[1][t] = off1[t] + bb1[blockIdx.x * RR + t];
    }
    __syncthreads();
    int base = blockIdx.x * EPB;
    for (int i = t; i < EPB; i += 256) {
        int j = base + i;
        unsigned int rr = rsJ[j];
        int r0 = rr & 0xffffu, r1 = rr >> 16;
        int p0 = atomicAdd(&lc[0][r0], 1);
        int p1 = atomicAdd(&lc[1][r1], 1);
        perm0[lb[0][r0] + p0] = j;
        perm1[lb[1][r1] + p1] = j;
    }
}

// per-(relation,dst) mean weights inside each dst segment -> pos-space arrays
__global__ void k_wts(const int* __restrict__ dstOff, const unsigned int* __restrict__ rdP,
                      float* __restrict__ wD0, float* __restrict__ wD1) {
    constexpr int CAP = 96;
    __shared__ unsigned int ld[4][CAP];
    int wave = threadIdx.x >> 6;
    int lane = threadIdx.x & 63;
    int d = blockIdx.x * 4 + wave;
    int j0 = 0, deg = 0;
    if (d < NN) { j0 = dstOff[d]; deg = dstOff[d + 1] - j0; }
    for (int j = lane; j < deg && j < CAP; j += 64) ld[wave][j] = rdP[j0 + j];
    __syncthreads();
    for (int j = lane; j < deg; j += 64) {
        unsigned int my = (j < CAP) ? ld[wave][j] : rdP[j0 + j];
        unsigned int m0 = my & 0xffffu, m1 = my >> 16;
        int c0 = 0, c1 = 0;
        for (int k = 0; k < deg; k++) {
            unsigned int p = (k < CAP) ? ld[wave][k] : rdP[j0 + k];
            c0 += ((p & 0xffffu) == m0);
            c1 += ((p >> 16) == m1);
        }
        wD0[j0 + j] = 1.0f / (float)c0;
        wD1[j0 + j] = 1.0f / (float)c1;
    }
}

// root-term GEMM via MFMA: O[n,h] = Xb[n,:] @ rootT[h,:] + bias[h]  (fp32 out)
template <int FIN, int HOUT>
__launch_bounds__(256, 3)
__global__ void k_bgemm(const unsigned short* __restrict__ X0,
                        const unsigned short* __restrict__ X1,
                        const unsigned short* __restrict__ X2,
                        const unsigned short* __restrict__ rootT,
                        const float* __restrict__ bias,
                        float* O0, float* O1, float* O2) {
    const int enc = blockIdx.y;
    const unsigned short* X = enc == 0 ? X0 : enc == 1 ? X1 : X2;
    float* O = enc == 0 ? O0 : enc == 1 ? O1 : O2;
    int n0 = blockIdx.x * BM;
    int mcount = min(BM, NN - n0);

    constexpr int LDK = FIN + 8;
    __shared__ unsigned short As[BM][LDK];
    __shared__ unsigned short Bs[HOUT][LDK];

    int tid = threadIdx.x;
    {
        constexpr int CHB = HOUT * FIN / 8;
        for (int c = tid; c < CHB; c += 256) {
            int row = c / (FIN / 8), cc = c % (FIN / 8);
            *(uint4*)&Bs[row][cc * 8] = *(const uint4*)&rootT[row * FIN + cc * 8];
        }
    }
    {
        constexpr int CHA = BM * FIN / 8;
        for (int c = tid; c < CHA; c += 256) {
            int row = c / (FIN / 8), cc = c % (FIN / 8);
            uint4 v = {0u, 0u, 0u, 0u};
            if (row < mcount) v = *(const uint4*)&X[(size_t)(n0 + row) * FIN + cc * 8];
            *(uint4*)&As[row][cc * 8] = v;
        }
    }
    __syncthreads();

    const int wave = tid >> 6;
    const int lane = tid & 63;
    const int q = lane >> 4;
    const int ln = lane & 15;
    constexpr int NT = HOUT / 16;
    constexpr int KS = FIN / 32;
    const int mbase = wave * 32;

    floatx4 acc[2][NT];
    #pragma unroll
    for (int a = 0; a < 2; a++)
        #pragma unroll
        for (int nt = 0; nt < NT; nt++) acc[a][nt] = floatx4{0.f, 0.f, 0.f, 0.f};

    for (int ks = 0; ks < KS; ks++) {
        int kk = ks * 32 + q * 8;
        short8 af0 = *(const short8*)&As[mbase + ln][kk];
        short8 af1 = *(const short8*)&As[mbase + 16 + ln][kk];
        #pragma unroll
        for (int nt = 0; nt < NT; nt++) {
            short8 bf = *(const short8*)&Bs[nt * 16 + ln][kk];
            acc[0][nt] = __builtin_amdgcn_mfma_f32_16x16x32_bf16(af0, bf, acc[0][nt], 0, 0, 0);
            acc[1][nt] = __builtin_amdgcn_mfma_f32_16x16x32_bf16(af1, bf, acc[1][nt], 0, 0, 0);
        }
    }

    #pragma unroll
    for (int mt = 0; mt < 2; mt++) {
        #pragma unroll
        for (int rr2 = 0; rr2 < 4; rr2++) {
            int i = mbase + mt * 16 + q * 4 + rr2;
            int n = n0 + i;
            if (i < mcount) {
                #pragma unroll
                for (int nt = 0; nt < NT; nt++)
                    O[(size_t)n * HOUT + nt * 16 + ln] = acc[mt][nt][rr2] + bias[nt * 16 + ln];
            }
        }
    }
}

// relation-grouped gather-GEMM with MFMA; tiles dispatched in src-octile-major
// order; A rows ascend in src within a tile (L2-resident gather). Epilogue
// writes unweighted bf16 msg rows to dst-sorted slots (full-line plain stores).
template <int FIN, int HOUT>
__launch_bounds__(256, (FIN == 128 ? 3 : 4))
__global__ void k_gemm(const unsigned short* __restrict__ X,
                       unsigned short* __restrict__ msg,
                       const int* __restrict__ perm, const int* __restrict__ off,
                       const int* __restrict__ tilR, const int* __restrict__ tilT,
                       const int* __restrict__ srcJ, const int* __restrict__ posDJ,
                       const unsigned short* __restrict__ WT) {
    int b = blockIdx.x;
    int r = tilR[b];
    if (r < 0) return;
    int t = tilT[b];
    int ebase = off[r] + t * BM;
    int mcount = min(BM, off[r + 1] - ebase);

    constexpr int LDK = FIN + 8;
    __shared__ unsigned short As[BM][LDK];
    __shared__ unsigned short Bs[HOUT][LDK];
    __shared__ int Sr[BM];
    __shared__ int Pd[BM];

    int tid = threadIdx.x;
    if (tid < BM) {
        if (tid < mcount) {
            int j = perm[ebase + tid];
            Sr[tid] = srcJ[j];
            Pd[tid] = posDJ[j];
        } else { Sr[tid] = -1; Pd[tid] = 0; }
    }
    __syncthreads();

    {
        const unsigned short* Wr = WT + (size_t)r * HOUT * FIN;
        constexpr int CHB = HOUT * FIN / 8;
        for (int c = tid; c < CHB; c += 256) {
            int row = c / (FIN / 8), cc = c % (FIN / 8);
            *(uint4*)&Bs[row][cc * 8] = *(const uint4*)&Wr[row * FIN + cc * 8];
        }
    }
    {
        constexpr int CHA = BM * FIN / 8;
        for (int c = tid; c < CHA; c += 256) {
            int row = c / (FIN / 8), cc = c % (FIN / 8);
            int s = Sr[row];
            uint4 v = {0u, 0u, 0u, 0u};
            if (s >= 0) v = *(const uint4*)&X[(size_t)s * FIN + cc * 8];
            *(uint4*)&As[row][cc * 8] = v;
        }
    }
    __syncthreads();

    const int wave = tid >> 6;
    const int lane = tid & 63;
    const int q = lane >> 4;
    const int ln = lane & 15;
    constexpr int NT = HOUT / 16;
    constexpr int KS = FIN / 32;
    const int mbase = wave * 32;

    floatx4 acc[2][NT];
    #pragma unroll
    for (int a = 0; a < 2; a++)
        #pragma unroll
        for (int nt = 0; nt < NT; nt++) acc[a][nt] = floatx4{0.f, 0.f, 0.f, 0.f};

    for (int ks = 0; ks < KS; ks++) {
        int kk = ks * 32 + q * 8;
        short8 af0 = *(const short8*)&As[mbase + ln][kk];
        short8 af1 = *(const short8*)&As[mbase + 16 + ln][kk];
        #pragma unroll
        for (int nt = 0; nt < NT; nt++) {
            short8 bf = *(const short8*)&Bs[nt * 16 + ln][kk];
            acc[0][nt] = __builtin_amdgcn_mfma_f32_16x16x32_bf16(af0, bf, acc[0][nt], 0, 0, 0);
            acc[1][nt] = __builtin_amdgcn_mfma_f32_16x16x32_bf16(af1, bf, acc[1][nt], 0, 0, 0);
        }
    }

    // epilogue: bf16 msgs through LDS (overlay As), coalesced full-line scatter
    __syncthreads();
    constexpr int LDM = HOUT + 8;
    unsigned short* Ms = &As[0][0];
    #pragma unroll
    for (int mt = 0; mt < 2; mt++) {
        #pragma unroll
        for (int rr2 = 0; rr2 < 4; rr2++) {
            int i = mbase + mt * 16 + q * 4 + rr2;
            #pragma unroll
            for (int nt = 0; nt < NT; nt++)
                Ms[i * LDM + nt * 16 + ln] = f2bf(acc[mt][nt][rr2]);
        }
    }
    __syncthreads();
    constexpr int CH = HOUT / 8;
    for (int c = tid; c < BM * CH; c += 256) {
        int row = c / CH, cc = c % CH;
        if (row < mcount)
            *(uint4*)&msg[(size_t)Pd[row] * HOUT + cc * 8] = *(const uint4*)&Ms[row * LDM + cc * 8];
    }
}

// weighted segment-sum of msg rows per dst + root base; optional relu+bf16.
template <int H, bool RELU>
__global__ void k_reduce(const unsigned short* __restrict__ msg,
                         const int* __restrict__ dstOff,
                         const float* __restrict__ wD,
                         float* __restrict__ base_io,
                         unsigned short* __restrict__ bfout) {
    int d = blockIdx.x * 4 + (threadIdx.x >> 6);
    if (d >= NN) return;
    int lane = threadIdx.x & 63;
    constexpr int HC = H / 4;
    constexpr int RPI = 64 / HC;
    int sub = lane / HC;
    int c4 = lane % HC;
    int j0 = dstOff[d], j1 = dstOff[d + 1];
    float a0 = 0.f, a1 = 0.f, a2 = 0.f, a3 = 0.f;
    for (int j = j0 + sub; j < j1; j += RPI) {
        float w = wD[j];
        uint2 v = *(const uint2*)&msg[(size_t)j * H + c4 * 4];
        a0 += w * bfbits2f(v.x << 16);
        a1 += w * bfbits2f(v.x & 0xffff0000u);
        a2 += w * bfbits2f(v.y << 16);
        a3 += w * bfbits2f(v.y & 0xffff0000u);
    }
    #pragma unroll
    for (int ofs = 32; ofs >= HC; ofs >>= 1) {
        a0 += __shfl_down(a0, ofs); a1 += __shfl_down(a1, ofs);
        a2 += __shfl_down(a2, ofs); a3 += __shfl_down(a3, ofs);
    }
    if (lane < HC) {
        size_t o = (size_t)d * H + c4 * 4;
        float v0 = base_io[o] + a0, v1 = base_io[o + 1] + a1;
        float v2 = base_io[o + 2] + a2, v3 = base_io[o + 3] + a3;
        if (RELU) {
            v0 = fmaxf(v0, 0.f); v1 = fmaxf(v1, 0.f);
            v2 = fmaxf(v2, 0.f); v3 = fmaxf(v3, 0.f);
        }
        base_io[o] = v0; base_io[o + 1] = v1; base_io[o + 2] = v2; base_io[o + 3] = v3;
        if (RELU) {
            bfout[o] = f2bf(v0); bfout[o + 1] = f2bf(v1);
            bfout[o + 2] = f2bf(v2); bfout[o + 3] = f2bf(v3);
        }
    }
}

// column sums of x2_o -> csum[32]
__global__ void k_mean(const float* __restrict__ x2o, float* csum) {
    __shared__ float s[256];
    int t = threadIdx.x; int hh = t & 31; int g = t >> 5;
    float acc = 0.f;
    for (int n = blockIdx.x * 8 + g; n < NN; n += gridDim.x * 8)
        acc += x2o[(size_t)n * 32 + hh];
    s[t] = acc;
    __syncthreads();
    if (t < 32) {
        float v = 0.f;
        for (int gg = 0; gg < 8; gg++) v += s[gg * 32 + t];
        unsafeAtomicAdd(&csum[t], v);
    }
}

// c = sigmoid(csum/N); v = disc_W @ c; bilinear scores
__global__ void k_disc(const float* __restrict__ x2o, const float* __restrict__ x2a,
                       const float* __restrict__ x2aa, const float* __restrict__ csum,
                       const float* __restrict__ discW, const float* __restrict__ discb,
                       float* ret_os, float* ret_osa) {
    __shared__ float c[32], v[32];
    int t = threadIdx.x;
    if (t < 32) c[t] = 1.f / (1.f + expf(-csum[t] * (1.f / NN)));
    __syncthreads();
    if (t < 32) {
        float a = 0.f;
        for (int j = 0; j < 32; j++) a += discW[t * 32 + j] * c[j];
        v[t] = a;
    }
    __syncthreads();
    float db = discb[0];
    int n = blockIdx.x * 256 + t;
    if (n < NN) {
        float s1 = 0.f, s2 = 0.f, s3 = 0.f;
        for (int j = 0; j < 32; j++) {
            float vj = v[j];
            s1 += x2o[(size_t)n * 32 + j] * vj;
            s2 += x2a[(size_t)n * 32 + j] * vj;
            s3 += x2aa[(size_t)n * 32 + j] * vj;
        }
        ret_os[n * 2] = s1 + db;  ret_os[n * 2 + 1] = s2 + db;
        ret_osa[n * 2] = s1 + db; ret_osa[n * 2 + 1] = s3 + db;
    }
}

// pair classifier as MFMA GEMM (K padded to 512, N padded to 80)
__launch_bounds__(256, 2)
__global__ void k_clsg(const float* __restrict__ h1o, const float* __restrict__ x2o,
                       const float* __restrict__ feat, const float* __restrict__ attt,
                       const int* __restrict__ idx,
                       const unsigned short* __restrict__ cwt,
                       const float* __restrict__ clsb, float* __restrict__ log_out) {
    constexpr int LDK = CLS_CK + 8;
    __shared__ unsigned short As[CLS_BM][LDK];
    __shared__ unsigned short Bs[CLS_N][LDK];
    __shared__ int nd[2][CLS_BM];

    int tid = threadIdx.x;
    int p0 = blockIdx.x * CLS_BM;
    if (tid < CLS_BM) {
        nd[0][tid] = idx[p0 + tid];
        nd[1][tid] = idx[BB + p0 + tid];
    }
    float a0 = attt[0], a1 = attt[1];

    const int wave = tid >> 6;
    const int lane = tid & 63;
    const int q = lane >> 4;
    const int ln = lane & 15;
    constexpr int NT = CLS_N / 16;
    const int mbase = wave * 16;

    floatx4 acc[NT];
    #pragma unroll
    for (int nt = 0; nt < NT; nt++) acc[nt] = floatx4{0.f, 0.f, 0.f, 0.f};

    for (int ch = 0; ch < CLS_K / CLS_CK; ch++) {
        int kbase = ch * CLS_CK;
        __syncthreads();
        for (int c = tid; c < CLS_N * CLS_CK / 8; c += 256) {
            int row = c / (CLS_CK / 8), cc = c % (CLS_CK / 8);
            *(uint4*)&Bs[row][cc * 8] = *(const uint4*)&cwt[(size_t)row * CLS_K + kbase + cc * 8];
        }
        for (int c = tid; c < CLS_BM * CLS_CK / 4; c += 256) {
            int row = c / (CLS_CK / 4);
            int j4 = (c % (CLS_CK / 4)) * 4;
            int j = kbase + j4;
            float4 v = {0.f, 0.f, 0.f, 0.f};
            if (j < 448) {
                int hseg = j / 224, jj = j % 224;
                int node = nd[hseg][row];
                if (jj < 64) {
                    v = *(const float4*)&h1o[(size_t)node * 64 + jj];
                    v.x *= a0; v.y *= a0; v.z *= a0; v.w *= a0;
                } else if (jj < 96) {
                    v = *(const float4*)&x2o[(size_t)node * 32 + (jj - 64)];
                    v.x *= a1; v.y *= a1; v.z *= a1; v.w *= a1;
                } else {
                    v = *(const float4*)&feat[(size_t)node * 128 + (jj - 96)];
                }
            }
            uint2 pk;
            pk.x = (unsigned)f2bf(v.x) | ((unsigned)f2bf(v.y) << 16);
            pk.y = (unsigned)f2bf(v.z) | ((unsigned)f2bf(v.w) << 16);
            *(uint2*)&As[row][j4] = pk;
        }
        __syncthreads();
        #pragma unroll
        for (int ks = 0; ks < CLS_CK / 32; ks++) {
            int kk = ks * 32 + q * 8;
            short8 af = *(const short8*)&As[mbase + ln][kk];
            #pragma unroll
            for (int nt = 0; nt < NT; nt++) {
                short8 bf = *(const short8*)&Bs[nt * 16 + ln][kk];
                acc[nt] = __builtin_amdgcn_mfma_f32_16x16x32_bf16(af, bf, acc[nt], 0, 0, 0);
            }
        }
    }

    #pragma unroll
    for (int rr2 = 0; rr2 < 4; rr2++) {
        int i = mbase + q * 4 + rr2;
        int pair = p0 + i;
        #pragma unroll
        for (int nt = 0; nt < NT; nt++) {
            int col = nt * 16 + ln;
            if (col < RR)
                log_out[(size_t)pair * RR + col] = acc[nt][rr2] + clsb[col];
        }
    }
}

extern "C" void kernel_launch(void* const* d_in, const int* in_sizes, int n_in,
                              void* d_out, int out_size, void* d_ws, size_t ws_size,
                              hipStream_t stream) {
    const float* x_o   = (const float*)d_in[0];
    const float* x_a   = (const float*)d_in[1];
    const float* feat  = (const float*)d_in[2];
    const float* W1    = (const float*)d_in[3];
    const float* root1 = (const float*)d_in[4];
    const float* b1    = (const float*)d_in[5];
    const float* W2    = (const float*)d_in[6];
    const float* root2 = (const float*)d_in[7];
    const float* b2    = (const float*)d_in[8];
    const float* attt  = (const float*)d_in[9];
    const float* discW = (const float*)d_in[10];
    const float* discb = (const float*)d_in[11];
    const float* clsW  = (const float*)d_in[12];
    const float* clsb  = (const float*)d_in[13];
    const int* ei      = (const int*)d_in[14];
    const int* et0     = (const int*)d_in[15];
    const int* et1     = (const int*)d_in[16];
    const int* idx     = (const int*)d_in[17];

    char* ws = (char*)d_ws;
    float* csum = (float*)(ws + OFF_CSUM);
    int* cntS  = (int*)(ws + OFF_CNTS);
    int* cntD  = (int*)(ws + OFF_CNTD);
    int* curS  = (int*)(ws + OFF_CURS);
    int* curD  = (int*)(ws + OFF_CURD);
    int* srcOff = (int*)(ws + OFF_SRCOFF);
    int* dstOff = (int*)(ws + OFF_DSTOFF);
    int* bh0   = (int*)(ws + OFF_BH0);
    int* bh1   = (int*)(ws + OFF_BH1);
    int* bb0   = (int*)(ws + OFF_BB0);
    int* bb1   = (int*)(ws + OFF_BB1);
    int* off0  = (int*)(ws + OFF_OFF0);
    int* off1  = (int*)(ws + OFF_OFF1);
    int* tilR0 = (int*)(ws + OFF_TILR0);
    int* tilT0 = (int*)(ws + OFF_TILT0);
    int* tilR1 = (int*)(ws + OFF_TILR1);
    int* tilT1 = (int*)(ws + OFF_TILT1);
    int* srcJ  = (int*)(ws + OFF_SRCJ);
    unsigned int* rsJ = (unsigned int*)(ws + OFF_RSJ);
    int* posDJ = (int*)(ws + OFF_POSDJ);
    unsigned int* rdP = (unsigned int*)(ws + OFF_RDP);
    float* wD0 = (float*)(ws + OFF_WD0);
    float* wD1 = (float*)(ws + OFF_WD1);
    int* perm0 = (int*)(ws + OFF_PERM0);
    int* perm1 = (int*)(ws + OFF_PERM1);
    unsigned short* xob = (unsigned short*)(ws + OFF_XOB);
    unsigned short* xab = (unsigned short*)(ws + OFF_XAB);
    float* h1o  = (float*)(ws + OFF_H1);
    float* h1a  = h1o + (size_t)NN * HH1;
    float* h1aa = h1a + (size_t)NN * HH1;
    unsigned short* h1bo  = (unsigned short*)(ws + OFF_H1B);
    unsigned short* h1ba  = h1bo + (size_t)NN * HH1;
    unsigned short* h1baa = h1ba + (size_t)NN * HH1;
    float* x2a  = (float*)(ws + OFF_X2A);
    float* x2aa = (float*)(ws + OFF_X2AA);
    unsigned short* w1t = (unsigned short*)(ws + OFF_W1BT);
    unsigned short* w2t = (unsigned short*)(ws + OFF_W2BT);
    unsigned short* r1t = (unsigned short*)(ws + OFF_R1T);
    unsigned short* r2t = (unsigned short*)(ws + OFF_R2T);
    unsigned short* cwt = (unsigned short*)(ws + OFF_CWT);
    unsigned short* msg = (unsigned short*)(ws + OFF_MSG);

    float* out = (float*)d_out;
    float* log_out = out + O_LOG;
    float* ret_os  = out + O_ROS;
    float* ret_osa = out + O_ROSA;
    float* x2o     = out + O_X2O;

    // 1) zero control block (csum + cntS/cntD/curS/curD) — ~320 KB
    hipMemsetAsync(ws, 0, ZERO_BYTES, stream);

    // 2) preprocessing: src/dst CSRs, src-sorted relabel, relation sort,
    //    octile-major tile tables, pos-space weights
    k_hist<<<NBH, 256, 0, stream>>>(ei, cntS, cntD,
                                    x_o, x_a, W1, W2, root1, root2, clsW,
                                    xob, xab, w1t, w2t, r1t, r2t, cwt);
    k_scanSD<<<1, 256, 0, stream>>>(cntS, cntD, srcOff, dstOff);
    k_orderS<<<2500, 256, 0, stream>>>(ei, et0, et1, srcOff, dstOff,
                                       curS, curD, srcJ, rsJ, posDJ, rdP);
    k_histR<<<NBH, 256, 0, stream>>>(rsJ, bh0, bh1);
    k_scanR<<<1, 256, 0, stream>>>(bh0, bh1, bb0, bb1, off0, off1,
                                   tilR0, tilT0, tilR1, tilT1);
    k_fillR<<<NBH, 256, 0, stream>>>(rsJ, off0, off1, bb0, bb1, perm0, perm1);
    k_wts<<<NN / 4, 256, 0, stream>>>(dstOff, rdP, wD0, wD1);

    // 3) layer 1: MFMA root GEMM + per-encoding (edge GEMM -> weighted reduce)
    {
        dim3 gb(NBT, 3);
        k_bgemm<FIN1, HH1><<<gb, 256, 0, stream>>>(xob, xab, xob, r1t, b1,
                                                   h1o, h1a, h1aa);
        const unsigned short* Xs[3] = {xob, xab, xob};
        float* Os[3] = {h1o, h1a, h1aa};
        unsigned short* Obs[3] = {h1bo, h1ba, h1baa};
        for (int enc = 0; enc < 3; enc++) {
            const int* perm = enc == 2 ? perm1 : perm0;
            const int* off  = enc == 2 ? off1 : off0;
            const int* tilR = enc == 2 ? tilR1 : tilR0;
            const int* tilT = enc == 2 ? tilT1 : tilT0;
            const float* wD = enc == 2 ? wD1 : wD0;
            k_gemm<FIN1, HH1><<<MAXT, 256, 0, stream>>>(Xs[enc], msg, perm, off,
                                                        tilR, tilT, srcJ, posDJ, w1t);
            k_reduce<HH1, true><<<NN / 4, 256, 0, stream>>>(msg, dstOff, wD,
                                                            Os[enc], Obs[enc]);
        }
    }

    // 4) layer 2: MFMA root GEMM + per-encoding (edge GEMM -> weighted reduce)
    {
        dim3 gb(NBT, 3);
        k_bgemm<HH1, HH2><<<gb, 256, 0, stream>>>(h1bo, h1ba, h1baa, r2t, b2,
                                                  x2o, x2a, x2aa);
        const unsigned short* Xs[3] = {h1bo, h1ba, h1baa};
        float* Os[3] = {x2o, x2a, x2aa};
        for (int enc = 0; enc < 3; enc++) {
            const int* perm = enc == 2 ? perm1 : perm0;
            const int* off  = enc == 2 ? off1 : off0;
            const int* tilR = enc == 2 ? tilR1 : tilR0;
            const int* tilT = enc == 2 ? tilT1 : tilT0;
            const float* wD = enc == 2 ? wD1 : wD0;
            k_gemm<HH1, HH2><<<MAXT, 256, 0, stream>>>(Xs[enc], msg, perm, off,
                                                       tilR, tilT, srcJ, posDJ, w2t);
            k_reduce<HH2, false><<<NN / 4, 256, 0, stream>>>(msg, dstOff, wD,
                                                             Os[enc], nullptr);
        }
    }

    // 5) readout + discriminator + classifier
    k_mean<<<256, 256, 0, stream>>>(x2o, csum);
    k_disc<<<(NN + 255) / 256, 256, 0, stream>>>(x2o, x2a, x2aa, csum, discW, discb,
                                                 ret_os, ret_osa);
    k_clsg<<<BB / CLS_BM, 256, 0, stream>>>(h1o, x2o, feat, attt, idx, cwt, clsb, log_out);
}

// Round 9
// 788.499 us; speedup vs baseline: 1.2764x; 1.0290x over previous
//
#include <hip/hip_runtime.h>
#include <hip/hip_bf16.h>

// ---------------- problem constants ----------------
#define NN 20000      // nodes
#define EE 640000     // edges
#define RR 65         // relations
#define FIN1 128      // input feat
#define HH1 64        // hidden1
#define HH2 32        // hidden2
#define BB 8192       // pairs

constexpr int BM = 128;                 // edge-tile rows per GEMM block
constexpr int NBH = 256;                // histogram/placement blocks
constexpr int EPB = EE / NBH;           // 2500 edges per block
constexpr int NBT = (NN + BM - 1) / BM; // 157 node tiles
constexpr int NOCT = 8;                 // src octiles (nodes per octile = 2500)
constexpr int NPO = NN / NOCT;          // 2500
constexpr int NB2 = NOCT * RR;          // 520 sort buckets (octile-major, relation inner)
constexpr int MAXT2 = EE / BM + NB2;    // 5520 tile upper bound

// classifier GEMM geometry (E[8192x448] @ clsW[448x65], padded)
constexpr int CLS_K  = 512;
constexpr int CLS_N  = 80;
constexpr int CLS_CK = 128;
constexpr int CLS_BM = 64;

typedef __attribute__((ext_vector_type(8))) short short8;   // 8 bf16 MFMA frag
typedef __attribute__((ext_vector_type(4))) float floatx4;  // 4 fp32 acc

// ---------------- workspace layout (bytes) ----------------
constexpr size_t aln(size_t x) { return (x + 255) & ~(size_t)255; }

constexpr size_t OFF_CSUM  = 0;                        // 32 f
constexpr size_t OFF_CNTD  = aln(OFF_CSUM + 32 * 4);  // NN int (dst degree)
constexpr size_t ZERO_BYTES = OFF_CNTD + (size_t)NN * 4;   // memset [0, ZERO_BYTES)
constexpr size_t OFF_DSTOFF = aln(ZERO_BYTES);         // NN+1 int
constexpr size_t OFF_BH0   = aln(OFF_DSTOFF + ((size_t)NN + 1) * 4); // NBH*NB2
constexpr size_t OFF_BH1   = OFF_BH0 + (size_t)NBH * NB2 * 4;
constexpr size_t OFF_BB0   = OFF_BH1 + (size_t)NBH * NB2 * 4;
constexpr size_t OFF_BB1   = OFF_BB0 + (size_t)NBH * NB2 * 4;
constexpr size_t OFF_OFFB0 = aln(OFF_BB1 + (size_t)NBH * NB2 * 4);   // NB2+1 int
constexpr size_t OFF_OFFB1 = OFF_OFFB0 + (NB2 + 1) * 4;
constexpr size_t OFF_TILB0 = aln(OFF_OFFB1 + (NB2 + 1) * 4);  // MAXT2 int
constexpr size_t OFF_TILT0 = OFF_TILB0 + (size_t)MAXT2 * 4;
constexpr size_t OFF_TILB1 = OFF_TILT0 + (size_t)MAXT2 * 4;
constexpr size_t OFF_TILT1 = OFF_TILB1 + (size_t)MAXT2 * 4;
constexpr size_t OFF_SLOT  = aln(OFF_TILT1 + (size_t)MAXT2 * 4);  // E int
constexpr size_t OFF_POSD  = OFF_SLOT + (size_t)EE * 4;           // E int (e -> dst pos)
constexpr size_t OFF_RDP   = OFF_POSD + (size_t)EE * 4;           // E uint (pos -> r0|r1<<16)
constexpr size_t OFF_WD0   = OFF_RDP + (size_t)EE * 4;            // E float (pos-space weights)
constexpr size_t OFF_WD1   = OFF_WD0 + (size_t)EE * 4;
constexpr size_t OFF_PERM0 = OFF_WD1 + (size_t)EE * 4;            // E int (stores e)
constexpr size_t OFF_PERM1 = OFF_PERM0 + (size_t)EE * 4;
constexpr size_t OFF_XOB   = aln(OFF_PERM1 + (size_t)EE * 4);     // N*F bf16
constexpr size_t OFF_XAB   = OFF_XOB + (size_t)NN * FIN1 * 2;
constexpr size_t OFF_H1    = aln(OFF_XAB + (size_t)NN * FIN1 * 2); // 3 * N*64 f
constexpr size_t OFF_H1B   = OFF_H1 + (size_t)3 * NN * HH1 * 4;    // 3 * N*64 bf16
constexpr size_t OFF_X2A   = OFF_H1B + (size_t)3 * NN * HH1 * 2;   // N*32 f
constexpr size_t OFF_X2AA  = OFF_X2A + (size_t)NN * HH2 * 4;
constexpr size_t OFF_W1BT  = OFF_X2AA + (size_t)NN * HH2 * 4;      // R*64*128 bf16
constexpr size_t OFF_W2BT  = OFF_W1BT + (size_t)RR * HH1 * FIN1 * 2;
constexpr size_t OFF_R1T   = OFF_W2BT + (size_t)RR * HH2 * HH1 * 2;
constexpr size_t OFF_R2T   = OFF_R1T + (size_t)HH1 * FIN1 * 2;
constexpr size_t OFF_CWT   = OFF_R2T + (size_t)HH2 * HH1 * 2;
constexpr size_t OFF_MSG   = aln(OFF_CWT + (size_t)CLS_N * CLS_K * 2); // E*64 bf16
constexpr size_t WS_END    = OFF_MSG + (size_t)EE * HH1 * 2;

// output offsets (floats)
constexpr size_t O_LOG  = 0;
constexpr size_t O_ROS  = (size_t)BB * RR;
constexpr size_t O_ROSA = O_ROS + (size_t)NN * 2;
constexpr size_t O_X2O  = O_ROSA + (size_t)NN * 2;

__device__ inline unsigned short f2bf(float f) {
    __hip_bfloat16 h = __float2bfloat16(f);
    return *reinterpret_cast<unsigned short*>(&h);
}
__device__ inline float bfbits2f(unsigned int hi_bits) {
    return __uint_as_float(hi_bits);
}

// ---------------- preprocessing ----------------
// per-block 520-bin (octile,relation) histograms via LDS -> plain stores,
// per-dst degree + slot (benign 20k-addr scatter atomic, sequential slot write),
// fused bf16 conversions. No j-space, no scattered metadata writes.
__global__ void k_hist(const int* __restrict__ ei, const int* __restrict__ et0,
                       const int* __restrict__ et1,
                       int* cntD, int* __restrict__ slotE,
                       int* __restrict__ bh0, int* __restrict__ bh1,
                       const float* __restrict__ x_o, const float* __restrict__ x_a,
                       const float* __restrict__ W1, const float* __restrict__ W2,
                       const float* __restrict__ root1, const float* __restrict__ root2,
                       const float* __restrict__ clsW,
                       unsigned short* xob, unsigned short* xab,
                       unsigned short* w1t, unsigned short* w2t,
                       unsigned short* r1t, unsigned short* r2t,
                       unsigned short* cwt) {
    __shared__ int lh0[NB2], lh1[NB2];
    int t = threadIdx.x;
    for (int p = t; p < NB2; p += 256) { lh0[p] = 0; lh1[p] = 0; }
    __syncthreads();
    int base = blockIdx.x * EPB;
    for (int i = t; i < EPB; i += 256) {
        int e = base + i;
        int oct = ei[e] / NPO;
        atomicAdd(&lh0[oct * RR + et0[e]], 1);
        atomicAdd(&lh1[oct * RR + et1[e]], 1);
        slotE[e] = atomicAdd(&cntD[ei[EE + e]], 1);
    }
    __syncthreads();
    for (int p = t; p < NB2; p += 256) {
        bh0[blockIdx.x * NB2 + p] = lh0[p];
        bh1[blockIdx.x * NB2 + p] = lh1[p];
    }
    // streaming conversions (grid-stride over 256-block grid)
    int stride = gridDim.x * 256;
    int i0 = blockIdx.x * 256 + t;
    const int NX = NN * FIN1;
    for (int i = i0; i < NX; i += stride) { xob[i] = f2bf(x_o[i]); xab[i] = f2bf(x_a[i]); }
    const int NW1 = RR * HH1 * FIN1;
    for (int i = i0; i < NW1; i += stride) {
        int k = i % FIN1; int rh = i / FIN1; int hh = rh % HH1; int r = rh / HH1;
        w1t[i] = f2bf(W1[((size_t)r * FIN1 + k) * HH1 + hh]);
    }
    const int NW2 = RR * HH2 * HH1;
    for (int i = i0; i < NW2; i += stride) {
        int k = i % HH1; int rh = i / HH1; int hh = rh % HH2; int r = rh / HH2;
        w2t[i] = f2bf(W2[((size_t)r * HH1 + k) * HH2 + hh]);
    }
    const int NR1 = HH1 * FIN1;
    for (int i = i0; i < NR1; i += stride) {
        int k = i % FIN1; int hh = i / FIN1;
        r1t[i] = f2bf(root1[(size_t)k * HH1 + hh]);
    }
    const int NR2 = HH2 * HH1;
    for (int i = i0; i < NR2; i += stride) {
        int k = i % HH1; int hh = i / HH1;
        r2t[i] = f2bf(root2[(size_t)k * HH2 + hh]);
    }
    const int NCW = CLS_N * CLS_K;
    for (int i = i0; i < NCW; i += stride) {
        int k = i % CLS_K; int n = i / CLS_K;
        cwt[i] = (n < RR && k < 448) ? f2bf(clsW[(size_t)k * RR + n]) : (unsigned short)0;
    }
}

// exclusive scan of per-dst degrees -> dstOff[NN+1] (single block)
__global__ void k_scanD(const int* __restrict__ cntD, int* __restrict__ dstOff) {
    __shared__ int s[256];
    int t = threadIdx.x;
    constexpr int PER = (NN + 255) / 256;
    int lo = t * PER, hi = min(NN, lo + PER);
    int sum = 0;
    for (int i = lo; i < hi; i++) sum += cntD[i];
    s[t] = sum;
    __syncthreads();
    for (int ofs = 1; ofs < 256; ofs <<= 1) {
        int v = 0;
        if (t >= ofs) v = s[t - ofs];
        __syncthreads();
        if (t >= ofs) s[t] += v;
        __syncthreads();
    }
    int run = s[t] - sum;
    for (int i = lo; i < hi; i++) { dstOff[i] = run; run += cntD[i]; }
    if (t == 255) dstOff[NN] = run;
}

// per-bucket scan over blocks (coalesced: consecutive threads = consecutive
// buckets) -> block bases + bucket offsets + tile tables. Fully parallel.
__global__ void k_scanB(const int* __restrict__ bh0, const int* __restrict__ bh1,
                        int* __restrict__ bb0, int* __restrict__ bb1,
                        int* offB0, int* offB1,
                        int* tilB0, int* tilT0, int* tilB1, int* tilT1) {
    __shared__ int h[2][NB2];
    __shared__ int o[2][NB2 + 1];
    __shared__ int to[2][NB2 + 1];
    __shared__ int csumE[2][8], csumT[2][8];
    int t = threadIdx.x;
    // 1) per-bucket block-base scan
    for (int p = t; p < 2 * NB2; p += 256) {
        int s = p / NB2, k = p % NB2;
        const int* bh = s ? bh1 : bh0;
        int* bb = s ? bb1 : bb0;
        int run = 0;
        for (int b = 0; b < NBH; b++) {
            bb[b * NB2 + k] = run;
            run += bh[b * NB2 + k];
        }
        h[s][k] = run;
    }
    __syncthreads();
    // 2) chunked exclusive scans (edges and tiles), 8 chunks of RR bins each
    if (t < 16) {
        int s = t / 8, c = t % 8;
        int runE = 0, runT = 0;
        for (int k = c * RR; k < (c + 1) * RR; k++) {
            o[s][k] = runE;  runE += h[s][k];
            to[s][k] = runT; runT += (h[s][k] + BM - 1) / BM;
        }
        csumE[s][c] = runE; csumT[s][c] = runT;
    }
    __syncthreads();
    if (t < 2) {
        int runE = 0, runT = 0;
        for (int c = 0; c < 8; c++) {
            int e = csumE[t][c], tt = csumT[t][c];
            csumE[t][c] = runE; csumT[t][c] = runT;
            runE += e; runT += tt;
        }
        o[t][NB2] = runE; to[t][NB2] = runT;
    }
    __syncthreads();
    if (t < 16) {
        int s = t / 8, c = t % 8;
        for (int k = c * RR; k < (c + 1) * RR; k++) {
            o[s][k] += csumE[s][c];
            to[s][k] += csumT[s][c];
        }
    }
    __syncthreads();
    for (int p = t; p <= NB2; p += 256) { offB0[p] = o[0][p]; offB1[p] = o[1][p]; }
    // 3) emit tile tables: 256 threads, binary search over LDS tile offsets
    for (int i = t; i < MAXT2; i += 256) {
        #pragma unroll
        for (int s = 0; s < 2; s++) {
            int total = to[s][NB2];
            int bkt = -1, ti = 0;
            if (i < total) {
                int lo = 0, hi = NB2;
                while (hi - lo > 1) { int mid = (lo + hi) >> 1; if (to[s][mid] <= i) lo = mid; else hi = mid; }
                bkt = lo;
                ti = i - to[s][lo];
            }
            if (s == 0) { tilB0[i] = bkt; tilT0[i] = ti; }
            else        { tilB1[i] = bkt; tilT1[i] = ti; }
        }
    }
}

// bucket-sorted perm placement with deterministic bases; perm stores e.
__global__ void k_fillB(const int* __restrict__ ei, const int* __restrict__ et0,
                        const int* __restrict__ et1,
                        const int* __restrict__ offB0, const int* __restrict__ offB1,
                        const int* __restrict__ bb0, const int* __restrict__ bb1,
                        int* perm0, int* perm1) {
    __shared__ int lc[2][NB2];
    __shared__ int lb[2][NB2];
    int t = threadIdx.x;
    for (int p = t; p < NB2; p += 256) {
        lc[0][p] = 0; lc[1][p] = 0;
        lb[0][p] = offB0[p] + bb0[blockIdx.x * NB2 + p];
        lb[1][p] = offB1[p] + bb1[blockIdx.x * NB2 + p];
    }
    __syncthreads();
    int base = blockIdx.x * EPB;
    for (int i = t; i < EPB; i += 256) {
        int e = base + i;
        int oct = ei[e] / NPO;
        int k0 = oct * RR + et0[e];
        int k1 = oct * RR + et1[e];
        int p0 = atomicAdd(&lc[0][k0], 1);
        int p1 = atomicAdd(&lc[1][k1], 1);
        perm0[lb[0][k0] + p0] = e;
        perm1[lb[1][k1] + p1] = e;
    }
}

// posD (sequential write) + rdP (the single scattered-write array)
__global__ void k_post(const int* __restrict__ ei, const int* __restrict__ et0,
                       const int* __restrict__ et1, const int* __restrict__ dstOff,
                       const int* __restrict__ slotE,
                       int* __restrict__ posD, unsigned int* __restrict__ rdP) {
    int e = blockIdx.x * 256 + threadIdx.x;
    if (e < EE) {
        int d = ei[EE + e];
        int pos = dstOff[d] + slotE[e];
        posD[e] = pos;
        rdP[pos] = (unsigned)et0[e] | ((unsigned)et1[e] << 16);
    }
}

// per-(relation,dst) mean weights inside each dst segment -> pos-space arrays
__global__ void k_wts(const int* __restrict__ dstOff, const unsigned int* __restrict__ rdP,
                      float* __restrict__ wD0, float* __restrict__ wD1) {
    constexpr int CAP = 96;
    __shared__ unsigned int ld[4][CAP];
    int wave = threadIdx.x >> 6;
    int lane = threadIdx.x & 63;
    int d = blockIdx.x * 4 + wave;
    int j0 = 0, deg = 0;
    if (d < NN) { j0 = dstOff[d]; deg = dstOff[d + 1] - j0; }
    for (int j = lane; j < deg && j < CAP; j += 64) ld[wave][j] = rdP[j0 + j];
    __syncthreads();
    for (int j = lane; j < deg; j += 64) {
        unsigned int my = (j < CAP) ? ld[wave][j] : rdP[j0 + j];
        unsigned int m0 = my & 0xffffu, m1 = my >> 16;
        int c0 = 0, c1 = 0;
        for (int k = 0; k < deg; k++) {
            unsigned int p = (k < CAP) ? ld[wave][k] : rdP[j0 + k];
            c0 += ((p & 0xffffu) == m0);
            c1 += ((p >> 16) == m1);
        }
        wD0[j0 + j] = 1.0f / (float)c0;
        wD1[j0 + j] = 1.0f / (float)c1;
    }
}

// root-term GEMM via MFMA: O[n,h] = Xb[n,:] @ rootT[h,:] + bias[h]  (fp32 out)
template <int FIN, int HOUT>
__launch_bounds__(256, 3)
__global__ void k_bgemm(const unsigned short* __restrict__ X0,
                        const unsigned short* __restrict__ X1,
                        const unsigned short* __restrict__ X2,
                        const unsigned short* __restrict__ rootT,
                        const float* __restrict__ bias,
                        float* O0, float* O1, float* O2) {
    const int enc = blockIdx.y;
    const unsigned short* X = enc == 0 ? X0 : enc == 1 ? X1 : X2;
    float* O = enc == 0 ? O0 : enc == 1 ? O1 : O2;
    int n0 = blockIdx.x * BM;
    int mcount = min(BM, NN - n0);

    constexpr int LDK = FIN + 8;
    __shared__ unsigned short As[BM][LDK];
    __shared__ unsigned short Bs[HOUT][LDK];

    int tid = threadIdx.x;
    {
        constexpr int CHB = HOUT * FIN / 8;
        for (int c = tid; c < CHB; c += 256) {
            int row = c / (FIN / 8), cc = c % (FIN / 8);
            *(uint4*)&Bs[row][cc * 8] = *(const uint4*)&rootT[row * FIN + cc * 8];
        }
    }
    {
        constexpr int CHA = BM * FIN / 8;
        for (int c = tid; c < CHA; c += 256) {
            int row = c / (FIN / 8), cc = c % (FIN / 8);
            uint4 v = {0u, 0u, 0u, 0u};
            if (row < mcount) v = *(const uint4*)&X[(size_t)(n0 + row) * FIN + cc * 8];
            *(uint4*)&As[row][cc * 8] = v;
        }
    }
    __syncthreads();

    const int wave = tid >> 6;
    const int lane = tid & 63;
    const int q = lane >> 4;
    const int ln = lane & 15;
    constexpr int NT = HOUT / 16;
    constexpr int KS = FIN / 32;
    const int mbase = wave * 32;

    floatx4 acc[2][NT];
    #pragma unroll
    for (int a = 0; a < 2; a++)
        #pragma unroll
        for (int nt = 0; nt < NT; nt++) acc[a][nt] = floatx4{0.f, 0.f, 0.f, 0.f};

    for (int ks = 0; ks < KS; ks++) {
        int kk = ks * 32 + q * 8;
        short8 af0 = *(const short8*)&As[mbase + ln][kk];
        short8 af1 = *(const short8*)&As[mbase + 16 + ln][kk];
        #pragma unroll
        for (int nt = 0; nt < NT; nt++) {
            short8 bf = *(const short8*)&Bs[nt * 16 + ln][kk];
            acc[0][nt] = __builtin_amdgcn_mfma_f32_16x16x32_bf16(af0, bf, acc[0][nt], 0, 0, 0);
            acc[1][nt] = __builtin_amdgcn_mfma_f32_16x16x32_bf16(af1, bf, acc[1][nt], 0, 0, 0);
        }
    }

    #pragma unroll
    for (int mt = 0; mt < 2; mt++) {
        #pragma unroll
        for (int rr2 = 0; rr2 < 4; rr2++) {
            int i = mbase + mt * 16 + q * 4 + rr2;
            int n = n0 + i;
            if (i < mcount) {
                #pragma unroll
                for (int nt = 0; nt < NT; nt++)
                    O[(size_t)n * HOUT + nt * 16 + ln] = acc[mt][nt][rr2] + bias[nt * 16 + ln];
            }
        }
    }
}

// bucket-grouped gather-GEMM with MFMA; tiles dispatched (src-octile, relation)
// major so concurrent blocks gather from one ~640 KB L2-resident X window.
// Epilogue writes unweighted bf16 msg rows to dst-sorted slots (plain stores).
template <int FIN, int HOUT>
__launch_bounds__(256, (FIN == 128 ? 3 : 4))
__global__ void k_gemm(const unsigned short* __restrict__ X,
                       unsigned short* __restrict__ msg,
                       const int* __restrict__ perm, const int* __restrict__ offB,
                       const int* __restrict__ tilB, const int* __restrict__ tilT,
                       const int* __restrict__ ei, const int* __restrict__ posD,
                       const unsigned short* __restrict__ WT) {
    int b = blockIdx.x;
    int bkt = tilB[b];
    if (bkt < 0) return;
    int r = bkt % RR;
    int t = tilT[b];
    int ebase = offB[bkt] + t * BM;
    int mcount = min(BM, offB[bkt + 1] - ebase);

    constexpr int LDK = FIN + 8;
    __shared__ unsigned short As[BM][LDK];
    __shared__ unsigned short Bs[HOUT][LDK];
    __shared__ int Sr[BM];
    __shared__ int Pd[BM];

    int tid = threadIdx.x;
    if (tid < BM) {
        if (tid < mcount) {
            int e = perm[ebase + tid];
            Sr[tid] = ei[e];
            Pd[tid] = posD[e];
        } else { Sr[tid] = -1; Pd[tid] = 0; }
    }
    __syncthreads();

    {
        const unsigned short* Wr = WT + (size_t)r * HOUT * FIN;
        constexpr int CHB = HOUT * FIN / 8;
        for (int c = tid; c < CHB; c += 256) {
            int row = c / (FIN / 8), cc = c % (FIN / 8);
            *(uint4*)&Bs[row][cc * 8] = *(const uint4*)&Wr[row * FIN + cc * 8];
        }
    }
    {
        constexpr int CHA = BM * FIN / 8;
        for (int c = tid; c < CHA; c += 256) {
            int row = c / (FIN / 8), cc = c % (FIN / 8);
            int s = Sr[row];
            uint4 v = {0u, 0u, 0u, 0u};
            if (s >= 0) v = *(const uint4*)&X[(size_t)s * FIN + cc * 8];
            *(uint4*)&As[row][cc * 8] = v;
        }
    }
    __syncthreads();

    const int wave = tid >> 6;
    const int lane = tid & 63;
    const int q = lane >> 4;
    const int ln = lane & 15;
    constexpr int NT = HOUT / 16;
    constexpr int KS = FIN / 32;
    const int mbase = wave * 32;

    floatx4 acc[2][NT];
    #pragma unroll
    for (int a = 0; a < 2; a++)
        #pragma unroll
        for (int nt = 0; nt < NT; nt++) acc[a][nt] = floatx4{0.f, 0.f, 0.f, 0.f};

    for (int ks = 0; ks < KS; ks++) {
        int kk = ks * 32 + q * 8;
        short8 af0 = *(const short8*)&As[mbase + ln][kk];
        short8 af1 = *(const short8*)&As[mbase + 16 + ln][kk];
        #pragma unroll
        for (int nt = 0; nt < NT; nt++) {
            short8 bf = *(const short8*)&Bs[nt * 16 + ln][kk];
            acc[0][nt] = __builtin_amdgcn_mfma_f32_16x16x32_bf16(af0, bf, acc[0][nt], 0, 0, 0);
            acc[1][nt] = __builtin_amdgcn_mfma_f32_16x16x32_bf16(af1, bf, acc[1][nt], 0, 0, 0);
        }
    }

    // epilogue: bf16 msgs through LDS (overlay As), coalesced full-line scatter
    __syncthreads();
    constexpr int LDM = HOUT + 8;
    unsigned short* Ms = &As[0][0];
    #pragma unroll
    for (int mt = 0; mt < 2; mt++) {
        #pragma unroll
        for (int rr2 = 0; rr2 < 4; rr2++) {
            int i = mbase + mt * 16 + q * 4 + rr2;
            #pragma unroll
            for (int nt = 0; nt < NT; nt++)
                Ms[i * LDM + nt * 16 + ln] = f2bf(acc[mt][nt][rr2]);
        }
    }
    __syncthreads();
    constexpr int CH = HOUT / 8;
    for (int c = tid; c < BM * CH; c += 256) {
        int row = c / CH, cc = c % CH;
        if (row < mcount)
            *(uint4*)&msg[(size_t)Pd[row] * HOUT + cc * 8] = *(const uint4*)&Ms[row * LDM + cc * 8];
    }
}

// weighted segment-sum of msg rows per dst + root base; optional relu+bf16.
template <int H, bool RELU>
__global__ void k_reduce(const unsigned short* __restrict__ msg,
                         const int* __restrict__ dstOff,
                         const float* __restrict__ wD,
                         float* __restrict__ base_io,
                         unsigned short* __restrict__ bfout) {
    int d = blockIdx.x * 4 + (threadIdx.x >> 6);
    if (d >= NN) return;
    int lane = threadIdx.x & 63;
    constexpr int HC = H / 4;
    constexpr int RPI = 64 / HC;
    int sub = lane / HC;
    int c4 = lane % HC;
    int j0 = dstOff[d], j1 = dstOff[d + 1];
    float a0 = 0.f, a1 = 0.f, a2 = 0.f, a3 = 0.f;
    for (int j = j0 + sub; j < j1; j += RPI) {
        float w = wD[j];
        uint2 v = *(const uint2*)&msg[(size_t)j * H + c4 * 4];
        a0 += w * bfbits2f(v.x << 16);
        a1 += w * bfbits2f(v.x & 0xffff0000u);
        a2 += w * bfbits2f(v.y << 16);
        a3 += w * bfbits2f(v.y & 0xffff0000u);
    }
    #pragma unroll
    for (int ofs = 32; ofs >= HC; ofs >>= 1) {
        a0 += __shfl_down(a0, ofs); a1 += __shfl_down(a1, ofs);
        a2 += __shfl_down(a2, ofs); a3 += __shfl_down(a3, ofs);
    }
    if (lane < HC) {
        size_t o = (size_t)d * H + c4 * 4;
        float v0 = base_io[o] + a0, v1 = base_io[o + 1] + a1;
        float v2 = base_io[o + 2] + a2, v3 = base_io[o + 3] + a3;
        if (RELU) {
            v0 = fmaxf(v0, 0.f); v1 = fmaxf(v1, 0.f);
            v2 = fmaxf(v2, 0.f); v3 = fmaxf(v3, 0.f);
        }
        base_io[o] = v0; base_io[o + 1] = v1; base_io[o + 2] = v2; base_io[o + 3] = v3;
        if (RELU) {
            bfout[o] = f2bf(v0); bfout[o + 1] = f2bf(v1);
            bfout[o + 2] = f2bf(v2); bfout[o + 3] = f2bf(v3);
        }
    }
}

// column sums of x2_o -> csum[32]
__global__ void k_mean(const float* __restrict__ x2o, float* csum) {
    __shared__ float s[256];
    int t = threadIdx.x; int hh = t & 31; int g = t >> 5;
    float acc = 0.f;
    for (int n = blockIdx.x * 8 + g; n < NN; n += gridDim.x * 8)
        acc += x2o[(size_t)n * 32 + hh];
    s[t] = acc;
    __syncthreads();
    if (t < 32) {
        float v = 0.f;
        for (int gg = 0; gg < 8; gg++) v += s[gg * 32 + t];
        unsafeAtomicAdd(&csum[t], v);
    }
}

// c = sigmoid(csum/N); v = disc_W @ c; bilinear scores
__global__ void k_disc(const float* __restrict__ x2o, const float* __restrict__ x2a,
                       const float* __restrict__ x2aa, const float* __restrict__ csum,
                       const float* __restrict__ discW, const float* __restrict__ discb,
                       float* ret_os, float* ret_osa) {
    __shared__ float c[32], v[32];
    int t = threadIdx.x;
    if (t < 32) c[t] = 1.f / (1.f + expf(-csum[t] * (1.f / NN)));
    __syncthreads();
    if (t < 32) {
        float a = 0.f;
        for (int j = 0; j < 32; j++) a += discW[t * 32 + j] * c[j];
        v[t] = a;
    }
    __syncthreads();
    float db = discb[0];
    int n = blockIdx.x * 256 + t;
    if (n < NN) {
        float s1 = 0.f, s2 = 0.f, s3 = 0.f;
        for (int j = 0; j < 32; j++) {
            float vj = v[j];
            s1 += x2o[(size_t)n * 32 + j] * vj;
            s2 += x2a[(size_t)n * 32 + j] * vj;
            s3 += x2aa[(size_t)n * 32 + j] * vj;
        }
        ret_os[n * 2] = s1 + db;  ret_os[n * 2 + 1] = s2 + db;
        ret_osa[n * 2] = s1 + db; ret_osa[n * 2 + 1] = s3 + db;
    }
}

// pair classifier as MFMA GEMM (K padded to 512, N padded to 80)
__launch_bounds__(256, 2)
__global__ void k_clsg(const float* __restrict__ h1o, const float* __restrict__ x2o,
                       const float* __restrict__ feat, const float* __restrict__ attt,
                       const int* __restrict__ idx,
                       const unsigned short* __restrict__ cwt,
                       const float* __restrict__ clsb, float* __restrict__ log_out) {
    constexpr int LDK = CLS_CK + 8;
    __shared__ unsigned short As[CLS_BM][LDK];
    __shared__ unsigned short Bs[CLS_N][LDK];
    __shared__ int nd[2][CLS_BM];

    int tid = threadIdx.x;
    int p0 = blockIdx.x * CLS_BM;
    if (tid < CLS_BM) {
        nd[0][tid] = idx[p0 + tid];
        nd[1][tid] = idx[BB + p0 + tid];
    }
    float a0 = attt[0], a1 = attt[1];

    const int wave = tid >> 6;
    const int lane = tid & 63;
    const int q = lane >> 4;
    const int ln = lane & 15;
    constexpr int NT = CLS_N / 16;
    const int mbase = wave * 16;

    floatx4 acc[NT];
    #pragma unroll
    for (int nt = 0; nt < NT; nt++) acc[nt] = floatx4{0.f, 0.f, 0.f, 0.f};

    for (int ch = 0; ch < CLS_K / CLS_CK; ch++) {
        int kbase = ch * CLS_CK;
        __syncthreads();
        for (int c = tid; c < CLS_N * CLS_CK / 8; c += 256) {
            int row = c / (CLS_CK / 8), cc = c % (CLS_CK / 8);
            *(uint4*)&Bs[row][cc * 8] = *(const uint4*)&cwt[(size_t)row * CLS_K + kbase + cc * 8];
        }
        for (int c = tid; c < CLS_BM * CLS_CK / 4; c += 256) {
            int row = c / (CLS_CK / 4);
            int j4 = (c % (CLS_CK / 4)) * 4;
            int j = kbase + j4;
            float4 v = {0.f, 0.f, 0.f, 0.f};
            if (j < 448) {
                int hseg = j / 224, jj = j % 224;
                int node = nd[hseg][row];
                if (jj < 64) {
                    v = *(const float4*)&h1o[(size_t)node * 64 + jj];
                    v.x *= a0; v.y *= a0; v.z *= a0; v.w *= a0;
                } else if (jj < 96) {
                    v = *(const float4*)&x2o[(size_t)node * 32 + (jj - 64)];
                    v.x *= a1; v.y *= a1; v.z *= a1; v.w *= a1;
                } else {
                    v = *(const float4*)&feat[(size_t)node * 128 + (jj - 96)];
                }
            }
            uint2 pk;
            pk.x = (unsigned)f2bf(v.x) | ((unsigned)f2bf(v.y) << 16);
            pk.y = (unsigned)f2bf(v.z) | ((unsigned)f2bf(v.w) << 16);
            *(uint2*)&As[row][j4] = pk;
        }
        __syncthreads();
        #pragma unroll
        for (int ks = 0; ks < CLS_CK / 32; ks++) {
            int kk = ks * 32 + q * 8;
            short8 af = *(const short8*)&As[mbase + ln][kk];
            #pragma unroll
            for (int nt = 0; nt < NT; nt++) {
                short8 bf = *(const short8*)&Bs[nt * 16 + ln][kk];
                acc[nt] = __builtin_amdgcn_mfma_f32_16x16x32_bf16(af, bf, acc[nt], 0, 0, 0);
            }
        }
    }

    #pragma unroll
    for (int rr2 = 0; rr2 < 4; rr2++) {
        int i = mbase + q * 4 + rr2;
        int pair = p0 + i;
        #pragma unroll
        for (int nt = 0; nt < NT; nt++) {
            int col = nt * 16 + ln;
            if (col < RR)
                log_out[(size_t)pair * RR + col] = acc[nt][rr2] + clsb[col];
        }
    }
}

extern "C" void kernel_launch(void* const* d_in, const int* in_sizes, int n_in,
                              void* d_out, int out_size, void* d_ws, size_t ws_size,
                              hipStream_t stream) {
    const float* x_o   = (const float*)d_in[0];
    const float* x_a   = (const float*)d_in[1];
    const float* feat  = (const float*)d_in[2];
    const float* W1    = (const float*)d_in[3];
    const float* root1 = (const float*)d_in[4];
    const float* b1    = (const float*)d_in[5];
    const float* W2    = (const float*)d_in[6];
    const float* root2 = (const float*)d_in[7];
    const float* b2    = (const float*)d_in[8];
    const float* attt  = (const float*)d_in[9];
    const float* discW = (const float*)d_in[10];
    const float* discb = (const float*)d_in[11];
    const float* clsW  = (const float*)d_in[12];
    const float* clsb  = (const float*)d_in[13];
    const int* ei      = (const int*)d_in[14];
    const int* et0     = (const int*)d_in[15];
    const int* et1     = (const int*)d_in[16];
    const int* idx     = (const int*)d_in[17];

    char* ws = (char*)d_ws;
    float* csum = (float*)(ws + OFF_CSUM);
    int* cntD  = (int*)(ws + OFF_CNTD);
    int* dstOff = (int*)(ws + OFF_DSTOFF);
    int* bh0   = (int*)(ws + OFF_BH0);
    int* bh1   = (int*)(ws + OFF_BH1);
    int* bb0   = (int*)(ws + OFF_BB0);
    int* bb1   = (int*)(ws + OFF_BB1);
    int* offB0 = (int*)(ws + OFF_OFFB0);
    int* offB1 = (int*)(ws + OFF_OFFB1);
    int* tilB0 = (int*)(ws + OFF_TILB0);
    int* tilT0 = (int*)(ws + OFF_TILT0);
    int* tilB1 = (int*)(ws + OFF_TILB1);
    int* tilT1 = (int*)(ws + OFF_TILT1);
    int* slotE = (int*)(ws + OFF_SLOT);
    int* posD  = (int*)(ws + OFF_POSD);
    unsigned int* rdP = (unsigned int*)(ws + OFF_RDP);
    float* wD0 = (float*)(ws + OFF_WD0);
    float* wD1 = (float*)(ws + OFF_WD1);
    int* perm0 = (int*)(ws + OFF_PERM0);
    int* perm1 = (int*)(ws + OFF_PERM1);
    unsigned short* xob = (unsigned short*)(ws + OFF_XOB);
    unsigned short* xab = (unsigned short*)(ws + OFF_XAB);
    float* h1o  = (float*)(ws + OFF_H1);
    float* h1a  = h1o + (size_t)NN * HH1;
    float* h1aa = h1a + (size_t)NN * HH1;
    unsigned short* h1bo  = (unsigned short*)(ws + OFF_H1B);
    unsigned short* h1ba  = h1bo + (size_t)NN * HH1;
    unsigned short* h1baa = h1ba + (size_t)NN * HH1;
    float* x2a  = (float*)(ws + OFF_X2A);
    float* x2aa = (float*)(ws + OFF_X2AA);
    unsigned short* w1t = (unsigned short*)(ws + OFF_W1BT);
    unsigned short* w2t = (unsigned short*)(ws + OFF_W2BT);
    unsigned short* r1t = (unsigned short*)(ws + OFF_R1T);
    unsigned short* r2t = (unsigned short*)(ws + OFF_R2T);
    unsigned short* cwt = (unsigned short*)(ws + OFF_CWT);
    unsigned short* msg = (unsigned short*)(ws + OFF_MSG);

    float* out = (float*)d_out;
    float* log_out = out + O_LOG;
    float* ret_os  = out + O_ROS;
    float* ret_osa = out + O_ROSA;
    float* x2o     = out + O_X2O;

    // 1) zero control block (csum + cntD) — ~80 KB
    hipMemsetAsync(ws, 0, ZERO_BYTES, stream);

    // 2) preprocessing: (octile,relation) bucket sort (deterministic, no
    //    small-array atomics), dst CSR via slot atomics, pos-space weights
    k_hist<<<NBH, 256, 0, stream>>>(ei, et0, et1, cntD, slotE, bh0, bh1,
                                    x_o, x_a, W1, W2, root1, root2, clsW,
                                    xob, xab, w1t, w2t, r1t, r2t, cwt);
    k_scanD<<<1, 256, 0, stream>>>(cntD, dstOff);
    k_scanB<<<1, 256, 0, stream>>>(bh0, bh1, bb0, bb1, offB0, offB1,
                                   tilB0, tilT0, tilB1, tilT1);
    k_fillB<<<NBH, 256, 0, stream>>>(ei, et0, et1, offB0, offB1, bb0, bb1,
                                     perm0, perm1);
    k_post<<<2500, 256, 0, stream>>>(ei, et0, et1, dstOff, slotE, posD, rdP);
    k_wts<<<NN / 4, 256, 0, stream>>>(dstOff, rdP, wD0, wD1);

    // 3) layer 1: MFMA root GEMM + per-encoding (edge GEMM -> weighted reduce)
    {
        dim3 gb(NBT, 3);
        k_bgemm<FIN1, HH1><<<gb, 256, 0, stream>>>(xob, xab, xob, r1t, b1,
                                                   h1o, h1a, h1aa);
        const unsigned short* Xs[3] = {xob, xab, xob};
        float* Os[3] = {h1o, h1a, h1aa};
        unsigned short* Obs[3] = {h1bo, h1ba, h1baa};
        for (int enc = 0; enc < 3; enc++) {
            const int* perm = enc == 2 ? perm1 : perm0;
            const int* offB = enc == 2 ? offB1 : offB0;
            const int* tilB = enc == 2 ? tilB1 : tilB0;
            const int* tilT = enc == 2 ? tilT1 : tilT0;
            const float* wD = enc == 2 ? wD1 : wD0;
            k_gemm<FIN1, HH1><<<MAXT2, 256, 0, stream>>>(Xs[enc], msg, perm, offB,
                                                         tilB, tilT, ei, posD, w1t);
            k_reduce<HH1, true><<<NN / 4, 256, 0, stream>>>(msg, dstOff, wD,
                                                            Os[enc], Obs[enc]);
        }
    }

    // 4) layer 2: MFMA root GEMM + per-encoding (edge GEMM -> weighted reduce)
    {
        dim3 gb(NBT, 3);
        k_bgemm<HH1, HH2><<<gb, 256, 0, stream>>>(h1bo, h1ba, h1baa, r2t, b2,
                                                  x2o, x2a, x2aa);
        const unsigned short* Xs[3] = {h1bo, h1ba, h1baa};
        float* Os[3] = {x2o, x2a, x2aa};
        for (int enc = 0; enc < 3; enc++) {
            const int* perm = enc == 2 ? perm1 : perm0;
            const int* offB = enc == 2 ? offB1 : offB0;
            const int* tilB = enc == 2 ? tilB1 : tilB0;
            const int* tilT = enc == 2 ? tilT1 : tilT0;
            const float* wD = enc == 2 ? wD1 : wD0;
            k_gemm<HH1, HH2><<<MAXT2, 256, 0, stream>>>(Xs[enc], msg, perm, offB,
                                                        tilB, tilT, ei, posD, w2t);
            k_reduce<HH2, false><<<NN / 4, 256, 0, stream>>>(msg, dstOff, wD,
                                                             Os[enc], nullptr);
        }
    }

    // 5) readout + discriminator + classifier
    k_mean<<<256, 256, 0, stream>>>(x2o, csum);
    k_disc<<<(NN + 255) / 256, 256, 0, stream>>>(x2o, x2a, x2aa, csum, discW, discb,
                                                 ret_os, ret_osa);
    k_clsg<<<BB / CLS_BM, 256, 0, stream>>>(h1o, x2o, feat, attt, idx, cwt, clsb, log_out);
}

// Round 10
// 734.657 us; speedup vs baseline: 1.3699x; 1.0733x over previous
//
#include <hip/hip_runtime.h>
#include <hip/hip_bf16.h>

// ---------------- problem constants ----------------
#define NN 20000      // nodes
#define EE 640000     // edges
#define RR 65         // relations
#define FIN1 128      // input feat
#define HH1 64        // hidden1
#define HH2 32        // hidden2
#define BB 8192       // pairs

constexpr int BM = 128;                 // edge-tile rows per GEMM block
constexpr int NBH = 256;                // histogram/placement blocks
constexpr int EPB = EE / NBH;           // 2500 edges per block
constexpr int NBT = (NN + BM - 1) / BM; // 157 node tiles
constexpr int NOCT = 8;                 // src octiles (nodes per octile = 2500)
constexpr int NPO = NN / NOCT;          // 2500
constexpr int NB2 = NOCT * RR;          // 520 sort buckets (octile-major, relation inner)
constexpr int MAXT2 = EE / BM + NB2;    // 5520 tile upper bound

// classifier GEMM geometry (E[8192x448] @ clsW[448x65], padded)
constexpr int CLS_K  = 512;
constexpr int CLS_N  = 80;
constexpr int CLS_CK = 128;
constexpr int CLS_BM = 64;

typedef __attribute__((ext_vector_type(8))) short short8;   // 8 bf16 MFMA frag
typedef __attribute__((ext_vector_type(4))) float floatx4;  // 4 fp32 acc

// ---------------- workspace layout (bytes) ----------------
constexpr size_t aln(size_t x) { return (x + 255) & ~(size_t)255; }

constexpr size_t OFF_CSUM  = 0;                        // 32 f
constexpr size_t OFF_CNTD  = aln(OFF_CSUM + 32 * 4);  // NN int (dst degree)
constexpr size_t ZERO_BYTES = OFF_CNTD + (size_t)NN * 4;   // memset [0, ZERO_BYTES)
constexpr size_t OFF_DSTOFF = aln(ZERO_BYTES);         // NN+1 int
constexpr size_t OFF_BH0   = aln(OFF_DSTOFF + ((size_t)NN + 1) * 4); // NBH*NB2
constexpr size_t OFF_BH1   = OFF_BH0 + (size_t)NBH * NB2 * 4;
constexpr size_t OFF_BB0   = OFF_BH1 + (size_t)NBH * NB2 * 4;
constexpr size_t OFF_BB1   = OFF_BB0 + (size_t)NBH * NB2 * 4;
constexpr size_t OFF_HT    = aln(OFF_BB1 + (size_t)NBH * NB2 * 4);   // 2*NB2 int totals
constexpr size_t OFF_OFFB0 = aln(OFF_HT + (size_t)2 * NB2 * 4);      // NB2+1 int
constexpr size_t OFF_OFFB1 = OFF_OFFB0 + (NB2 + 1) * 4;
constexpr size_t OFF_TILB0 = aln(OFF_OFFB1 + (NB2 + 1) * 4);  // MAXT2 int
constexpr size_t OFF_TILT0 = OFF_TILB0 + (size_t)MAXT2 * 4;
constexpr size_t OFF_TILB1 = OFF_TILT0 + (size_t)MAXT2 * 4;
constexpr size_t OFF_TILT1 = OFF_TILB1 + (size_t)MAXT2 * 4;
constexpr size_t OFF_SLOT  = aln(OFF_TILT1 + (size_t)MAXT2 * 4);  // E int
constexpr size_t OFF_POSD  = OFF_SLOT + (size_t)EE * 4;           // E int (e -> dst pos)
constexpr size_t OFF_RDP   = OFF_POSD + (size_t)EE * 4;           // E uint (pos -> r0|r1<<16)
constexpr size_t OFF_WD0   = OFF_RDP + (size_t)EE * 4;            // E float (pos-space weights)
constexpr size_t OFF_WD1   = OFF_WD0 + (size_t)EE * 4;
constexpr size_t OFF_PERM0 = OFF_WD1 + (size_t)EE * 4;            // E int (stores e)
constexpr size_t OFF_PERM1 = OFF_PERM0 + (size_t)EE * 4;
constexpr size_t OFF_XOB   = aln(OFF_PERM1 + (size_t)EE * 4);     // N*F bf16
constexpr size_t OFF_XAB   = OFF_XOB + (size_t)NN * FIN1 * 2;
constexpr size_t OFF_H1    = aln(OFF_XAB + (size_t)NN * FIN1 * 2); // 3 * N*64 f
constexpr size_t OFF_H1B   = OFF_H1 + (size_t)3 * NN * HH1 * 4;    // 3 * N*64 bf16
constexpr size_t OFF_X2A   = OFF_H1B + (size_t)3 * NN * HH1 * 2;   // N*32 f
constexpr size_t OFF_X2AA  = OFF_X2A + (size_t)NN * HH2 * 4;
constexpr size_t OFF_W1BT  = OFF_X2AA + (size_t)NN * HH2 * 4;      // R*64*128 bf16
constexpr size_t OFF_W2BT  = OFF_W1BT + (size_t)RR * HH1 * FIN1 * 2;
constexpr size_t OFF_R1T   = OFF_W2BT + (size_t)RR * HH2 * HH1 * 2;
constexpr size_t OFF_R2T   = OFF_R1T + (size_t)HH1 * FIN1 * 2;
constexpr size_t OFF_CWT   = OFF_R2T + (size_t)HH2 * HH1 * 2;
constexpr size_t OFF_MSG   = aln(OFF_CWT + (size_t)CLS_N * CLS_K * 2); // E*64 bf16
constexpr size_t WS_END    = OFF_MSG + (size_t)EE * HH1 * 2;

// output offsets (floats)
constexpr size_t O_LOG  = 0;
constexpr size_t O_ROS  = (size_t)BB * RR;
constexpr size_t O_ROSA = O_ROS + (size_t)NN * 2;
constexpr size_t O_X2O  = O_ROSA + (size_t)NN * 2;

__device__ inline unsigned short f2bf(float f) {
    __hip_bfloat16 h = __float2bfloat16(f);
    return *reinterpret_cast<unsigned short*>(&h);
}
__device__ inline float bfbits2f(unsigned int hi_bits) {
    return __uint_as_float(hi_bits);
}

// ---------------- preprocessing ----------------
// per-block 520-bin (octile,relation) histograms via LDS -> plain stores,
// per-dst degree + slot (benign 20k-addr scatter atomic), fused bf16 conversions.
__global__ void k_hist(const int* __restrict__ ei, const int* __restrict__ et0,
                       const int* __restrict__ et1,
                       int* cntD, int* __restrict__ slotE,
                       int* __restrict__ bh0, int* __restrict__ bh1,
                       const float* __restrict__ x_o, const float* __restrict__ x_a,
                       const float* __restrict__ W1, const float* __restrict__ W2,
                       const float* __restrict__ root1, const float* __restrict__ root2,
                       const float* __restrict__ clsW,
                       unsigned short* xob, unsigned short* xab,
                       unsigned short* w1t, unsigned short* w2t,
                       unsigned short* r1t, unsigned short* r2t,
                       unsigned short* cwt) {
    __shared__ int lh0[NB2], lh1[NB2];
    int t = threadIdx.x;
    for (int p = t; p < NB2; p += 256) { lh0[p] = 0; lh1[p] = 0; }
    __syncthreads();
    int base = blockIdx.x * EPB;
    for (int i = t; i < EPB; i += 256) {
        int e = base + i;
        int oct = ei[e] / NPO;
        atomicAdd(&lh0[oct * RR + et0[e]], 1);
        atomicAdd(&lh1[oct * RR + et1[e]], 1);
        slotE[e] = atomicAdd(&cntD[ei[EE + e]], 1);
    }
    __syncthreads();
    for (int p = t; p < NB2; p += 256) {
        bh0[blockIdx.x * NB2 + p] = lh0[p];
        bh1[blockIdx.x * NB2 + p] = lh1[p];
    }
    // streaming conversions (grid-stride over 256-block grid)
    int stride = gridDim.x * 256;
    int i0 = blockIdx.x * 256 + t;
    const int NX = NN * FIN1;
    for (int i = i0; i < NX; i += stride) { xob[i] = f2bf(x_o[i]); xab[i] = f2bf(x_a[i]); }
    const int NW1 = RR * HH1 * FIN1;
    for (int i = i0; i < NW1; i += stride) {
        int k = i % FIN1; int rh = i / FIN1; int hh = rh % HH1; int r = rh / HH1;
        w1t[i] = f2bf(W1[((size_t)r * FIN1 + k) * HH1 + hh]);
    }
    const int NW2 = RR * HH2 * HH1;
    for (int i = i0; i < NW2; i += stride) {
        int k = i % HH1; int rh = i / HH1; int hh = rh % HH2; int r = rh / HH2;
        w2t[i] = f2bf(W2[((size_t)r * HH1 + k) * HH2 + hh]);
    }
    const int NR1 = HH1 * FIN1;
    for (int i = i0; i < NR1; i += stride) {
        int k = i % FIN1; int hh = i / FIN1;
        r1t[i] = f2bf(root1[(size_t)k * HH1 + hh]);
    }
    const int NR2 = HH2 * HH1;
    for (int i = i0; i < NR2; i += stride) {
        int k = i % HH1; int hh = i / HH1;
        r2t[i] = f2bf(root2[(size_t)k * HH2 + hh]);
    }
    const int NCW = CLS_N * CLS_K;
    for (int i = i0; i < NCW; i += stride) {
        int k = i % CLS_K; int n = i / CLS_K;
        cwt[i] = (n < RR && k < 448) ? f2bf(clsW[(size_t)k * RR + n]) : (unsigned short)0;
    }
}

// exclusive scan of per-dst degrees -> dstOff[NN+1] (single block)
__global__ void k_scanD(const int* __restrict__ cntD, int* __restrict__ dstOff) {
    __shared__ int s[256];
    int t = threadIdx.x;
    constexpr int PER = (NN + 255) / 256;
    int lo = t * PER, hi = min(NN, lo + PER);
    int sum = 0;
    for (int i = lo; i < hi; i++) sum += cntD[i];
    s[t] = sum;
    __syncthreads();
    for (int ofs = 1; ofs < 256; ofs <<= 1) {
        int v = 0;
        if (t >= ofs) v = s[t - ofs];
        __syncthreads();
        if (t >= ofs) s[t] += v;
        __syncthreads();
    }
    int run = s[t] - sum;
    for (int i = lo; i < hi; i++) { dstOff[i] = run; run += cntD[i]; }
    if (t == 255) dstOff[NN] = run;
}

// phase 1: per-bucket exclusive prefix over the 256 histogram blocks.
// One WAVE per (sort, bucket) column: lane l holds blocks 4l..4l+3, wave-level
// shfl scan — all 1040 columns in flight across the grid (no serial walk).
__global__ void k_scanB1(const int* __restrict__ bh0, const int* __restrict__ bh1,
                         int* __restrict__ bb0, int* __restrict__ bb1,
                         int* __restrict__ hT) {
    int w = (blockIdx.x * 256 + threadIdx.x) >> 6;
    int lane = threadIdx.x & 63;
    if (w >= 2 * NB2) return;
    int s = w / NB2, k = w % NB2;
    const int* bh = s ? bh1 : bh0;
    int* bb = s ? bb1 : bb0;
    int v[4];
    #pragma unroll
    for (int i = 0; i < 4; i++) v[i] = bh[(size_t)(lane * 4 + i) * NB2 + k];
    int ls = v[0] + v[1] + v[2] + v[3];
    int inc = ls;
    #pragma unroll
    for (int ofs = 1; ofs < 64; ofs <<= 1) {
        int o = __shfl_up(inc, ofs);
        if (lane >= ofs) inc += o;
    }
    int run = inc - ls;   // exclusive base for this lane
    #pragma unroll
    for (int i = 0; i < 4; i++) {
        bb[(size_t)(lane * 4 + i) * NB2 + k] = run;
        run += v[i];
    }
    if (lane == 63) hT[s * NB2 + k] = run;  // column total
}

// phase 2 (single block): bucket offsets + tile tables from the 1040 totals.
__global__ void k_scanB2(const int* __restrict__ hT,
                         int* offB0, int* offB1,
                         int* tilB0, int* tilT0, int* tilB1, int* tilT1) {
    __shared__ int h[2][NB2];
    __shared__ int o[2][NB2 + 1];
    __shared__ int to[2][NB2 + 1];
    __shared__ int csumE[2][8], csumT[2][8];
    int t = threadIdx.x;
    for (int p = t; p < 2 * NB2; p += 256) h[p / NB2][p % NB2] = hT[p];
    __syncthreads();
    // chunked exclusive scans (edges and tiles), 8 chunks of RR bins each
    if (t < 16) {
        int s = t / 8, c = t % 8;
        int runE = 0, runT = 0;
        for (int k = c * RR; k < (c + 1) * RR; k++) {
            o[s][k] = runE;  runE += h[s][k];
            to[s][k] = runT; runT += (h[s][k] + BM - 1) / BM;
        }
        csumE[s][c] = runE; csumT[s][c] = runT;
    }
    __syncthreads();
    if (t < 2) {
        int runE = 0, runT = 0;
        for (int c = 0; c < 8; c++) {
            int e = csumE[t][c], tt = csumT[t][c];
            csumE[t][c] = runE; csumT[t][c] = runT;
            runE += e; runT += tt;
        }
        o[t][NB2] = runE; to[t][NB2] = runT;
    }
    __syncthreads();
    if (t < 16) {
        int s = t / 8, c = t % 8;
        for (int k = c * RR; k < (c + 1) * RR; k++) {
            o[s][k] += csumE[s][c];
            to[s][k] += csumT[s][c];
        }
    }
    __syncthreads();
    for (int p = t; p <= NB2; p += 256) { offB0[p] = o[0][p]; offB1[p] = o[1][p]; }
    // emit tile tables: 256 threads, binary search over LDS tile offsets
    for (int i = t; i < MAXT2; i += 256) {
        #pragma unroll
        for (int s = 0; s < 2; s++) {
            int total = to[s][NB2];
            int bkt = -1, ti = 0;
            if (i < total) {
                int lo = 0, hi = NB2;
                while (hi - lo > 1) { int mid = (lo + hi) >> 1; if (to[s][mid] <= i) lo = mid; else hi = mid; }
                bkt = lo;
                ti = i - to[s][lo];
            }
            if (s == 0) { tilB0[i] = bkt; tilT0[i] = ti; }
            else        { tilB1[i] = bkt; tilT1[i] = ti; }
        }
    }
}

// bucket-sorted perm placement with deterministic bases; perm stores e.
__global__ void k_fillB(const int* __restrict__ ei, const int* __restrict__ et0,
                        const int* __restrict__ et1,
                        const int* __restrict__ offB0, const int* __restrict__ offB1,
                        const int* __restrict__ bb0, const int* __restrict__ bb1,
                        int* perm0, int* perm1) {
    __shared__ int lc[2][NB2];
    __shared__ int lb[2][NB2];
    int t = threadIdx.x;
    for (int p = t; p < NB2; p += 256) {
        lc[0][p] = 0; lc[1][p] = 0;
        lb[0][p] = offB0[p] + bb0[blockIdx.x * NB2 + p];
        lb[1][p] = offB1[p] + bb1[blockIdx.x * NB2 + p];
    }
    __syncthreads();
    int base = blockIdx.x * EPB;
    for (int i = t; i < EPB; i += 256) {
        int e = base + i;
        int oct = ei[e] / NPO;
        int k0 = oct * RR + et0[e];
        int k1 = oct * RR + et1[e];
        int p0 = atomicAdd(&lc[0][k0], 1);
        int p1 = atomicAdd(&lc[1][k1], 1);
        perm0[lb[0][k0] + p0] = e;
        perm1[lb[1][k1] + p1] = e;
    }
}

// posD (sequential write) + rdP (the single scattered-write array)
__global__ void k_post(const int* __restrict__ ei, const int* __restrict__ et0,
                       const int* __restrict__ et1, const int* __restrict__ dstOff,
                       const int* __restrict__ slotE,
                       int* __restrict__ posD, unsigned int* __restrict__ rdP) {
    int e = blockIdx.x * 256 + threadIdx.x;
    if (e < EE) {
        int d = ei[EE + e];
        int pos = dstOff[d] + slotE[e];
        posD[e] = pos;
        rdP[pos] = (unsigned)et0[e] | ((unsigned)et1[e] << 16);
    }
}

// per-(relation,dst) mean weights inside each dst segment -> pos-space arrays
__global__ void k_wts(const int* __restrict__ dstOff, const unsigned int* __restrict__ rdP,
                      float* __restrict__ wD0, float* __restrict__ wD1) {
    constexpr int CAP = 96;
    __shared__ unsigned int ld[4][CAP];
    int wave = threadIdx.x >> 6;
    int lane = threadIdx.x & 63;
    int d = blockIdx.x * 4 + wave;
    int j0 = 0, deg = 0;
    if (d < NN) { j0 = dstOff[d]; deg = dstOff[d + 1] - j0; }
    for (int j = lane; j < deg && j < CAP; j += 64) ld[wave][j] = rdP[j0 + j];
    __syncthreads();
    for (int j = lane; j < deg; j += 64) {
        unsigned int my = (j < CAP) ? ld[wave][j] : rdP[j0 + j];
        unsigned int m0 = my & 0xffffu, m1 = my >> 16;
        int c0 = 0, c1 = 0;
        for (int k = 0; k < deg; k++) {
            unsigned int p = (k < CAP) ? ld[wave][k] : rdP[j0 + k];
            c0 += ((p & 0xffffu) == m0);
            c1 += ((p >> 16) == m1);
        }
        wD0[j0 + j] = 1.0f / (float)c0;
        wD1[j0 + j] = 1.0f / (float)c1;
    }
}

// root-term GEMM via MFMA: O[n,h] = Xb[n,:] @ rootT[h,:] + bias[h]  (fp32 out)
template <int FIN, int HOUT>
__launch_bounds__(256, 3)
__global__ void k_bgemm(const unsigned short* __restrict__ X0,
                        const unsigned short* __restrict__ X1,
                        const unsigned short* __restrict__ X2,
                        const unsigned short* __restrict__ rootT,
                        const float* __restrict__ bias,
                        float* O0, float* O1, float* O2) {
    const int enc = blockIdx.y;
    const unsigned short* X = enc == 0 ? X0 : enc == 1 ? X1 : X2;
    float* O = enc == 0 ? O0 : enc == 1 ? O1 : O2;
    int n0 = blockIdx.x * BM;
    int mcount = min(BM, NN - n0);

    constexpr int LDK = FIN + 8;
    __shared__ unsigned short As[BM][LDK];
    __shared__ unsigned short Bs[HOUT][LDK];

    int tid = threadIdx.x;
    {
        constexpr int CHB = HOUT * FIN / 8;
        for (int c = tid; c < CHB; c += 256) {
            int row = c / (FIN / 8), cc = c % (FIN / 8);
            *(uint4*)&Bs[row][cc * 8] = *(const uint4*)&rootT[row * FIN + cc * 8];
        }
    }
    {
        constexpr int CHA = BM * FIN / 8;
        for (int c = tid; c < CHA; c += 256) {
            int row = c / (FIN / 8), cc = c % (FIN / 8);
            uint4 v = {0u, 0u, 0u, 0u};
            if (row < mcount) v = *(const uint4*)&X[(size_t)(n0 + row) * FIN + cc * 8];
            *(uint4*)&As[row][cc * 8] = v;
        }
    }
    __syncthreads();

    const int wave = tid >> 6;
    const int lane = tid & 63;
    const int q = lane >> 4;
    const int ln = lane & 15;
    constexpr int NT = HOUT / 16;
    constexpr int KS = FIN / 32;
    const int mbase = wave * 32;

    floatx4 acc[2][NT];
    #pragma unroll
    for (int a = 0; a < 2; a++)
        #pragma unroll
        for (int nt = 0; nt < NT; nt++) acc[a][nt] = floatx4{0.f, 0.f, 0.f, 0.f};

    for (int ks = 0; ks < KS; ks++) {
        int kk = ks * 32 + q * 8;
        short8 af0 = *(const short8*)&As[mbase + ln][kk];
        short8 af1 = *(const short8*)&As[mbase + 16 + ln][kk];
        #pragma unroll
        for (int nt = 0; nt < NT; nt++) {
            short8 bf = *(const short8*)&Bs[nt * 16 + ln][kk];
            acc[0][nt] = __builtin_amdgcn_mfma_f32_16x16x32_bf16(af0, bf, acc[0][nt], 0, 0, 0);
            acc[1][nt] = __builtin_amdgcn_mfma_f32_16x16x32_bf16(af1, bf, acc[1][nt], 0, 0, 0);
        }
    }

    #pragma unroll
    for (int mt = 0; mt < 2; mt++) {
        #pragma unroll
        for (int rr2 = 0; rr2 < 4; rr2++) {
            int i = mbase + mt * 16 + q * 4 + rr2;
            int n = n0 + i;
            if (i < mcount) {
                #pragma unroll
                for (int nt = 0; nt < NT; nt++)
                    O[(size_t)n * HOUT + nt * 16 + ln] = acc[mt][nt][rr2] + bias[nt * 16 + ln];
            }
        }
    }
}

// bucket-grouped gather-GEMM with MFMA; tiles dispatched (src-octile, relation)
// major so concurrent blocks gather from one ~640 KB L2-resident X window.
// Epilogue writes unweighted bf16 msg rows to dst-sorted slots (plain stores).
template <int FIN, int HOUT>
__launch_bounds__(256, (FIN == 128 ? 3 : 4))
__global__ void k_gemm(const unsigned short* __restrict__ X,
                       unsigned short* __restrict__ msg,
                       const int* __restrict__ perm, const int* __restrict__ offB,
                       const int* __restrict__ tilB, const int* __restrict__ tilT,
                       const int* __restrict__ ei, const int* __restrict__ posD,
                       const unsigned short* __restrict__ WT) {
    int b = blockIdx.x;
    int bkt = tilB[b];
    if (bkt < 0) return;
    int r = bkt % RR;
    int t = tilT[b];
    int ebase = offB[bkt] + t * BM;
    int mcount = min(BM, offB[bkt + 1] - ebase);

    constexpr int LDK = FIN + 8;
    __shared__ unsigned short As[BM][LDK];
    __shared__ unsigned short Bs[HOUT][LDK];
    __shared__ int Sr[BM];
    __shared__ int Pd[BM];

    int tid = threadIdx.x;
    if (tid < BM) {
        if (tid < mcount) {
            int e = perm[ebase + tid];
            Sr[tid] = ei[e];
            Pd[tid] = posD[e];
        } else { Sr[tid] = -1; Pd[tid] = 0; }
    }
    __syncthreads();

    {
        const unsigned short* Wr = WT + (size_t)r * HOUT * FIN;
        constexpr int CHB = HOUT * FIN / 8;
        for (int c = tid; c < CHB; c += 256) {
            int row = c / (FIN / 8), cc = c % (FIN / 8);
            *(uint4*)&Bs[row][cc * 8] = *(const uint4*)&Wr[row * FIN + cc * 8];
        }
    }
    {
        constexpr int CHA = BM * FIN / 8;
        for (int c = tid; c < CHA; c += 256) {
            int row = c / (FIN / 8), cc = c % (FIN / 8);
            int s = Sr[row];
            uint4 v = {0u, 0u, 0u, 0u};
            if (s >= 0) v = *(const uint4*)&X[(size_t)s * FIN + cc * 8];
            *(uint4*)&As[row][cc * 8] = v;
        }
    }
    __syncthreads();

    const int wave = tid >> 6;
    const int lane = tid & 63;
    const int q = lane >> 4;
    const int ln = lane & 15;
    constexpr int NT = HOUT / 16;
    constexpr int KS = FIN / 32;
    const int mbase = wave * 32;

    floatx4 acc[2][NT];
    #pragma unroll
    for (int a = 0; a < 2; a++)
        #pragma unroll
        for (int nt = 0; nt < NT; nt++) acc[a][nt] = floatx4{0.f, 0.f, 0.f, 0.f};

    for (int ks = 0; ks < KS; ks++) {
        int kk = ks * 32 + q * 8;
        short8 af0 = *(const short8*)&As[mbase + ln][kk];
        short8 af1 = *(const short8*)&As[mbase + 16 + ln][kk];
        #pragma unroll
        for (int nt = 0; nt < NT; nt++) {
            short8 bf = *(const short8*)&Bs[nt * 16 + ln][kk];
            acc[0][nt] = __builtin_amdgcn_mfma_f32_16x16x32_bf16(af0, bf, acc[0][nt], 0, 0, 0);
            acc[1][nt] = __builtin_amdgcn_mfma_f32_16x16x32_bf16(af1, bf, acc[1][nt], 0, 0, 0);
        }
    }

    // epilogue: bf16 msgs through LDS (overlay As), coalesced full-line scatter
    __syncthreads();
    constexpr int LDM = HOUT + 8;
    unsigned short* Ms = &As[0][0];
    #pragma unroll
    for (int mt = 0; mt < 2; mt++) {
        #pragma unroll
        for (int rr2 = 0; rr2 < 4; rr2++) {
            int i = mbase + mt * 16 + q * 4 + rr2;
            #pragma unroll
            for (int nt = 0; nt < NT; nt++)
                Ms[i * LDM + nt * 16 + ln] = f2bf(acc[mt][nt][rr2]);
        }
    }
    __syncthreads();
    constexpr int CH = HOUT / 8;
    for (int c = tid; c < BM * CH; c += 256) {
        int row = c / CH, cc = c % CH;
        if (row < mcount)
            *(uint4*)&msg[(size_t)Pd[row] * HOUT + cc * 8] = *(const uint4*)&Ms[row * LDM + cc * 8];
    }
}

// weighted segment-sum of msg rows per dst + root base; optional relu+bf16.
template <int H, bool RELU>
__global__ void k_reduce(const unsigned short* __restrict__ msg,
                         const int* __restrict__ dstOff,
                         const float* __restrict__ wD,
                         float* __restrict__ base_io,
                         unsigned short* __restrict__ bfout) {
    int d = blockIdx.x * 4 + (threadIdx.x >> 6);
    if (d >= NN) return;
    int lane = threadIdx.x & 63;
    constexpr int HC = H / 4;
    constexpr int RPI = 64 / HC;
    int sub = lane / HC;
    int c4 = lane % HC;
    int j0 = dstOff[d], j1 = dstOff[d + 1];
    float a0 = 0.f, a1 = 0.f, a2 = 0.f, a3 = 0.f;
    for (int j = j0 + sub; j < j1; j += RPI) {
        float w = wD[j];
        uint2 v = *(const uint2*)&msg[(size_t)j * H + c4 * 4];
        a0 += w * bfbits2f(v.x << 16);
        a1 += w * bfbits2f(v.x & 0xffff0000u);
        a2 += w * bfbits2f(v.y << 16);
        a3 += w * bfbits2f(v.y & 0xffff0000u);
    }
    #pragma unroll
    for (int ofs = 32; ofs >= HC; ofs >>= 1) {
        a0 += __shfl_down(a0, ofs); a1 += __shfl_down(a1, ofs);
        a2 += __shfl_down(a2, ofs); a3 += __shfl_down(a3, ofs);
    }
    if (lane < HC) {
        size_t o = (size_t)d * H + c4 * 4;
        float v0 = base_io[o] + a0, v1 = base_io[o + 1] + a1;
        float v2 = base_io[o + 2] + a2, v3 = base_io[o + 3] + a3;
        if (RELU) {
            v0 = fmaxf(v0, 0.f); v1 = fmaxf(v1, 0.f);
            v2 = fmaxf(v2, 0.f); v3 = fmaxf(v3, 0.f);
        }
        base_io[o] = v0; base_io[o + 1] = v1; base_io[o + 2] = v2; base_io[o + 3] = v3;
        if (RELU) {
            bfout[o] = f2bf(v0); bfout[o + 1] = f2bf(v1);
            bfout[o + 2] = f2bf(v2); bfout[o + 3] = f2bf(v3);
        }
    }
}

// column sums of x2_o -> csum[32]
__global__ void k_mean(const float* __restrict__ x2o, float* csum) {
    __shared__ float s[256];
    int t = threadIdx.x; int hh = t & 31; int g = t >> 5;
    float acc = 0.f;
    for (int n = blockIdx.x * 8 + g; n < NN; n += gridDim.x * 8)
        acc += x2o[(size_t)n * 32 + hh];
    s[t] = acc;
    __syncthreads();
    if (t < 32) {
        float v = 0.f;
        for (int gg = 0; gg < 8; gg++) v += s[gg * 32 + t];
        unsafeAtomicAdd(&csum[t], v);
    }
}

// c = sigmoid(csum/N); v = disc_W @ c; bilinear scores
__global__ void k_disc(const float* __restrict__ x2o, const float* __restrict__ x2a,
                       const float* __restrict__ x2aa, const float* __restrict__ csum,
                       const float* __restrict__ discW, const float* __restrict__ discb,
                       float* ret_os, float* ret_osa) {
    __shared__ float c[32], v[32];
    int t = threadIdx.x;
    if (t < 32) c[t] = 1.f / (1.f + expf(-csum[t] * (1.f / NN)));
    __syncthreads();
    if (t < 32) {
        float a = 0.f;
        for (int j = 0; j < 32; j++) a += discW[t * 32 + j] * c[j];
        v[t] = a;
    }
    __syncthreads();
    float db = discb[0];
    int n = blockIdx.x * 256 + t;
    if (n < NN) {
        float s1 = 0.f, s2 = 0.f, s3 = 0.f;
        for (int j = 0; j < 32; j++) {
            float vj = v[j];
            s1 += x2o[(size_t)n * 32 + j] * vj;
            s2 += x2a[(size_t)n * 32 + j] * vj;
            s3 += x2aa[(size_t)n * 32 + j] * vj;
        }
        ret_os[n * 2] = s1 + db;  ret_os[n * 2 + 1] = s2 + db;
        ret_osa[n * 2] = s1 + db; ret_osa[n * 2 + 1] = s3 + db;
    }
}

// pair classifier as MFMA GEMM (K padded to 512, N padded to 80)
__launch_bounds__(256, 2)
__global__ void k_clsg(const float* __restrict__ h1o, const float* __restrict__ x2o,
                       const float* __restrict__ feat, const float* __restrict__ attt,
                       const int* __restrict__ idx,
                       const unsigned short* __restrict__ cwt,
                       const float* __restrict__ clsb, float* __restrict__ log_out) {
    constexpr int LDK = CLS_CK + 8;
    __shared__ unsigned short As[CLS_BM][LDK];
    __shared__ unsigned short Bs[CLS_N][LDK];
    __shared__ int nd[2][CLS_BM];

    int tid = threadIdx.x;
    int p0 = blockIdx.x * CLS_BM;
    if (tid < CLS_BM) {
        nd[0][tid] = idx[p0 + tid];
        nd[1][tid] = idx[BB + p0 + tid];
    }
    float a0 = attt[0], a1 = attt[1];

    const int wave = tid >> 6;
    const int lane = tid & 63;
    const int q = lane >> 4;
    const int ln = lane & 15;
    constexpr int NT = CLS_N / 16;
    const int mbase = wave * 16;

    floatx4 acc[NT];
    #pragma unroll
    for (int nt = 0; nt < NT; nt++) acc[nt] = floatx4{0.f, 0.f, 0.f, 0.f};

    for (int ch = 0; ch < CLS_K / CLS_CK; ch++) {
        int kbase = ch * CLS_CK;
        __syncthreads();
        for (int c = tid; c < CLS_N * CLS_CK / 8; c += 256) {
            int row = c / (CLS_CK / 8), cc = c % (CLS_CK / 8);
            *(uint4*)&Bs[row][cc * 8] = *(const uint4*)&cwt[(size_t)row * CLS_K + kbase + cc * 8];
        }
        for (int c = tid; c < CLS_BM * CLS_CK / 4; c += 256) {
            int row = c / (CLS_CK / 4);
            int j4 = (c % (CLS_CK / 4)) * 4;
            int j = kbase + j4;
            float4 v = {0.f, 0.f, 0.f, 0.f};
            if (j < 448) {
                int hseg = j / 224, jj = j % 224;
                int node = nd[hseg][row];
                if (jj < 64) {
                    v = *(const float4*)&h1o[(size_t)node * 64 + jj];
                    v.x *= a0; v.y *= a0; v.z *= a0; v.w *= a0;
                } else if (jj < 96) {
                    v = *(const float4*)&x2o[(size_t)node * 32 + (jj - 64)];
                    v.x *= a1; v.y *= a1; v.z *= a1; v.w *= a1;
                } else {
                    v = *(const float4*)&feat[(size_t)node * 128 + (jj - 96)];
                }
            }
            uint2 pk;
            pk.x = (unsigned)f2bf(v.x) | ((unsigned)f2bf(v.y) << 16);
            pk.y = (unsigned)f2bf(v.z) | ((unsigned)f2bf(v.w) << 16);
            *(uint2*)&As[row][j4] = pk;
        }
        __syncthreads();
        #pragma unroll
        for (int ks = 0; ks < CLS_CK / 32; ks++) {
            int kk = ks * 32 + q * 8;
            short8 af = *(const short8*)&As[mbase + ln][kk];
            #pragma unroll
            for (int nt = 0; nt < NT; nt++) {
                short8 bf = *(const short8*)&Bs[nt * 16 + ln][kk];
                acc[nt] = __builtin_amdgcn_mfma_f32_16x16x32_bf16(af, bf, acc[nt], 0, 0, 0);
            }
        }
    }

    #pragma unroll
    for (int rr2 = 0; rr2 < 4; rr2++) {
        int i = mbase + q * 4 + rr2;
        int pair = p0 + i;
        #pragma unroll
        for (int nt = 0; nt < NT; nt++) {
            int col = nt * 16 + ln;
            if (col < RR)
                log_out[(size_t)pair * RR + col] = acc[nt][rr2] + clsb[col];
        }
    }
}

extern "C" void kernel_launch(void* const* d_in, const int* in_sizes, int n_in,
                              void* d_out, int out_size, void* d_ws, size_t ws_size,
                              hipStream_t stream) {
    const float* x_o   = (const float*)d_in[0];
    const float* x_a   = (const float*)d_in[1];
    const float* feat  = (const float*)d_in[2];
    const float* W1    = (const float*)d_in[3];
    const float* root1 = (const float*)d_in[4];
    const float* b1    = (const float*)d_in[5];
    const float* W2    = (const float*)d_in[6];
    const float* root2 = (const float*)d_in[7];
    const float* b2    = (const float*)d_in[8];
    const float* attt  = (const float*)d_in[9];
    const float* discW = (const float*)d_in[10];
    const float* discb = (const float*)d_in[11];
    const float* clsW  = (const float*)d_in[12];
    const float* clsb  = (const float*)d_in[13];
    const int* ei      = (const int*)d_in[14];
    const int* et0     = (const int*)d_in[15];
    const int* et1     = (const int*)d_in[16];
    const int* idx     = (const int*)d_in[17];

    char* ws = (char*)d_ws;
    float* csum = (float*)(ws + OFF_CSUM);
    int* cntD  = (int*)(ws + OFF_CNTD);
    int* dstOff = (int*)(ws + OFF_DSTOFF);
    int* bh0   = (int*)(ws + OFF_BH0);
    int* bh1   = (int*)(ws + OFF_BH1);
    int* bb0   = (int*)(ws + OFF_BB0);
    int* bb1   = (int*)(ws + OFF_BB1);
    int* hT    = (int*)(ws + OFF_HT);
    int* offB0 = (int*)(ws + OFF_OFFB0);
    int* offB1 = (int*)(ws + OFF_OFFB1);
    int* tilB0 = (int*)(ws + OFF_TILB0);
    int* tilT0 = (int*)(ws + OFF_TILT0);
    int* tilB1 = (int*)(ws + OFF_TILB1);
    int* tilT1 = (int*)(ws + OFF_TILT1);
    int* slotE = (int*)(ws + OFF_SLOT);
    int* posD  = (int*)(ws + OFF_POSD);
    unsigned int* rdP = (unsigned int*)(ws + OFF_RDP);
    float* wD0 = (float*)(ws + OFF_WD0);
    float* wD1 = (float*)(ws + OFF_WD1);
    int* perm0 = (int*)(ws + OFF_PERM0);
    int* perm1 = (int*)(ws + OFF_PERM1);
    unsigned short* xob = (unsigned short*)(ws + OFF_XOB);
    unsigned short* xab = (unsigned short*)(ws + OFF_XAB);
    float* h1o  = (float*)(ws + OFF_H1);
    float* h1a  = h1o + (size_t)NN * HH1;
    float* h1aa = h1a + (size_t)NN * HH1;
    unsigned short* h1bo  = (unsigned short*)(ws + OFF_H1B);
    unsigned short* h1ba  = h1bo + (size_t)NN * HH1;
    unsigned short* h1baa = h1ba + (size_t)NN * HH1;
    float* x2a  = (float*)(ws + OFF_X2A);
    float* x2aa = (float*)(ws + OFF_X2AA);
    unsigned short* w1t = (unsigned short*)(ws + OFF_W1BT);
    unsigned short* w2t = (unsigned short*)(ws + OFF_W2BT);
    unsigned short* r1t = (unsigned short*)(ws + OFF_R1T);
    unsigned short* r2t = (unsigned short*)(ws + OFF_R2T);
    unsigned short* cwt = (unsigned short*)(ws + OFF_CWT);
    unsigned short* msg = (unsigned short*)(ws + OFF_MSG);

    float* out = (float*)d_out;
    float* log_out = out + O_LOG;
    float* ret_os  = out + O_ROS;
    float* ret_osa = out + O_ROSA;
    float* x2o     = out + O_X2O;

    // 1) zero control block (csum + cntD) — ~80 KB
    hipMemsetAsync(ws, 0, ZERO_BYTES, stream);

    // 2) preprocessing: (octile,relation) bucket sort (deterministic, no
    //    small-array atomics), dst CSR via slot atomics, pos-space weights
    k_hist<<<NBH, 256, 0, stream>>>(ei, et0, et1, cntD, slotE, bh0, bh1,
                                    x_o, x_a, W1, W2, root1, root2, clsW,
                                    xob, xab, w1t, w2t, r1t, r2t, cwt);
    k_scanD<<<1, 256, 0, stream>>>(cntD, dstOff);
    k_scanB1<<<(2 * NB2 + 3) / 4, 256, 0, stream>>>(bh0, bh1, bb0, bb1, hT);
    k_scanB2<<<1, 256, 0, stream>>>(hT, offB0, offB1,
                                    tilB0, tilT0, tilB1, tilT1);
    k_fillB<<<NBH, 256, 0, stream>>>(ei, et0, et1, offB0, offB1, bb0, bb1,
                                     perm0, perm1);
    k_post<<<2500, 256, 0, stream>>>(ei, et0, et1, dstOff, slotE, posD, rdP);
    k_wts<<<NN / 4, 256, 0, stream>>>(dstOff, rdP, wD0, wD1);

    // 3) layer 1: MFMA root GEMM + per-encoding (edge GEMM -> weighted reduce)
    {
        dim3 gb(NBT, 3);
        k_bgemm<FIN1, HH1><<<gb, 256, 0, stream>>>(xob, xab, xob, r1t, b1,
                                                   h1o, h1a, h1aa);
        const unsigned short* Xs[3] = {xob, xab, xob};
        float* Os[3] = {h1o, h1a, h1aa};
        unsigned short* Obs[3] = {h1bo, h1ba, h1baa};
        for (int enc = 0; enc < 3; enc++) {
            const int* perm = enc == 2 ? perm1 : perm0;
            const int* offB = enc == 2 ? offB1 : offB0;
            const int* tilB = enc == 2 ? tilB1 : tilB0;
            const int* tilT = enc == 2 ? tilT1 : tilT0;
            const float* wD = enc == 2 ? wD1 : wD0;
            k_gemm<FIN1, HH1><<<MAXT2, 256, 0, stream>>>(Xs[enc], msg, perm, offB,
                                                         tilB, tilT, ei, posD, w1t);
            k_reduce<HH1, true><<<NN / 4, 256, 0, stream>>>(msg, dstOff, wD,
                                                            Os[enc], Obs[enc]);
        }
    }

    // 4) layer 2: MFMA root GEMM + per-encoding (edge GEMM -> weighted reduce)
    {
        dim3 gb(NBT, 3);
        k_bgemm<HH1, HH2><<<gb, 256, 0, stream>>>(h1bo, h1ba, h1baa, r2t, b2,
                                                  x2o, x2a, x2aa);
        const unsigned short* Xs[3] = {h1bo, h1ba, h1baa};
        float* Os[3] = {x2o, x2a, x2aa};
        for (int enc = 0; enc < 3; enc++) {
            const int* perm = enc == 2 ? perm1 : perm0;
            const int* offB = enc == 2 ? offB1 : offB0;
            const int* tilB = enc == 2 ? tilB1 : tilB0;
            const int* tilT = enc == 2 ? tilT1 : tilT0;
            const float* wD = enc == 2 ? wD1 : wD0;
            k_gemm<HH1, HH2><<<MAXT2, 256, 0, stream>>>(Xs[enc], msg, perm, offB,
                                                        tilB, tilT, ei, posD, w2t);
            k_reduce<HH2, false><<<NN / 4, 256, 0, stream>>>(msg, dstOff, wD,
                                                             Os[enc], nullptr);
        }
    }

    // 5) readout + discriminator + classifier
    k_mean<<<256, 256, 0, stream>>>(x2o, csum);
    k_disc<<<(NN + 255) / 256, 256, 0, stream>>>(x2o, x2a, x2aa, csum, discW, discb,
                                                 ret_os, ret_osa);
    k_clsg<<<BB / CLS_BM, 256, 0, stream>>>(h1o, x2o, feat, attt, idx, cwt, clsb, log_out);
}

// Round 12
// 730.105 us; speedup vs baseline: 1.3784x; 1.0062x over previous
//
#include <hip/hip_runtime.h>
#include <hip/hip_bf16.h>

// ---------------- problem constants ----------------
#define NN 20000      // nodes
#define EE 640000     // edges
#define RR 65         // relations
#define FIN1 128      // input feat
#define HH1 64        // hidden1
#define HH2 32        // hidden2
#define BB 8192       // pairs

constexpr int BM = 128;                 // edge-tile rows per GEMM block
constexpr int NBH = 256;                // histogram/placement blocks
constexpr int EPB = EE / NBH;           // 2500 edges per block
constexpr int NBT = (NN + BM - 1) / BM; // 157 node tiles
constexpr int NOCT = 8;                 // src octiles (nodes per octile = 2500)
constexpr int NPO = NN / NOCT;          // 2500
constexpr int NB2 = NOCT * RR;          // 520 sort buckets (octile-major, relation inner)
constexpr int MAXT2 = EE / BM + NB2;    // 5520 tile upper bound

// classifier GEMM geometry (E[8192x448] @ clsW[448x65], padded)
constexpr int CLS_K  = 512;
constexpr int CLS_N  = 80;
constexpr int CLS_CK = 128;
constexpr int CLS_BM = 64;

typedef __attribute__((ext_vector_type(8))) short short8;   // 8 bf16 MFMA frag
typedef __attribute__((ext_vector_type(4))) float floatx4;  // 4 fp32 acc
typedef __attribute__((ext_vector_type(4))) unsigned int uint4e;  // nt-capable 16B
typedef __attribute__((ext_vector_type(2))) unsigned int uint2e;  // nt-capable 8B

// ---------------- workspace layout (bytes) ----------------
constexpr size_t aln(size_t x) { return (x + 255) & ~(size_t)255; }

constexpr size_t OFF_CSUM  = 0;                        // 32 f
constexpr size_t OFF_CNTD  = aln(OFF_CSUM + 32 * 4);  // NN int (dst degree)
constexpr size_t ZERO_BYTES = OFF_CNTD + (size_t)NN * 4;   // memset [0, ZERO_BYTES)
constexpr size_t OFF_DSTOFF = aln(ZERO_BYTES);         // NN+1 int
constexpr size_t OFF_BH0   = aln(OFF_DSTOFF + ((size_t)NN + 1) * 4); // NBH*NB2
constexpr size_t OFF_BH1   = OFF_BH0 + (size_t)NBH * NB2 * 4;
constexpr size_t OFF_BB0   = OFF_BH1 + (size_t)NBH * NB2 * 4;
constexpr size_t OFF_BB1   = OFF_BB0 + (size_t)NBH * NB2 * 4;
constexpr size_t OFF_HT    = aln(OFF_BB1 + (size_t)NBH * NB2 * 4);   // 2*NB2 int totals
constexpr size_t OFF_OFFB0 = aln(OFF_HT + (size_t)2 * NB2 * 4);      // NB2+1 int
constexpr size_t OFF_OFFB1 = OFF_OFFB0 + (NB2 + 1) * 4;
constexpr size_t OFF_TILB0 = aln(OFF_OFFB1 + (NB2 + 1) * 4);  // MAXT2 int
constexpr size_t OFF_TILT0 = OFF_TILB0 + (size_t)MAXT2 * 4;
constexpr size_t OFF_TILB1 = OFF_TILT0 + (size_t)MAXT2 * 4;
constexpr size_t OFF_TILT1 = OFF_TILB1 + (size_t)MAXT2 * 4;
constexpr size_t OFF_SLOT  = aln(OFF_TILT1 + (size_t)MAXT2 * 4);  // E int
constexpr size_t OFF_POSD  = OFF_SLOT + (size_t)EE * 4;           // E int (e -> dst pos)
constexpr size_t OFF_RDP   = OFF_POSD + (size_t)EE * 4;           // E uint (pos -> r0|r1<<16)
constexpr size_t OFF_WD0   = OFF_RDP + (size_t)EE * 4;            // E float (pos-space weights)
constexpr size_t OFF_WD1   = OFF_WD0 + (size_t)EE * 4;
constexpr size_t OFF_PERM0 = OFF_WD1 + (size_t)EE * 4;            // E int (stores e)
constexpr size_t OFF_PERM1 = OFF_PERM0 + (size_t)EE * 4;
constexpr size_t OFF_XOB   = aln(OFF_PERM1 + (size_t)EE * 4);     // N*F bf16
constexpr size_t OFF_XAB   = OFF_XOB + (size_t)NN * FIN1 * 2;
constexpr size_t OFF_H1    = aln(OFF_XAB + (size_t)NN * FIN1 * 2); // 3 * N*64 f
constexpr size_t OFF_H1B   = OFF_H1 + (size_t)3 * NN * HH1 * 4;    // 3 * N*64 bf16
constexpr size_t OFF_X2A   = OFF_H1B + (size_t)3 * NN * HH1 * 2;   // N*32 f
constexpr size_t OFF_X2AA  = OFF_X2A + (size_t)NN * HH2 * 4;
constexpr size_t OFF_W1BT  = OFF_X2AA + (size_t)NN * HH2 * 4;      // R*64*128 bf16
constexpr size_t OFF_W2BT  = OFF_W1BT + (size_t)RR * HH1 * FIN1 * 2;
constexpr size_t OFF_R1T   = OFF_W2BT + (size_t)RR * HH2 * HH1 * 2;
constexpr size_t OFF_R2T   = OFF_R1T + (size_t)HH1 * FIN1 * 2;
constexpr size_t OFF_CWT   = OFF_R2T + (size_t)HH2 * HH1 * 2;
constexpr size_t OFF_MSG   = aln(OFF_CWT + (size_t)CLS_N * CLS_K * 2); // E*64 bf16
constexpr size_t WS_END    = OFF_MSG + (size_t)EE * HH1 * 2;

// output offsets (floats)
constexpr size_t O_LOG  = 0;
constexpr size_t O_ROS  = (size_t)BB * RR;
constexpr size_t O_ROSA = O_ROS + (size_t)NN * 2;
constexpr size_t O_X2O  = O_ROSA + (size_t)NN * 2;

__device__ inline unsigned short f2bf(float f) {
    __hip_bfloat16 h = __float2bfloat16(f);
    return *reinterpret_cast<unsigned short*>(&h);
}
__device__ inline float bfbits2f(unsigned int hi_bits) {
    return __uint_as_float(hi_bits);
}

// ---------------- preprocessing ----------------
// per-block 520-bin (octile,relation) histograms via LDS -> plain stores,
// per-dst degree + slot (benign 20k-addr scatter atomic), fused bf16 conversions.
__global__ void k_hist(const int* __restrict__ ei, const int* __restrict__ et0,
                       const int* __restrict__ et1,
                       int* cntD, int* __restrict__ slotE,
                       int* __restrict__ bh0, int* __restrict__ bh1,
                       const float* __restrict__ x_o, const float* __restrict__ x_a,
                       const float* __restrict__ W1, const float* __restrict__ W2,
                       const float* __restrict__ root1, const float* __restrict__ root2,
                       const float* __restrict__ clsW,
                       unsigned short* xob, unsigned short* xab,
                       unsigned short* w1t, unsigned short* w2t,
                       unsigned short* r1t, unsigned short* r2t,
                       unsigned short* cwt) {
    __shared__ int lh0[NB2], lh1[NB2];
    int t = threadIdx.x;
    for (int p = t; p < NB2; p += 256) { lh0[p] = 0; lh1[p] = 0; }
    __syncthreads();
    int base = blockIdx.x * EPB;
    for (int i = t; i < EPB; i += 256) {
        int e = base + i;
        int oct = ei[e] / NPO;
        atomicAdd(&lh0[oct * RR + et0[e]], 1);
        atomicAdd(&lh1[oct * RR + et1[e]], 1);
        slotE[e] = atomicAdd(&cntD[ei[EE + e]], 1);
    }
    __syncthreads();
    for (int p = t; p < NB2; p += 256) {
        bh0[blockIdx.x * NB2 + p] = lh0[p];
        bh1[blockIdx.x * NB2 + p] = lh1[p];
    }
    // streaming conversions (grid-stride over 256-block grid)
    int stride = gridDim.x * 256;
    int i0 = blockIdx.x * 256 + t;
    const int NX = NN * FIN1;
    for (int i = i0; i < NX; i += stride) { xob[i] = f2bf(x_o[i]); xab[i] = f2bf(x_a[i]); }
    const int NW1 = RR * HH1 * FIN1;
    for (int i = i0; i < NW1; i += stride) {
        int k = i % FIN1; int rh = i / FIN1; int hh = rh % HH1; int r = rh / HH1;
        w1t[i] = f2bf(W1[((size_t)r * FIN1 + k) * HH1 + hh]);
    }
    const int NW2 = RR * HH2 * HH1;
    for (int i = i0; i < NW2; i += stride) {
        int k = i % HH1; int rh = i / HH1; int hh = rh % HH2; int r = rh / HH2;
        w2t[i] = f2bf(W2[((size_t)r * HH1 + k) * HH2 + hh]);
    }
    const int NR1 = HH1 * FIN1;
    for (int i = i0; i < NR1; i += stride) {
        int k = i % FIN1; int hh = i / FIN1;
        r1t[i] = f2bf(root1[(size_t)k * HH1 + hh]);
    }
    const int NR2 = HH2 * HH1;
    for (int i = i0; i < NR2; i += stride) {
        int k = i % HH1; int hh = i / HH1;
        r2t[i] = f2bf(root2[(size_t)k * HH2 + hh]);
    }
    const int NCW = CLS_N * CLS_K;
    for (int i = i0; i < NCW; i += stride) {
        int k = i % CLS_K; int n = i / CLS_K;
        cwt[i] = (n < RR && k < 448) ? f2bf(clsW[(size_t)k * RR + n]) : (unsigned short)0;
    }
}

// exclusive scan of per-dst degrees -> dstOff[NN+1] (single block)
__global__ void k_scanD(const int* __restrict__ cntD, int* __restrict__ dstOff) {
    __shared__ int s[256];
    int t = threadIdx.x;
    constexpr int PER = (NN + 255) / 256;
    int lo = t * PER, hi = min(NN, lo + PER);
    int sum = 0;
    for (int i = lo; i < hi; i++) sum += cntD[i];
    s[t] = sum;
    __syncthreads();
    for (int ofs = 1; ofs < 256; ofs <<= 1) {
        int v = 0;
        if (t >= ofs) v = s[t - ofs];
        __syncthreads();
        if (t >= ofs) s[t] += v;
        __syncthreads();
    }
    int run = s[t] - sum;
    for (int i = lo; i < hi; i++) { dstOff[i] = run; run += cntD[i]; }
    if (t == 255) dstOff[NN] = run;
}

// phase 1: per-bucket exclusive prefix over the 256 histogram blocks.
// One WAVE per (sort, bucket) column: lane l holds blocks 4l..4l+3, wave-level
// shfl scan — all 1040 columns in flight across the grid (no serial walk).
__global__ void k_scanB1(const int* __restrict__ bh0, const int* __restrict__ bh1,
                         int* __restrict__ bb0, int* __restrict__ bb1,
                         int* __restrict__ hT) {
    int w = (blockIdx.x * 256 + threadIdx.x) >> 6;
    int lane = threadIdx.x & 63;
    if (w >= 2 * NB2) return;
    int s = w / NB2, k = w % NB2;
    const int* bh = s ? bh1 : bh0;
    int* bb = s ? bb1 : bb0;
    int v[4];
    #pragma unroll
    for (int i = 0; i < 4; i++) v[i] = bh[(size_t)(lane * 4 + i) * NB2 + k];
    int ls = v[0] + v[1] + v[2] + v[3];
    int inc = ls;
    #pragma unroll
    for (int ofs = 1; ofs < 64; ofs <<= 1) {
        int o = __shfl_up(inc, ofs);
        if (lane >= ofs) inc += o;
    }
    int run = inc - ls;   // exclusive base for this lane
    #pragma unroll
    for (int i = 0; i < 4; i++) {
        bb[(size_t)(lane * 4 + i) * NB2 + k] = run;
        run += v[i];
    }
    if (lane == 63) hT[s * NB2 + k] = run;  // column total
}

// phase 2 (single block): bucket offsets + tile tables from the 1040 totals.
__global__ void k_scanB2(const int* __restrict__ hT,
                         int* offB0, int* offB1,
                         int* tilB0, int* tilT0, int* tilB1, int* tilT1) {
    __shared__ int h[2][NB2];
    __shared__ int o[2][NB2 + 1];
    __shared__ int to[2][NB2 + 1];
    __shared__ int csumE[2][8], csumT[2][8];
    int t = threadIdx.x;
    for (int p = t; p < 2 * NB2; p += 256) h[p / NB2][p % NB2] = hT[p];
    __syncthreads();
    if (t < 16) {
        int s = t / 8, c = t % 8;
        int runE = 0, runT = 0;
        for (int k = c * RR; k < (c + 1) * RR; k++) {
            o[s][k] = runE;  runE += h[s][k];
            to[s][k] = runT; runT += (h[s][k] + BM - 1) / BM;
        }
        csumE[s][c] = runE; csumT[s][c] = runT;
    }
    __syncthreads();
    if (t < 2) {
        int runE = 0, runT = 0;
        for (int c = 0; c < 8; c++) {
            int e = csumE[t][c], tt = csumT[t][c];
            csumE[t][c] = runE; csumT[t][c] = runT;
            runE += e; runT += tt;
        }
        o[t][NB2] = runE; to[t][NB2] = runT;
    }
    __syncthreads();
    if (t < 16) {
        int s = t / 8, c = t % 8;
        for (int k = c * RR; k < (c + 1) * RR; k++) {
            o[s][k] += csumE[s][c];
            to[s][k] += csumT[s][c];
        }
    }
    __syncthreads();
    for (int p = t; p <= NB2; p += 256) { offB0[p] = o[0][p]; offB1[p] = o[1][p]; }
    for (int i = t; i < MAXT2; i += 256) {
        #pragma unroll
        for (int s = 0; s < 2; s++) {
            int total = to[s][NB2];
            int bkt = -1, ti = 0;
            if (i < total) {
                int lo = 0, hi = NB2;
                while (hi - lo > 1) { int mid = (lo + hi) >> 1; if (to[s][mid] <= i) lo = mid; else hi = mid; }
                bkt = lo;
                ti = i - to[s][lo];
            }
            if (s == 0) { tilB0[i] = bkt; tilT0[i] = ti; }
            else        { tilB1[i] = bkt; tilT1[i] = ti; }
        }
    }
}

// bucket-sorted perm placement with deterministic bases; perm stores e.
__global__ void k_fillB(const int* __restrict__ ei, const int* __restrict__ et0,
                        const int* __restrict__ et1,
                        const int* __restrict__ offB0, const int* __restrict__ offB1,
                        const int* __restrict__ bb0, const int* __restrict__ bb1,
                        int* perm0, int* perm1) {
    __shared__ int lc[2][NB2];
    __shared__ int lb[2][NB2];
    int t = threadIdx.x;
    for (int p = t; p < NB2; p += 256) {
        lc[0][p] = 0; lc[1][p] = 0;
        lb[0][p] = offB0[p] + bb0[blockIdx.x * NB2 + p];
        lb[1][p] = offB1[p] + bb1[blockIdx.x * NB2 + p];
    }
    __syncthreads();
    int base = blockIdx.x * EPB;
    for (int i = t; i < EPB; i += 256) {
        int e = base + i;
        int oct = ei[e] / NPO;
        int k0 = oct * RR + et0[e];
        int k1 = oct * RR + et1[e];
        int p0 = atomicAdd(&lc[0][k0], 1);
        int p1 = atomicAdd(&lc[1][k1], 1);
        perm0[lb[0][k0] + p0] = e;
        perm1[lb[1][k1] + p1] = e;
    }
}

// posD (sequential write) + rdP (the single scattered-write array)
__global__ void k_post(const int* __restrict__ ei, const int* __restrict__ et0,
                       const int* __restrict__ et1, const int* __restrict__ dstOff,
                       const int* __restrict__ slotE,
                       int* __restrict__ posD, unsigned int* __restrict__ rdP) {
    int e = blockIdx.x * 256 + threadIdx.x;
    if (e < EE) {
        int d = ei[EE + e];
        int pos = dstOff[d] + slotE[e];
        posD[e] = pos;
        rdP[pos] = (unsigned)et0[e] | ((unsigned)et1[e] << 16);
    }
}

// per-(relation,dst) mean weights inside each dst segment -> pos-space arrays
__global__ void k_wts(const int* __restrict__ dstOff, const unsigned int* __restrict__ rdP,
                      float* __restrict__ wD0, float* __restrict__ wD1) {
    constexpr int CAP = 96;
    __shared__ unsigned int ld[4][CAP];
    int wave = threadIdx.x >> 6;
    int lane = threadIdx.x & 63;
    int d = blockIdx.x * 4 + wave;
    int j0 = 0, deg = 0;
    if (d < NN) { j0 = dstOff[d]; deg = dstOff[d + 1] - j0; }
    for (int j = lane; j < deg && j < CAP; j += 64) ld[wave][j] = rdP[j0 + j];
    __syncthreads();
    for (int j = lane; j < deg; j += 64) {
        unsigned int my = (j < CAP) ? ld[wave][j] : rdP[j0 + j];
        unsigned int m0 = my & 0xffffu, m1 = my >> 16;
        int c0 = 0, c1 = 0;
        for (int k = 0; k < deg; k++) {
            unsigned int p = (k < CAP) ? ld[wave][k] : rdP[j0 + k];
            c0 += ((p & 0xffffu) == m0);
            c1 += ((p >> 16) == m1);
        }
        wD0[j0 + j] = 1.0f / (float)c0;
        wD1[j0 + j] = 1.0f / (float)c1;
    }
}

// root-term GEMM via MFMA: O[n,h] = Xb[n,:] @ rootT[h,:] + bias[h]  (fp32 out)
template <int FIN, int HOUT>
__launch_bounds__(256, 3)
__global__ void k_bgemm(const unsigned short* __restrict__ X0,
                        const unsigned short* __restrict__ X1,
                        const unsigned short* __restrict__ X2,
                        const unsigned short* __restrict__ rootT,
                        const float* __restrict__ bias,
                        float* O0, float* O1, float* O2) {
    const int enc = blockIdx.y;
    const unsigned short* X = enc == 0 ? X0 : enc == 1 ? X1 : X2;
    float* O = enc == 0 ? O0 : enc == 1 ? O1 : O2;
    int n0 = blockIdx.x * BM;
    int mcount = min(BM, NN - n0);

    constexpr int LDK = FIN + 8;
    __shared__ unsigned short As[BM][LDK];
    __shared__ unsigned short Bs[HOUT][LDK];

    int tid = threadIdx.x;
    {
        constexpr int CHB = HOUT * FIN / 8;
        for (int c = tid; c < CHB; c += 256) {
            int row = c / (FIN / 8), cc = c % (FIN / 8);
            *(uint4*)&Bs[row][cc * 8] = *(const uint4*)&rootT[row * FIN + cc * 8];
        }
    }
    {
        constexpr int CHA = BM * FIN / 8;
        for (int c = tid; c < CHA; c += 256) {
            int row = c / (FIN / 8), cc = c % (FIN / 8);
            uint4 v = {0u, 0u, 0u, 0u};
            if (row < mcount) v = *(const uint4*)&X[(size_t)(n0 + row) * FIN + cc * 8];
            *(uint4*)&As[row][cc * 8] = v;
        }
    }
    __syncthreads();

    const int wave = tid >> 6;
    const int lane = tid & 63;
    const int q = lane >> 4;
    const int ln = lane & 15;
    constexpr int NT = HOUT / 16;
    constexpr int KS = FIN / 32;
    const int mbase = wave * 32;

    floatx4 acc[2][NT];
    #pragma unroll
    for (int a = 0; a < 2; a++)
        #pragma unroll
        for (int nt = 0; nt < NT; nt++) acc[a][nt] = floatx4{0.f, 0.f, 0.f, 0.f};

    for (int ks = 0; ks < KS; ks++) {
        int kk = ks * 32 + q * 8;
        short8 af0 = *(const short8*)&As[mbase + ln][kk];
        short8 af1 = *(const short8*)&As[mbase + 16 + ln][kk];
        #pragma unroll
        for (int nt = 0; nt < NT; nt++) {
            short8 bf = *(const short8*)&Bs[nt * 16 + ln][kk];
            acc[0][nt] = __builtin_amdgcn_mfma_f32_16x16x32_bf16(af0, bf, acc[0][nt], 0, 0, 0);
            acc[1][nt] = __builtin_amdgcn_mfma_f32_16x16x32_bf16(af1, bf, acc[1][nt], 0, 0, 0);
        }
    }

    #pragma unroll
    for (int mt = 0; mt < 2; mt++) {
        #pragma unroll
        for (int rr2 = 0; rr2 < 4; rr2++) {
            int i = mbase + mt * 16 + q * 4 + rr2;
            int n = n0 + i;
            if (i < mcount) {
                #pragma unroll
                for (int nt = 0; nt < NT; nt++)
                    O[(size_t)n * HOUT + nt * 16 + ln] = acc[mt][nt][rr2] + bias[nt * 16 + ln];
            }
        }
    }
}

// bucket-grouped gather-GEMM with MFMA; tiles dispatched (src-octile, relation)
// major so concurrent blocks gather from one ~640 KB L2-resident X window.
// Epilogue writes unweighted bf16 msg rows to dst-sorted slots via NONTEMPORAL
// stores — the 80 MB msg stream must not evict the gather window from L2.
template <int FIN, int HOUT>
__launch_bounds__(256, (FIN == 128 ? 3 : 4))
__global__ void k_gemm(const unsigned short* __restrict__ X,
                       unsigned short* __restrict__ msg,
                       const int* __restrict__ perm, const int* __restrict__ offB,
                       const int* __restrict__ tilB, const int* __restrict__ tilT,
                       const int* __restrict__ ei, const int* __restrict__ posD,
                       const unsigned short* __restrict__ WT) {
    int b = blockIdx.x;
    int bkt = tilB[b];
    if (bkt < 0) return;
    int r = bkt % RR;
    int t = tilT[b];
    int ebase = offB[bkt] + t * BM;
    int mcount = min(BM, offB[bkt + 1] - ebase);

    constexpr int LDK = FIN + 8;
    __shared__ unsigned short As[BM][LDK];
    __shared__ unsigned short Bs[HOUT][LDK];
    __shared__ int Sr[BM];
    __shared__ int Pd[BM];

    int tid = threadIdx.x;
    if (tid < BM) {
        if (tid < mcount) {
            int e = perm[ebase + tid];
            Sr[tid] = ei[e];
            Pd[tid] = posD[e];
        } else { Sr[tid] = -1; Pd[tid] = 0; }
    }
    __syncthreads();

    {
        const unsigned short* Wr = WT + (size_t)r * HOUT * FIN;
        constexpr int CHB = HOUT * FIN / 8;
        for (int c = tid; c < CHB; c += 256) {
            int row = c / (FIN / 8), cc = c % (FIN / 8);
            *(uint4*)&Bs[row][cc * 8] = *(const uint4*)&Wr[row * FIN + cc * 8];
        }
    }
    {
        constexpr int CHA = BM * FIN / 8;
        for (int c = tid; c < CHA; c += 256) {
            int row = c / (FIN / 8), cc = c % (FIN / 8);
            int s = Sr[row];
            uint4 v = {0u, 0u, 0u, 0u};
            if (s >= 0) v = *(const uint4*)&X[(size_t)s * FIN + cc * 8];
            *(uint4*)&As[row][cc * 8] = v;
        }
    }
    __syncthreads();

    const int wave = tid >> 6;
    const int lane = tid & 63;
    const int q = lane >> 4;
    const int ln = lane & 15;
    constexpr int NT = HOUT / 16;
    constexpr int KS = FIN / 32;
    const int mbase = wave * 32;

    floatx4 acc[2][NT];
    #pragma unroll
    for (int a = 0; a < 2; a++)
        #pragma unroll
        for (int nt = 0; nt < NT; nt++) acc[a][nt] = floatx4{0.f, 0.f, 0.f, 0.f};

    for (int ks = 0; ks < KS; ks++) {
        int kk = ks * 32 + q * 8;
        short8 af0 = *(const short8*)&As[mbase + ln][kk];
        short8 af1 = *(const short8*)&As[mbase + 16 + ln][kk];
        #pragma unroll
        for (int nt = 0; nt < NT; nt++) {
            short8 bf = *(const short8*)&Bs[nt * 16 + ln][kk];
            acc[0][nt] = __builtin_amdgcn_mfma_f32_16x16x32_bf16(af0, bf, acc[0][nt], 0, 0, 0);
            acc[1][nt] = __builtin_amdgcn_mfma_f32_16x16x32_bf16(af1, bf, acc[1][nt], 0, 0, 0);
        }
    }

    // epilogue: bf16 msgs through LDS (overlay As), coalesced full-line
    // NONTEMPORAL scatter (no L2 retention for the write-only msg stream)
    __syncthreads();
    constexpr int LDM = HOUT + 8;
    unsigned short* Ms = &As[0][0];
    #pragma unroll
    for (int mt = 0; mt < 2; mt++) {
        #pragma unroll
        for (int rr2 = 0; rr2 < 4; rr2++) {
            int i = mbase + mt * 16 + q * 4 + rr2;
            #pragma unroll
            for (int nt = 0; nt < NT; nt++)
                Ms[i * LDM + nt * 16 + ln] = f2bf(acc[mt][nt][rr2]);
        }
    }
    __syncthreads();
    constexpr int CH = HOUT / 8;
    for (int c = tid; c < BM * CH; c += 256) {
        int row = c / CH, cc = c % CH;
        if (row < mcount) {
            uint4e v = *(const uint4e*)&Ms[row * LDM + cc * 8];
            __builtin_nontemporal_store(v, (uint4e*)&msg[(size_t)Pd[row] * HOUT + cc * 8]);
        }
    }
}

// weighted segment-sum of msg rows per dst + root base; optional relu+bf16.
// msg read is NONTEMPORAL (zero-reuse stream).
template <int H, bool RELU>
__global__ void k_reduce(const unsigned short* __restrict__ msg,
                         const int* __restrict__ dstOff,
                         const float* __restrict__ wD,
                         float* __restrict__ base_io,
                         unsigned short* __restrict__ bfout) {
    int d = blockIdx.x * 4 + (threadIdx.x >> 6);
    if (d >= NN) return;
    int lane = threadIdx.x & 63;
    constexpr int HC = H / 4;
    constexpr int RPI = 64 / HC;
    int sub = lane / HC;
    int c4 = lane % HC;
    int j0 = dstOff[d], j1 = dstOff[d + 1];
    float a0 = 0.f, a1 = 0.f, a2 = 0.f, a3 = 0.f;
    for (int j = j0 + sub; j < j1; j += RPI) {
        float w = wD[j];
        uint2e v = __builtin_nontemporal_load((const uint2e*)&msg[(size_t)j * H + c4 * 4]);
        a0 += w * bfbits2f(v.x << 16);
        a1 += w * bfbits2f(v.x & 0xffff0000u);
        a2 += w * bfbits2f(v.y << 16);
        a3 += w * bfbits2f(v.y & 0xffff0000u);
    }
    #pragma unroll
    for (int ofs = 32; ofs >= HC; ofs >>= 1) {
        a0 += __shfl_down(a0, ofs); a1 += __shfl_down(a1, ofs);
        a2 += __shfl_down(a2, ofs); a3 += __shfl_down(a3, ofs);
    }
    if (lane < HC) {
        size_t o = (size_t)d * H + c4 * 4;
        float v0 = base_io[o] + a0, v1 = base_io[o + 1] + a1;
        float v2 = base_io[o + 2] + a2, v3 = base_io[o + 3] + a3;
        if (RELU) {
            v0 = fmaxf(v0, 0.f); v1 = fmaxf(v1, 0.f);
            v2 = fmaxf(v2, 0.f); v3 = fmaxf(v3, 0.f);
        }
        base_io[o] = v0; base_io[o + 1] = v1; base_io[o + 2] = v2; base_io[o + 3] = v3;
        if (RELU) {
            bfout[o] = f2bf(v0); bfout[o + 1] = f2bf(v1);
            bfout[o + 2] = f2bf(v2); bfout[o + 3] = f2bf(v3);
        }
    }
}

// column sums of x2_o -> csum[32]
__global__ void k_mean(const float* __restrict__ x2o, float* csum) {
    __shared__ float s[256];
    int t = threadIdx.x; int hh = t & 31; int g = t >> 5;
    float acc = 0.f;
    for (int n = blockIdx.x * 8 + g; n < NN; n += gridDim.x * 8)
        acc += x2o[(size_t)n * 32 + hh];
    s[t] = acc;
    __syncthreads();
    if (t < 32) {
        float v = 0.f;
        for (int gg = 0; gg < 8; gg++) v += s[gg * 32 + t];
        unsafeAtomicAdd(&csum[t], v);
    }
}

// c = sigmoid(csum/N); v = disc_W @ c; bilinear scores
__global__ void k_disc(const float* __restrict__ x2o, const float* __restrict__ x2a,
                       const float* __restrict__ x2aa, const float* __restrict__ csum,
                       const float* __restrict__ discW, const float* __restrict__ discb,
                       float* ret_os, float* ret_osa) {
    __shared__ float c[32], v[32];
    int t = threadIdx.x;
    if (t < 32) c[t] = 1.f / (1.f + expf(-csum[t] * (1.f / NN)));
    __syncthreads();
    if (t < 32) {
        float a = 0.f;
        for (int j = 0; j < 32; j++) a += discW[t * 32 + j] * c[j];
        v[t] = a;
    }
    __syncthreads();
    float db = discb[0];
    int n = blockIdx.x * 256 + t;
    if (n < NN) {
        float s1 = 0.f, s2 = 0.f, s3 = 0.f;
        for (int j = 0; j < 32; j++) {
            float vj = v[j];
            s1 += x2o[(size_t)n * 32 + j] * vj;
            s2 += x2a[(size_t)n * 32 + j] * vj;
            s3 += x2aa[(size_t)n * 32 + j] * vj;
        }
        ret_os[n * 2] = s1 + db;  ret_os[n * 2 + 1] = s2 + db;
        ret_osa[n * 2] = s1 + db; ret_osa[n * 2 + 1] = s3 + db;
    }
}

// pair classifier as MFMA GEMM (K padded to 512, N padded to 80)
__launch_bounds__(256, 2)
__global__ void k_clsg(const float* __restrict__ h1o, const float* __restrict__ x2o,
                       const float* __restrict__ feat, const float* __restrict__ attt,
                       const int* __restrict__ idx,
                       const unsigned short* __restrict__ cwt,
                       const float* __restrict__ clsb, float* __restrict__ log_out) {
    constexpr int LDK = CLS_CK + 8;
    __shared__ unsigned short As[CLS_BM][LDK];
    __shared__ unsigned short Bs[CLS_N][LDK];
    __shared__ int nd[2][CLS_BM];

    int tid = threadIdx.x;
    int p0 = blockIdx.x * CLS_BM;
    if (tid < CLS_BM) {
        nd[0][tid] = idx[p0 + tid];
        nd[1][tid] = idx[BB + p0 + tid];
    }
    float a0 = attt[0], a1 = attt[1];

    const int wave = tid >> 6;
    const int lane = tid & 63;
    const int q = lane >> 4;
    const int ln = lane & 15;
    constexpr int NT = CLS_N / 16;
    const int mbase = wave * 16;

    floatx4 acc[NT];
    #pragma unroll
    for (int nt = 0; nt < NT; nt++) acc[nt] = floatx4{0.f, 0.f, 0.f, 0.f};

    for (int ch = 0; ch < CLS_K / CLS_CK; ch++) {
        int kbase = ch * CLS_CK;
        __syncthreads();
        for (int c = tid; c < CLS_N * CLS_CK / 8; c += 256) {
            int row = c / (CLS_CK / 8), cc = c % (CLS_CK / 8);
            *(uint4*)&Bs[row][cc * 8] = *(const uint4*)&cwt[(size_t)row * CLS_K + kbase + cc * 8];
        }
        for (int c = tid; c < CLS_BM * CLS_CK / 4; c += 256) {
            int row = c / (CLS_CK / 4);
            int j4 = (c % (CLS_CK / 4)) * 4;
            int j = kbase + j4;
            float4 v = {0.f, 0.f, 0.f, 0.f};
            if (j < 448) {
                int hseg = j / 224, jj = j % 224;
                int node = nd[hseg][row];
                if (jj < 64) {
                    v = *(const float4*)&h1o[(size_t)node * 64 + jj];
                    v.x *= a0; v.y *= a0; v.z *= a0; v.w *= a0;
                } else if (jj < 96) {
                    v = *(const float4*)&x2o[(size_t)node * 32 + (jj - 64)];
                    v.x *= a1; v.y *= a1; v.z *= a1; v.w *= a1;
                } else {
                    v = *(const float4*)&feat[(size_t)node * 128 + (jj - 96)];
                }
            }
            uint2 pk;
            pk.x = (unsigned)f2bf(v.x) | ((unsigned)f2bf(v.y) << 16);
            pk.y = (unsigned)f2bf(v.z) | ((unsigned)f2bf(v.w) << 16);
            *(uint2*)&As[row][j4] = pk;
        }
        __syncthreads();
        #pragma unroll
        for (int ks = 0; ks < CLS_CK / 32; ks++) {
            int kk = ks * 32 + q * 8;
            short8 af = *(const short8*)&As[mbase + ln][kk];
            #pragma unroll
            for (int nt = 0; nt < NT; nt++) {
                short8 bf = *(const short8*)&Bs[nt * 16 + ln][kk];
                acc[nt] = __builtin_amdgcn_mfma_f32_16x16x32_bf16(af, bf, acc[nt], 0, 0, 0);
            }
        }
    }

    #pragma unroll
    for (int rr2 = 0; rr2 < 4; rr2++) {
        int i = mbase + q * 4 + rr2;
        int pair = p0 + i;
        #pragma unroll
        for (int nt = 0; nt < NT; nt++) {
            int col = nt * 16 + ln;
            if (col < RR)
                log_out[(size_t)pair * RR + col] = acc[nt][rr2] + clsb[col];
        }
    }
}

extern "C" void kernel_launch(void* const* d_in, const int* in_sizes, int n_in,
                              void* d_out, int out_size, void* d_ws, size_t ws_size,
                              hipStream_t stream) {
    const float* x_o   = (const float*)d_in[0];
    const float* x_a   = (const float*)d_in[1];
    const float* feat  = (const float*)d_in[2];
    const float* W1    = (const float*)d_in[3];
    const float* root1 = (const float*)d_in[4];
    const float* b1    = (const float*)d_in[5];
    const float* W2    = (const float*)d_in[6];
    const float* root2 = (const float*)d_in[7];
    const float* b2    = (const float*)d_in[8];
    const float* attt  = (const float*)d_in[9];
    const float* discW = (const float*)d_in[10];
    const float* discb = (const float*)d_in[11];
    const float* clsW  = (const float*)d_in[12];
    const float* clsb  = (const float*)d_in[13];
    const int* ei      = (const int*)d_in[14];
    const int* et0     = (const int*)d_in[15];
    const int* et1     = (const int*)d_in[16];
    const int* idx     = (const int*)d_in[17];

    char* ws = (char*)d_ws;
    float* csum = (float*)(ws + OFF_CSUM);
    int* cntD  = (int*)(ws + OFF_CNTD);
    int* dstOff = (int*)(ws + OFF_DSTOFF);
    int* bh0   = (int*)(ws + OFF_BH0);
    int* bh1   = (int*)(ws + OFF_BH1);
    int* bb0   = (int*)(ws + OFF_BB0);
    int* bb1   = (int*)(ws + OFF_BB1);
    int* hT    = (int*)(ws + OFF_HT);
    int* offB0 = (int*)(ws + OFF_OFFB0);
    int* offB1 = (int*)(ws + OFF_OFFB1);
    int* tilB0 = (int*)(ws + OFF_TILB0);
    int* tilT0 = (int*)(ws + OFF_TILT0);
    int* tilB1 = (int*)(ws + OFF_TILB1);
    int* tilT1 = (int*)(ws + OFF_TILT1);
    int* slotE = (int*)(ws + OFF_SLOT);
    int* posD  = (int*)(ws + OFF_POSD);
    unsigned int* rdP = (unsigned int*)(ws + OFF_RDP);
    float* wD0 = (float*)(ws + OFF_WD0);
    float* wD1 = (float*)(ws + OFF_WD1);
    int* perm0 = (int*)(ws + OFF_PERM0);
    int* perm1 = (int*)(ws + OFF_PERM1);
    unsigned short* xob = (unsigned short*)(ws + OFF_XOB);
    unsigned short* xab = (unsigned short*)(ws + OFF_XAB);
    float* h1o  = (float*)(ws + OFF_H1);
    float* h1a  = h1o + (size_t)NN * HH1;
    float* h1aa = h1a + (size_t)NN * HH1;
    unsigned short* h1bo  = (unsigned short*)(ws + OFF_H1B);
    unsigned short* h1ba  = h1bo + (size_t)NN * HH1;
    unsigned short* h1baa = h1ba + (size_t)NN * HH1;
    float* x2a  = (float*)(ws + OFF_X2A);
    float* x2aa = (float*)(ws + OFF_X2AA);
    unsigned short* w1t = (unsigned short*)(ws + OFF_W1BT);
    unsigned short* w2t = (unsigned short*)(ws + OFF_W2BT);
    unsigned short* r1t = (unsigned short*)(ws + OFF_R1T);
    unsigned short* r2t = (unsigned short*)(ws + OFF_R2T);
    unsigned short* cwt = (unsigned short*)(ws + OFF_CWT);
    unsigned short* msg = (unsigned short*)(ws + OFF_MSG);

    float* out = (float*)d_out;
    float* log_out = out + O_LOG;
    float* ret_os  = out + O_ROS;
    float* ret_osa = out + O_ROSA;
    float* x2o     = out + O_X2O;

    // 1) zero control block (csum + cntD) — ~80 KB
    hipMemsetAsync(ws, 0, ZERO_BYTES, stream);

    // 2) preprocessing: (octile,relation) bucket sort (deterministic, no
    //    small-array atomics), dst CSR via slot atomics, pos-space weights
    k_hist<<<NBH, 256, 0, stream>>>(ei, et0, et1, cntD, slotE, bh0, bh1,
                                    x_o, x_a, W1, W2, root1, root2, clsW,
                                    xob, xab, w1t, w2t, r1t, r2t, cwt);
    k_scanD<<<1, 256, 0, stream>>>(cntD, dstOff);
    k_scanB1<<<(2 * NB2 + 3) / 4, 256, 0, stream>>>(bh0, bh1, bb0, bb1, hT);
    k_scanB2<<<1, 256, 0, stream>>>(hT, offB0, offB1,
                                    tilB0, tilT0, tilB1, tilT1);
    k_fillB<<<NBH, 256, 0, stream>>>(ei, et0, et1, offB0, offB1, bb0, bb1,
                                     perm0, perm1);
    k_post<<<2500, 256, 0, stream>>>(ei, et0, et1, dstOff, slotE, posD, rdP);
    k_wts<<<NN / 4, 256, 0, stream>>>(dstOff, rdP, wD0, wD1);

    // 3) layer 1: MFMA root GEMM + per-encoding (edge GEMM -> weighted reduce)
    {
        dim3 gb(NBT, 3);
        k_bgemm<FIN1, HH1><<<gb, 256, 0, stream>>>(xob, xab, xob, r1t, b1,
                                                   h1o, h1a, h1aa);
        const unsigned short* Xs[3] = {xob, xab, xob};
        float* Os[3] = {h1o, h1a, h1aa};
        unsigned short* Obs[3] = {h1bo, h1ba, h1baa};
        for (int enc = 0; enc < 3; enc++) {
            const int* perm = enc == 2 ? perm1 : perm0;
            const int* offB = enc == 2 ? offB1 : offB0;
            const int* tilB = enc == 2 ? tilB1 : tilB0;
            const int* tilT = enc == 2 ? tilT1 : tilT0;
            const float* wD = enc == 2 ? wD1 : wD0;
            k_gemm<FIN1, HH1><<<MAXT2, 256, 0, stream>>>(Xs[enc], msg, perm, offB,
                                                         tilB, tilT, ei, posD, w1t);
            k_reduce<HH1, true><<<NN / 4, 256, 0, stream>>>(msg, dstOff, wD,
                                                            Os[enc], Obs[enc]);
        }
    }

    // 4) layer 2: MFMA root GEMM + per-encoding (edge GEMM -> weighted reduce)
    {
        dim3 gb(NBT, 3);
        k_bgemm<HH1, HH2><<<gb, 256, 0, stream>>>(h1bo, h1ba, h1baa, r2t, b2,
                                                  x2o, x2a, x2aa);
        const unsigned short* Xs[3] = {h1bo, h1ba, h1baa};
        float* Os[3] = {x2o, x2a, x2aa};
        for (int enc = 0; enc < 3; enc++) {
            const int* perm = enc == 2 ? perm1 : perm0;
            const int* offB = enc == 2 ? offB1 : offB0;
            const int* tilB = enc == 2 ? tilB1 : tilB0;
            const int* tilT = enc == 2 ? tilT1 : tilT0;
            const float* wD = enc == 2 ? wD1 : wD0;
            k_gemm<HH1, HH2><<<MAXT2, 256, 0, stream>>>(Xs[enc], msg, perm, offB,
                                                        tilB, tilT, ei, posD, w2t);
            k_reduce<HH2, false><<<NN / 4, 256, 0, stream>>>(msg, dstOff, wD,
                                                             Os[enc], nullptr);
        }
    }

    // 5) readout + discriminator + classifier
    k_mean<<<256, 256, 0, stream>>>(x2o, csum);
    k_disc<<<(NN + 255) / 256, 256, 0, stream>>>(x2o, x2a, x2aa, csum, discW, discb,
                                                 ret_os, ret_osa);
    k_clsg<<<BB / CLS_BM, 256, 0, stream>>>(h1o, x2o, feat, attt, idx, cwt, clsb, log_out);
}

// Round 14
// 650.919 us; speedup vs baseline: 1.5461x; 1.1217x over previous
//
#include <hip/hip_runtime.h>
#include <hip/hip_bf16.h>

// ---------------- problem constants ----------------
#define NN 20000      // nodes
#define EE 640000     // edges
#define RR 65         // relations
#define FIN1 128      // input feat
#define HH1 64        // hidden1
#define HH2 32        // hidden2
#define BB 8192       // pairs

constexpr int BM = 128;                 // edge-tile rows per GEMM block
constexpr int NBH = 256;                // histogram/placement blocks
constexpr int EPB = EE / NBH;           // 2500 edges per block
constexpr int NBT = (NN + BM - 1) / BM; // 157 node tiles
constexpr int NOCT = 8;                 // src octiles (nodes per octile = 2500)
constexpr int NPO = NN / NOCT;          // 2500
constexpr int NB2 = NOCT * RR;          // 520 sort buckets (octile-major, relation inner)
constexpr int MAXT2 = EE / BM + NB2;    // 5520 tile upper bound

// classifier GEMM geometry (E[8192x448] @ clsW[448x65], padded)
constexpr int CLS_K  = 512;
constexpr int CLS_N  = 80;
constexpr int CLS_CK = 128;
constexpr int CLS_BM = 64;

typedef __attribute__((ext_vector_type(8))) short short8;   // 8 bf16 MFMA frag
typedef __attribute__((ext_vector_type(4))) float floatx4;  // 4 fp32 acc
typedef __attribute__((ext_vector_type(4))) unsigned int uint4e;  // nt-capable 16B
typedef __attribute__((ext_vector_type(2))) unsigned int uint2e;  // nt-capable 8B

// ---------------- workspace layout (bytes) ----------------
constexpr size_t aln(size_t x) { return (x + 255) & ~(size_t)255; }

constexpr size_t OFF_CSUM  = 0;                        // 32 f
constexpr size_t OFF_CNTD  = aln(OFF_CSUM + 32 * 4);  // NN int (dst degree)
constexpr size_t ZERO_BYTES = OFF_CNTD + (size_t)NN * 4;   // memset [0, ZERO_BYTES)
constexpr size_t OFF_DSTOFF = aln(ZERO_BYTES);         // NN+1 int
constexpr size_t OFF_BH0   = aln(OFF_DSTOFF + ((size_t)NN + 1) * 4); // NBH*NB2
constexpr size_t OFF_BH1   = OFF_BH0 + (size_t)NBH * NB2 * 4;
constexpr size_t OFF_BB0   = OFF_BH1 + (size_t)NBH * NB2 * 4;
constexpr size_t OFF_BB1   = OFF_BB0 + (size_t)NBH * NB2 * 4;
constexpr size_t OFF_HT    = aln(OFF_BB1 + (size_t)NBH * NB2 * 4);   // 2*NB2 int totals
constexpr size_t OFF_OFFB0 = aln(OFF_HT + (size_t)2 * NB2 * 4);      // NB2+1 int
constexpr size_t OFF_OFFB1 = OFF_OFFB0 + (NB2 + 1) * 4;
constexpr size_t OFF_TILB0 = aln(OFF_OFFB1 + (NB2 + 1) * 4);  // MAXT2 int
constexpr size_t OFF_TILT0 = OFF_TILB0 + (size_t)MAXT2 * 4;
constexpr size_t OFF_TILB1 = OFF_TILT0 + (size_t)MAXT2 * 4;
constexpr size_t OFF_TILT1 = OFF_TILB1 + (size_t)MAXT2 * 4;
constexpr size_t OFF_SLOT  = aln(OFF_TILT1 + (size_t)MAXT2 * 4);  // E int
constexpr size_t OFF_POSD  = OFF_SLOT + (size_t)EE * 4;           // E int (e -> dst pos)
constexpr size_t OFF_RDP   = OFF_POSD + (size_t)EE * 4;           // E uint (pos -> r0|r1<<16)
constexpr size_t OFF_WD0   = OFF_RDP + (size_t)EE * 4;            // E float (pos-space weights)
constexpr size_t OFF_WD1   = OFF_WD0 + (size_t)EE * 4;
constexpr size_t OFF_PERM0 = OFF_WD1 + (size_t)EE * 4;            // E uint (srcLocal<<20|pos)
constexpr size_t OFF_PERM1 = OFF_PERM0 + (size_t)EE * 4;
constexpr size_t OFF_XOB   = aln(OFF_PERM1 + (size_t)EE * 4);     // N*F bf16
constexpr size_t OFF_XAB   = OFF_XOB + (size_t)NN * FIN1 * 2;
constexpr size_t OFF_H1    = aln(OFF_XAB + (size_t)NN * FIN1 * 2); // 3 * N*64 f
constexpr size_t OFF_H1B   = OFF_H1 + (size_t)3 * NN * HH1 * 4;    // 3 * N*64 bf16
constexpr size_t OFF_X2A   = OFF_H1B + (size_t)3 * NN * HH1 * 2;   // N*32 f
constexpr size_t OFF_X2AA  = OFF_X2A + (size_t)NN * HH2 * 4;
constexpr size_t OFF_W1BT  = OFF_X2AA + (size_t)NN * HH2 * 4;      // R*64*128 bf16
constexpr size_t OFF_W2BT  = OFF_W1BT + (size_t)RR * HH1 * FIN1 * 2;
constexpr size_t OFF_R1T   = OFF_W2BT + (size_t)RR * HH2 * HH1 * 2;
constexpr size_t OFF_R2T   = OFF_R1T + (size_t)HH1 * FIN1 * 2;
constexpr size_t OFF_CWT   = OFF_R2T + (size_t)HH2 * HH1 * 2;
constexpr size_t OFF_PART  = aln(OFF_CWT + (size_t)CLS_N * CLS_K * 2); // 256*32 f partials
constexpr size_t OFF_MSG   = aln(OFF_PART + (size_t)256 * 32 * 4);     // E*64 bf16
constexpr size_t WS_END    = OFF_MSG + (size_t)EE * HH1 * 2;

// output offsets (floats)
constexpr size_t O_LOG  = 0;
constexpr size_t O_ROS  = (size_t)BB * RR;
constexpr size_t O_ROSA = O_ROS + (size_t)NN * 2;
constexpr size_t O_X2O  = O_ROSA + (size_t)NN * 2;

__device__ inline unsigned short f2bf(float f) {
    __hip_bfloat16 h = __float2bfloat16(f);
    return *reinterpret_cast<unsigned short*>(&h);
}
__device__ inline float bfbits2f(unsigned int hi_bits) {
    return __uint_as_float(hi_bits);
}

// ---------------- preprocessing ----------------
// per-block 520-bin (octile,relation) histograms via LDS -> plain stores,
// per-dst degree + slot (benign 20k-addr scatter atomic), fused bf16 conversions.
__global__ void k_hist(const int* __restrict__ ei, const int* __restrict__ et0,
                       const int* __restrict__ et1,
                       int* cntD, int* __restrict__ slotE,
                       int* __restrict__ bh0, int* __restrict__ bh1,
                       const float* __restrict__ x_o, const float* __restrict__ x_a,
                       const float* __restrict__ W1, const float* __restrict__ W2,
                       const float* __restrict__ root1, const float* __restrict__ root2,
                       const float* __restrict__ clsW,
                       unsigned short* xob, unsigned short* xab,
                       unsigned short* w1t, unsigned short* w2t,
                       unsigned short* r1t, unsigned short* r2t,
                       unsigned short* cwt) {
    __shared__ int lh0[NB2], lh1[NB2];
    int t = threadIdx.x;
    for (int p = t; p < NB2; p += 256) { lh0[p] = 0; lh1[p] = 0; }
    __syncthreads();
    int base = blockIdx.x * EPB;
    for (int i = t; i < EPB; i += 256) {
        int e = base + i;
        int oct = ei[e] / NPO;
        atomicAdd(&lh0[oct * RR + et0[e]], 1);
        atomicAdd(&lh1[oct * RR + et1[e]], 1);
        slotE[e] = atomicAdd(&cntD[ei[EE + e]], 1);
    }
    __syncthreads();
    for (int p = t; p < NB2; p += 256) {
        bh0[blockIdx.x * NB2 + p] = lh0[p];
        bh1[blockIdx.x * NB2 + p] = lh1[p];
    }
    // streaming conversions (grid-stride over 256-block grid)
    int stride = gridDim.x * 256;
    int i0 = blockIdx.x * 256 + t;
    const int NX = NN * FIN1;
    for (int i = i0; i < NX; i += stride) { xob[i] = f2bf(x_o[i]); xab[i] = f2bf(x_a[i]); }
    const int NW1 = RR * HH1 * FIN1;
    for (int i = i0; i < NW1; i += stride) {
        int k = i % FIN1; int rh = i / FIN1; int hh = rh % HH1; int r = rh / HH1;
        w1t[i] = f2bf(W1[((size_t)r * FIN1 + k) * HH1 + hh]);
    }
    const int NW2 = RR * HH2 * HH1;
    for (int i = i0; i < NW2; i += stride) {
        int k = i % HH1; int rh = i / HH1; int hh = rh % HH2; int r = rh / HH2;
        w2t[i] = f2bf(W2[((size_t)r * HH1 + k) * HH2 + hh]);
    }
    const int NR1 = HH1 * FIN1;
    for (int i = i0; i < NR1; i += stride) {
        int k = i % FIN1; int hh = i / FIN1;
        r1t[i] = f2bf(root1[(size_t)k * HH1 + hh]);
    }
    const int NR2 = HH2 * HH1;
    for (int i = i0; i < NR2; i += stride) {
        int k = i % HH1; int hh = i / HH1;
        r2t[i] = f2bf(root2[(size_t)k * HH2 + hh]);
    }
    const int NCW = CLS_N * CLS_K;
    for (int i = i0; i < NCW; i += stride) {
        int k = i % CLS_K; int n = i / CLS_K;
        cwt[i] = (n < RR && k < 448) ? f2bf(clsW[(size_t)k * RR + n]) : (unsigned short)0;
    }
}

// exclusive scan of per-dst degrees -> dstOff[NN+1] (single block)
__global__ void k_scanD(const int* __restrict__ cntD, int* __restrict__ dstOff) {
    __shared__ int s[256];
    int t = threadIdx.x;
    constexpr int PER = (NN + 255) / 256;
    int lo = t * PER, hi = min(NN, lo + PER);
    int sum = 0;
    for (int i = lo; i < hi; i++) sum += cntD[i];
    s[t] = sum;
    __syncthreads();
    for (int ofs = 1; ofs < 256; ofs <<= 1) {
        int v = 0;
        if (t >= ofs) v = s[t - ofs];
        __syncthreads();
        if (t >= ofs) s[t] += v;
        __syncthreads();
    }
    int run = s[t] - sum;
    for (int i = lo; i < hi; i++) { dstOff[i] = run; run += cntD[i]; }
    if (t == 255) dstOff[NN] = run;
}

// posD (sequential write) + rdP (the single scattered-write array)
__global__ void k_post(const int* __restrict__ ei, const int* __restrict__ et0,
                       const int* __restrict__ et1, const int* __restrict__ dstOff,
                       const int* __restrict__ slotE,
                       int* __restrict__ posD, unsigned int* __restrict__ rdP) {
    int e = blockIdx.x * 256 + threadIdx.x;
    if (e < EE) {
        int d = ei[EE + e];
        int pos = dstOff[d] + slotE[e];
        posD[e] = pos;
        rdP[pos] = (unsigned)et0[e] | ((unsigned)et1[e] << 16);
    }
}

// phase 1: per-bucket exclusive prefix over the 256 histogram blocks.
// One WAVE per (sort, bucket) column: lane l holds blocks 4l..4l+3, wave-level
// shfl scan — all 1040 columns in flight across the grid (no serial walk).
__global__ void k_scanB1(const int* __restrict__ bh0, const int* __restrict__ bh1,
                         int* __restrict__ bb0, int* __restrict__ bb1,
                         int* __restrict__ hT) {
    int w = (blockIdx.x * 256 + threadIdx.x) >> 6;
    int lane = threadIdx.x & 63;
    if (w >= 2 * NB2) return;
    int s = w / NB2, k = w % NB2;
    const int* bh = s ? bh1 : bh0;
    int* bb = s ? bb1 : bb0;
    int v[4];
    #pragma unroll
    for (int i = 0; i < 4; i++) v[i] = bh[(size_t)(lane * 4 + i) * NB2 + k];
    int ls = v[0] + v[1] + v[2] + v[3];
    int inc = ls;
    #pragma unroll
    for (int ofs = 1; ofs < 64; ofs <<= 1) {
        int o = __shfl_up(inc, ofs);
        if (lane >= ofs) inc += o;
    }
    int run = inc - ls;   // exclusive base for this lane
    #pragma unroll
    for (int i = 0; i < 4; i++) {
        bb[(size_t)(lane * 4 + i) * NB2 + k] = run;
        run += v[i];
    }
    if (lane == 63) hT[s * NB2 + k] = run;  // column total
}

// phase 2 (single block): bucket offsets + tile tables from the 1040 totals.
__global__ void k_scanB2(const int* __restrict__ hT,
                         int* offB0, int* offB1,
                         int* tilB0, int* tilT0, int* tilB1, int* tilT1) {
    __shared__ int h[2][NB2];
    __shared__ int o[2][NB2 + 1];
    __shared__ int to[2][NB2 + 1];
    __shared__ int csumE[2][8], csumT[2][8];
    int t = threadIdx.x;
    for (int p = t; p < 2 * NB2; p += 256) h[p / NB2][p % NB2] = hT[p];
    __syncthreads();
    if (t < 16) {
        int s = t / 8, c = t % 8;
        int runE = 0, runT = 0;
        for (int k = c * RR; k < (c + 1) * RR; k++) {
            o[s][k] = runE;  runE += h[s][k];
            to[s][k] = runT; runT += (h[s][k] + BM - 1) / BM;
        }
        csumE[s][c] = runE; csumT[s][c] = runT;
    }
    __syncthreads();
    if (t < 2) {
        int runE = 0, runT = 0;
        for (int c = 0; c < 8; c++) {
            int e = csumE[t][c], tt = csumT[t][c];
            csumE[t][c] = runE; csumT[t][c] = runT;
            runE += e; runT += tt;
        }
        o[t][NB2] = runE; to[t][NB2] = runT;
    }
    __syncthreads();
    if (t < 16) {
        int s = t / 8, c = t % 8;
        for (int k = c * RR; k < (c + 1) * RR; k++) {
            o[s][k] += csumE[s][c];
            to[s][k] += csumT[s][c];
        }
    }
    __syncthreads();
    for (int p = t; p <= NB2; p += 256) { offB0[p] = o[0][p]; offB1[p] = o[1][p]; }
    for (int i = t; i < MAXT2; i += 256) {
        #pragma unroll
        for (int s = 0; s < 2; s++) {
            int total = to[s][NB2];
            int bkt = -1, ti = 0;
            if (i < total) {
                int lo = 0, hi = NB2;
                while (hi - lo > 1) { int mid = (lo + hi) >> 1; if (to[s][mid] <= i) lo = mid; else hi = mid; }
                bkt = lo;
                ti = i - to[s][lo];
            }
            if (s == 0) { tilB0[i] = bkt; tilT0[i] = ti; }
            else        { tilB1[i] = bkt; tilT1[i] = ti; }
        }
    }
}

// bucket-sorted perm placement with deterministic bases.
// perm stores PACKED metadata: (srcLocal << 20) | pos — k_gemm never touches
// ei/posD (kills the 2x128 scattered metadata gathers per tile).
__global__ void k_fillB(const int* __restrict__ ei, const int* __restrict__ et0,
                        const int* __restrict__ et1, const int* __restrict__ posD,
                        const int* __restrict__ offB0, const int* __restrict__ offB1,
                        const int* __restrict__ bb0, const int* __restrict__ bb1,
                        unsigned int* perm0, unsigned int* perm1) {
    __shared__ int lc[2][NB2];
    __shared__ int lb[2][NB2];
    int t = threadIdx.x;
    for (int p = t; p < NB2; p += 256) {
        lc[0][p] = 0; lc[1][p] = 0;
        lb[0][p] = offB0[p] + bb0[blockIdx.x * NB2 + p];
        lb[1][p] = offB1[p] + bb1[blockIdx.x * NB2 + p];
    }
    __syncthreads();
    int base = blockIdx.x * EPB;
    for (int i = t; i < EPB; i += 256) {
        int e = base + i;
        int src = ei[e];                 // sequential read
        int pos = posD[e];               // sequential read
        int oct = src / NPO;
        unsigned int packed = ((unsigned)(src - oct * NPO) << 20) | (unsigned)pos;
        int k0 = oct * RR + et0[e];
        int k1 = oct * RR + et1[e];
        int p0 = atomicAdd(&lc[0][k0], 1);
        int p1 = atomicAdd(&lc[1][k1], 1);
        perm0[lb[0][k0] + p0] = packed;
        perm1[lb[1][k1] + p1] = packed;
    }
}

// per-(relation,dst) mean weights inside each dst segment -> pos-space arrays
__global__ void k_wts(const int* __restrict__ dstOff, const unsigned int* __restrict__ rdP,
                      float* __restrict__ wD0, float* __restrict__ wD1) {
    constexpr int CAP = 96;
    __shared__ unsigned int ld[4][CAP];
    int wave = threadIdx.x >> 6;
    int lane = threadIdx.x & 63;
    int d = blockIdx.x * 4 + wave;
    int j0 = 0, deg = 0;
    if (d < NN) { j0 = dstOff[d]; deg = dstOff[d + 1] - j0; }
    for (int j = lane; j < deg && j < CAP; j += 64) ld[wave][j] = rdP[j0 + j];
    __syncthreads();
    for (int j = lane; j < deg; j += 64) {
        unsigned int my = (j < CAP) ? ld[wave][j] : rdP[j0 + j];
        unsigned int m0 = my & 0xffffu, m1 = my >> 16;
        int c0 = 0, c1 = 0;
        for (int k = 0; k < deg; k++) {
            unsigned int p = (k < CAP) ? ld[wave][k] : rdP[j0 + k];
            c0 += ((p & 0xffffu) == m0);
            c1 += ((p >> 16) == m1);
        }
        wD0[j0 + j] = 1.0f / (float)c0;
        wD1[j0 + j] = 1.0f / (float)c1;
    }
}

// root-term GEMM via MFMA: O[n,h] = Xb[n,:] @ rootT[h,:] + bias[h]  (fp32 out)
template <int FIN, int HOUT>
__launch_bounds__(256, 3)
__global__ void k_bgemm(const unsigned short* __restrict__ X0,
                        const unsigned short* __restrict__ X1,
                        const unsigned short* __restrict__ X2,
                        const unsigned short* __restrict__ rootT,
                        const float* __restrict__ bias,
                        float* O0, float* O1, float* O2) {
    const int enc = blockIdx.y;
    const unsigned short* X = enc == 0 ? X0 : enc == 1 ? X1 : X2;
    float* O = enc == 0 ? O0 : enc == 1 ? O1 : O2;
    int n0 = blockIdx.x * BM;
    int mcount = min(BM, NN - n0);

    constexpr int LDK = FIN + 8;
    __shared__ unsigned short As[BM][LDK];
    __shared__ unsigned short Bs[HOUT][LDK];

    int tid = threadIdx.x;
    {
        constexpr int CHB = HOUT * FIN / 8;
        for (int c = tid; c < CHB; c += 256) {
            int row = c / (FIN / 8), cc = c % (FIN / 8);
            *(uint4*)&Bs[row][cc * 8] = *(const uint4*)&rootT[row * FIN + cc * 8];
        }
    }
    {
        constexpr int CHA = BM * FIN / 8;
        for (int c = tid; c < CHA; c += 256) {
            int row = c / (FIN / 8), cc = c % (FIN / 8);
            uint4 v = {0u, 0u, 0u, 0u};
            if (row < mcount) v = *(const uint4*)&X[(size_t)(n0 + row) * FIN + cc * 8];
            *(uint4*)&As[row][cc * 8] = v;
        }
    }
    __syncthreads();

    const int wave = tid >> 6;
    const int lane = tid & 63;
    const int q = lane >> 4;
    const int ln = lane & 15;
    constexpr int NT = HOUT / 16;
    constexpr int KS = FIN / 32;
    const int mbase = wave * 32;

    floatx4 acc[2][NT];
    #pragma unroll
    for (int a = 0; a < 2; a++)
        #pragma unroll
        for (int nt = 0; nt < NT; nt++) acc[a][nt] = floatx4{0.f, 0.f, 0.f, 0.f};

    for (int ks = 0; ks < KS; ks++) {
        int kk = ks * 32 + q * 8;
        short8 af0 = *(const short8*)&As[mbase + ln][kk];
        short8 af1 = *(const short8*)&As[mbase + 16 + ln][kk];
        #pragma unroll
        for (int nt = 0; nt < NT; nt++) {
            short8 bf = *(const short8*)&Bs[nt * 16 + ln][kk];
            acc[0][nt] = __builtin_amdgcn_mfma_f32_16x16x32_bf16(af0, bf, acc[0][nt], 0, 0, 0);
            acc[1][nt] = __builtin_amdgcn_mfma_f32_16x16x32_bf16(af1, bf, acc[1][nt], 0, 0, 0);
        }
    }

    #pragma unroll
    for (int mt = 0; mt < 2; mt++) {
        #pragma unroll
        for (int rr2 = 0; rr2 < 4; rr2++) {
            int i = mbase + mt * 16 + q * 4 + rr2;
            int n = n0 + i;
            if (i < mcount) {
                #pragma unroll
                for (int nt = 0; nt < NT; nt++)
                    O[(size_t)n * HOUT + nt * 16 + ln] = acc[mt][nt][rr2] + bias[nt * 16 + ln];
            }
        }
    }
}

// bucket-grouped gather-GEMM with MFMA; tiles dispatched (src-octile, relation)
// major; per-edge metadata comes packed in perm (sequential 512B read/tile).
// Epilogue writes unweighted bf16 msg rows via NONTEMPORAL stores.
template <int FIN, int HOUT>
__launch_bounds__(256, (FIN == 128 ? 3 : 4))
__global__ void k_gemm(const unsigned short* __restrict__ X,
                       unsigned short* __restrict__ msg,
                       const unsigned int* __restrict__ perm,
                       const int* __restrict__ offB,
                       const int* __restrict__ tilB, const int* __restrict__ tilT,
                       const unsigned short* __restrict__ WT) {
    int b = blockIdx.x;
    int bkt = tilB[b];
    if (bkt < 0) return;
    int r = bkt % RR;
    int srcBase = (bkt / RR) * NPO;
    int t = tilT[b];
    int ebase = offB[bkt] + t * BM;
    int mcount = min(BM, offB[bkt + 1] - ebase);

    constexpr int LDK = FIN + 8;
    __shared__ unsigned short As[BM][LDK];
    __shared__ unsigned short Bs[HOUT][LDK];
    __shared__ int Sr[BM];
    __shared__ int Pd[BM];

    int tid = threadIdx.x;
    if (tid < BM) {
        if (tid < mcount) {
            unsigned int p = perm[ebase + tid];   // sequential
            Sr[tid] = srcBase + (int)(p >> 20);
            Pd[tid] = (int)(p & 0xFFFFFu);
        } else { Sr[tid] = -1; Pd[tid] = 0; }
    }
    __syncthreads();

    {
        const unsigned short* Wr = WT + (size_t)r * HOUT * FIN;
        constexpr int CHB = HOUT * FIN / 8;
        for (int c = tid; c < CHB; c += 256) {
            int row = c / (FIN / 8), cc = c % (FIN / 8);
            *(uint4*)&Bs[row][cc * 8] = *(const uint4*)&Wr[row * FIN + cc * 8];
        }
    }
    {
        constexpr int CHA = BM * FIN / 8;
        for (int c = tid; c < CHA; c += 256) {
            int row = c / (FIN / 8), cc = c % (FIN / 8);
            int s = Sr[row];
            uint4 v = {0u, 0u, 0u, 0u};
            if (s >= 0) v = *(const uint4*)&X[(size_t)s * FIN + cc * 8];
            *(uint4*)&As[row][cc * 8] = v;
        }
    }
    __syncthreads();

    const int wave = tid >> 6;
    const int lane = tid & 63;
    const int q = lane >> 4;
    const int ln = lane & 15;
    constexpr int NT = HOUT / 16;
    constexpr int KS = FIN / 32;
    const int mbase = wave * 32;

    floatx4 acc[2][NT];
    #pragma unroll
    for (int a = 0; a < 2; a++)
        #pragma unroll
        for (int nt = 0; nt < NT; nt++) acc[a][nt] = floatx4{0.f, 0.f, 0.f, 0.f};

    for (int ks = 0; ks < KS; ks++) {
        int kk = ks * 32 + q * 8;
        short8 af0 = *(const short8*)&As[mbase + ln][kk];
        short8 af1 = *(const short8*)&As[mbase + 16 + ln][kk];
        #pragma unroll
        for (int nt = 0; nt < NT; nt++) {
            short8 bf = *(const short8*)&Bs[nt * 16 + ln][kk];
            acc[0][nt] = __builtin_amdgcn_mfma_f32_16x16x32_bf16(af0, bf, acc[0][nt], 0, 0, 0);
            acc[1][nt] = __builtin_amdgcn_mfma_f32_16x16x32_bf16(af1, bf, acc[1][nt], 0, 0, 0);
        }
    }

    // epilogue: bf16 msgs through LDS (overlay As), coalesced full-line
    // NONTEMPORAL scatter (no L2 retention for the write-only msg stream)
    __syncthreads();
    constexpr int LDM = HOUT + 8;
    unsigned short* Ms = &As[0][0];
    #pragma unroll
    for (int mt = 0; mt < 2; mt++) {
        #pragma unroll
        for (int rr2 = 0; rr2 < 4; rr2++) {
            int i = mbase + mt * 16 + q * 4 + rr2;
            #pragma unroll
            for (int nt = 0; nt < NT; nt++)
                Ms[i * LDM + nt * 16 + ln] = f2bf(acc[mt][nt][rr2]);
        }
    }
    __syncthreads();
    constexpr int CH = HOUT / 8;
    for (int c = tid; c < BM * CH; c += 256) {
        int row = c / CH, cc = c % CH;
        if (row < mcount) {
            uint4e v = *(const uint4e*)&Ms[row * LDM + cc * 8];
            __builtin_nontemporal_store(v, (uint4e*)&msg[(size_t)Pd[row] * HOUT + cc * 8]);
        }
    }
}

// weighted segment-sum of msg rows per dst + root base; optional relu+bf16.
// DOUBLE accumulation: the per-dst multiset of fp32 products is fixed, and
// 53-bit summation makes the result independent of the (nondeterministic)
// edge->slot assignment order — outputs are stable across graph replays.
template <int H, bool RELU>
__global__ void k_reduce(const unsigned short* __restrict__ msg,
                         const int* __restrict__ dstOff,
                         const float* __restrict__ wD,
                         float* __restrict__ base_io,
                         unsigned short* __restrict__ bfout) {
    int d = blockIdx.x * 4 + (threadIdx.x >> 6);
    if (d >= NN) return;
    int lane = threadIdx.x & 63;
    constexpr int HC = H / 4;
    constexpr int RPI = 64 / HC;
    int sub = lane / HC;
    int c4 = lane % HC;
    int j0 = dstOff[d], j1 = dstOff[d + 1];
    double a0 = 0.0, a1 = 0.0, a2 = 0.0, a3 = 0.0;
    for (int j = j0 + sub; j < j1; j += RPI) {
        float w = wD[j];
        uint2e v = __builtin_nontemporal_load((const uint2e*)&msg[(size_t)j * H + c4 * 4]);
        a0 += (double)(w * bfbits2f(v.x << 16));
        a1 += (double)(w * bfbits2f(v.x & 0xffff0000u));
        a2 += (double)(w * bfbits2f(v.y << 16));
        a3 += (double)(w * bfbits2f(v.y & 0xffff0000u));
    }
    #pragma unroll
    for (int ofs = 32; ofs >= HC; ofs >>= 1) {
        a0 += __shfl_down(a0, ofs); a1 += __shfl_down(a1, ofs);
        a2 += __shfl_down(a2, ofs); a3 += __shfl_down(a3, ofs);
    }
    if (lane < HC) {
        size_t o = (size_t)d * H + c4 * 4;
        float v0 = base_io[o] + (float)a0, v1 = base_io[o + 1] + (float)a1;
        float v2 = base_io[o + 2] + (float)a2, v3 = base_io[o + 3] + (float)a3;
        if (RELU) {
            v0 = fmaxf(v0, 0.f); v1 = fmaxf(v1, 0.f);
            v2 = fmaxf(v2, 0.f); v3 = fmaxf(v3, 0.f);
        }
        base_io[o] = v0; base_io[o + 1] = v1; base_io[o + 2] = v2; base_io[o + 3] = v3;
        if (RELU) {
            bfout[o] = f2bf(v0); bfout[o + 1] = f2bf(v1);
            bfout[o + 2] = f2bf(v2); bfout[o + 3] = f2bf(v3);
        }
    }
}

// column partial sums of x2_o -> part[block][32] (plain stores, deterministic)
__global__ void k_mean(const float* __restrict__ x2o, float* __restrict__ part) {
    __shared__ float s[256];
    int t = threadIdx.x; int hh = t & 31; int g = t >> 5;
    float acc = 0.f;
    for (int n = blockIdx.x * 8 + g; n < NN; n += gridDim.x * 8)
        acc += x2o[(size_t)n * 32 + hh];
    s[t] = acc;
    __syncthreads();
    if (t < 32) {
        float v = 0.f;
        for (int gg = 0; gg < 8; gg++) v += s[gg * 32 + t];
        part[blockIdx.x * 32 + t] = v;
    }
}

// deterministic final column sum: csum[c] = sum_b part[b][c] in fixed order
__global__ void k_csum(const float* __restrict__ part, float* __restrict__ csum) {
    int t = threadIdx.x;
    if (t < 32) {
        double a = 0.0;
        for (int b = 0; b < 256; b++) a += (double)part[b * 32 + t];
        csum[t] = (float)a;
    }
}

// c = sigmoid(csum/N); v = disc_W @ c; bilinear scores
__global__ void k_disc(const float* __restrict__ x2o, const float* __restrict__ x2a,
                       const float* __restrict__ x2aa, const float* __restrict__ csum,
                       const float* __restrict__ discW, const float* __restrict__ discb,
                       float* ret_os, float* ret_osa) {
    __shared__ float c[32], v[32];
    int t = threadIdx.x;
    if (t < 32) c[t] = 1.f / (1.f + expf(-csum[t] * (1.f / NN)));
    __syncthreads();
    if (t < 32) {
        float a = 0.f;
        for (int j = 0; j < 32; j++) a += discW[t * 32 + j] * c[j];
        v[t] = a;
    }
    __syncthreads();
    float db = discb[0];
    int n = blockIdx.x * 256 + t;
    if (n < NN) {
        float s1 = 0.f, s2 = 0.f, s3 = 0.f;
        for (int j = 0; j < 32; j++) {
            float vj = v[j];
            s1 += x2o[(size_t)n * 32 + j] * vj;
            s2 += x2a[(size_t)n * 32 + j] * vj;
            s3 += x2aa[(size_t)n * 32 + j] * vj;
        }
        ret_os[n * 2] = s1 + db;  ret_os[n * 2 + 1] = s2 + db;
        ret_osa[n * 2] = s1 + db; ret_osa[n * 2 + 1] = s3 + db;
    }
}

// pair classifier as MFMA GEMM (K padded to 512, N padded to 80)
__launch_bounds__(256, 2)
__global__ void k_clsg(const float* __restrict__ h1o, const float* __restrict__ x2o,
                       const float* __restrict__ feat, const float* __restrict__ attt,
                       const int* __restrict__ idx,
                       const unsigned short* __restrict__ cwt,
                       const float* __restrict__ clsb, float* __restrict__ log_out) {
    constexpr int LDK = CLS_CK + 8;
    __shared__ unsigned short As[CLS_BM][LDK];
    __shared__ unsigned short Bs[CLS_N][LDK];
    __shared__ int nd[2][CLS_BM];

    int tid = threadIdx.x;
    int p0 = blockIdx.x * CLS_BM;
    if (tid < CLS_BM) {
        nd[0][tid] = idx[p0 + tid];
        nd[1][tid] = idx[BB + p0 + tid];
    }
    float a0 = attt[0], a1 = attt[1];

    const int wave = tid >> 6;
    const int lane = tid & 63;
    const int q = lane >> 4;
    const int ln = lane & 15;
    constexpr int NT = CLS_N / 16;
    const int mbase = wave * 16;

    floatx4 acc[NT];
    #pragma unroll
    for (int nt = 0; nt < NT; nt++) acc[nt] = floatx4{0.f, 0.f, 0.f, 0.f};

    for (int ch = 0; ch < CLS_K / CLS_CK; ch++) {
        int kbase = ch * CLS_CK;
        __syncthreads();
        for (int c = tid; c < CLS_N * CLS_CK / 8; c += 256) {
            int row = c / (CLS_CK / 8), cc = c % (CLS_CK / 8);
            *(uint4*)&Bs[row][cc * 8] = *(const uint4*)&cwt[(size_t)row * CLS_K + kbase + cc * 8];
        }
        for (int c = tid; c < CLS_BM * CLS_CK / 4; c += 256) {
            int row = c / (CLS_CK / 4);
            int j4 = (c % (CLS_CK / 4)) * 4;
            int j = kbase + j4;
            float4 v = {0.f, 0.f, 0.f, 0.f};
            if (j < 448) {
                int hseg = j / 224, jj = j % 224;
                int node = nd[hseg][row];
                if (jj < 64) {
                    v = *(const float4*)&h1o[(size_t)node * 64 + jj];
                    v.x *= a0; v.y *= a0; v.z *= a0; v.w *= a0;
                } else if (jj < 96) {
                    v = *(const float4*)&x2o[(size_t)node * 32 + (jj - 64)];
                    v.x *= a1; v.y *= a1; v.z *= a1; v.w *= a1;
                } else {
                    v = *(const float4*)&feat[(size_t)node * 128 + (jj - 96)];
                }
            }
            uint2 pk;
            pk.x = (unsigned)f2bf(v.x) | ((unsigned)f2bf(v.y) << 16);
            pk.y = (unsigned)f2bf(v.z) | ((unsigned)f2bf(v.w) << 16);
            *(uint2*)&As[row][j4] = pk;
        }
        __syncthreads();
        #pragma unroll
        for (int ks = 0; ks < CLS_CK / 32; ks++) {
            int kk = ks * 32 + q * 8;
            short8 af = *(const short8*)&As[mbase + ln][kk];
            #pragma unroll
            for (int nt = 0; nt < NT; nt++) {
                short8 bf = *(const short8*)&Bs[nt * 16 + ln][kk];
                acc[nt] = __builtin_amdgcn_mfma_f32_16x16x32_bf16(af, bf, acc[nt], 0, 0, 0);
            }
        }
    }

    #pragma unroll
    for (int rr2 = 0; rr2 < 4; rr2++) {
        int i = mbase + q * 4 + rr2;
        int pair = p0 + i;
        #pragma unroll
        for (int nt = 0; nt < NT; nt++) {
            int col = nt * 16 + ln;
            if (col < RR)
                log_out[(size_t)pair * RR + col] = acc[nt][rr2] + clsb[col];
        }
    }
}

extern "C" void kernel_launch(void* const* d_in, const int* in_sizes, int n_in,
                              void* d_out, int out_size, void* d_ws, size_t ws_size,
                              hipStream_t stream) {
    const float* x_o   = (const float*)d_in[0];
    const float* x_a   = (const float*)d_in[1];
    const float* feat  = (const float*)d_in[2];
    const float* W1    = (const float*)d_in[3];
    const float* root1 = (const float*)d_in[4];
    const float* b1    = (const float*)d_in[5];
    const float* W2    = (const float*)d_in[6];
    const float* root2 = (const float*)d_in[7];
    const float* b2    = (const float*)d_in[8];
    const float* attt  = (const float*)d_in[9];
    const float* discW = (const float*)d_in[10];
    const float* discb = (const float*)d_in[11];
    const float* clsW  = (const float*)d_in[12];
    const float* clsb  = (const float*)d_in[13];
    const int* ei      = (const int*)d_in[14];
    const int* et0     = (const int*)d_in[15];
    const int* et1     = (const int*)d_in[16];
    const int* idx     = (const int*)d_in[17];

    char* ws = (char*)d_ws;
    float* csum = (float*)(ws + OFF_CSUM);
    int* cntD  = (int*)(ws + OFF_CNTD);
    int* dstOff = (int*)(ws + OFF_DSTOFF);
    int* bh0   = (int*)(ws + OFF_BH0);
    int* bh1   = (int*)(ws + OFF_BH1);
    int* bb0   = (int*)(ws + OFF_BB0);
    int* bb1   = (int*)(ws + OFF_BB1);
    int* hT    = (int*)(ws + OFF_HT);
    int* offB0 = (int*)(ws + OFF_OFFB0);
    int* offB1 = (int*)(ws + OFF_OFFB1);
    int* tilB0 = (int*)(ws + OFF_TILB0);
    int* tilT0 = (int*)(ws + OFF_TILT0);
    int* tilB1 = (int*)(ws + OFF_TILB1);
    int* tilT1 = (int*)(ws + OFF_TILT1);
    int* slotE = (int*)(ws + OFF_SLOT);
    int* posD  = (int*)(ws + OFF_POSD);
    unsigned int* rdP = (unsigned int*)(ws + OFF_RDP);
    float* wD0 = (float*)(ws + OFF_WD0);
    float* wD1 = (float*)(ws + OFF_WD1);
    unsigned int* perm0 = (unsigned int*)(ws + OFF_PERM0);
    unsigned int* perm1 = (unsigned int*)(ws + OFF_PERM1);
    unsigned short* xob = (unsigned short*)(ws + OFF_XOB);
    unsigned short* xab = (unsigned short*)(ws + OFF_XAB);
    float* h1o  = (float*)(ws + OFF_H1);
    float* h1a  = h1o + (size_t)NN * HH1;
    float* h1aa = h1a + (size_t)NN * HH1;
    unsigned short* h1bo  = (unsigned short*)(ws + OFF_H1B);
    unsigned short* h1ba  = h1bo + (size_t)NN * HH1;
    unsigned short* h1baa = h1ba + (size_t)NN * HH1;
    float* x2a  = (float*)(ws + OFF_X2A);
    float* x2aa = (float*)(ws + OFF_X2AA);
    unsigned short* w1t = (unsigned short*)(ws + OFF_W1BT);
    unsigned short* w2t = (unsigned short*)(ws + OFF_W2BT);
    unsigned short* r1t = (unsigned short*)(ws + OFF_R1T);
    unsigned short* r2t = (unsigned short*)(ws + OFF_R2T);
    unsigned short* cwt = (unsigned short*)(ws + OFF_CWT);
    float* part = (float*)(ws + OFF_PART);
    unsigned short* msg = (unsigned short*)(ws + OFF_MSG);

    float* out = (float*)d_out;
    float* log_out = out + O_LOG;
    float* ret_os  = out + O_ROS;
    float* ret_osa = out + O_ROSA;
    float* x2o     = out + O_X2O;

    // 1) zero control block (csum + cntD) — ~80 KB
    hipMemsetAsync(ws, 0, ZERO_BYTES, stream);

    // 2) preprocessing: (octile,relation) bucket sort with packed metadata
    k_hist<<<NBH, 256, 0, stream>>>(ei, et0, et1, cntD, slotE, bh0, bh1,
                                    x_o, x_a, W1, W2, root1, root2, clsW,
                                    xob, xab, w1t, w2t, r1t, r2t, cwt);
    k_scanD<<<1, 256, 0, stream>>>(cntD, dstOff);
    k_post<<<2500, 256, 0, stream>>>(ei, et0, et1, dstOff, slotE, posD, rdP);
    k_scanB1<<<(2 * NB2 + 3) / 4, 256, 0, stream>>>(bh0, bh1, bb0, bb1, hT);
    k_scanB2<<<1, 256, 0, stream>>>(hT, offB0, offB1,
                                    tilB0, tilT0, tilB1, tilT1);
    k_fillB<<<NBH, 256, 0, stream>>>(ei, et0, et1, posD, offB0, offB1, bb0, bb1,
                                     perm0, perm1);
    k_wts<<<NN / 4, 256, 0, stream>>>(dstOff, rdP, wD0, wD1);

    // 3) layer 1: MFMA root GEMM + per-encoding (edge GEMM -> weighted reduce)
    {
        dim3 gb(NBT, 3);
        k_bgemm<FIN1, HH1><<<gb, 256, 0, stream>>>(xob, xab, xob, r1t, b1,
                                                   h1o, h1a, h1aa);
        const unsigned short* Xs[3] = {xob, xab, xob};
        float* Os[3] = {h1o, h1a, h1aa};
        unsigned short* Obs[3] = {h1bo, h1ba, h1baa};
        for (int enc = 0; enc < 3; enc++) {
            const unsigned int* perm = enc == 2 ? perm1 : perm0;
            const int* offB = enc == 2 ? offB1 : offB0;
            const int* tilB = enc == 2 ? tilB1 : tilB0;
            const int* tilT = enc == 2 ? tilT1 : tilT0;
            const float* wD = enc == 2 ? wD1 : wD0;
            k_gemm<FIN1, HH1><<<MAXT2, 256, 0, stream>>>(Xs[enc], msg, perm, offB,
                                                         tilB, tilT, w1t);
            k_reduce<HH1, true><<<NN / 4, 256, 0, stream>>>(msg, dstOff, wD,
                                                            Os[enc], Obs[enc]);
        }
    }

    // 4) layer 2: MFMA root GEMM + per-encoding (edge GEMM -> weighted reduce)
    {
        dim3 gb(NBT, 3);
        k_bgemm<HH1, HH2><<<gb, 256, 0, stream>>>(h1bo, h1ba, h1baa, r2t, b2,
                                                  x2o, x2a, x2aa);
        const unsigned short* Xs[3] = {h1bo, h1ba, h1baa};
        float* Os[3] = {x2o, x2a, x2aa};
        for (int enc = 0; enc < 3; enc++) {
            const unsigned int* perm = enc == 2 ? perm1 : perm0;
            const int* offB = enc == 2 ? offB1 : offB0;
            const int* tilB = enc == 2 ? tilB1 : tilB0;
            const int* tilT = enc == 2 ? tilT1 : tilT0;
            const float* wD = enc == 2 ? wD1 : wD0;
            k_gemm<HH1, HH2><<<MAXT2, 256, 0, stream>>>(Xs[enc], msg, perm, offB,
                                                        tilB, tilT, w2t);
            k_reduce<HH2, false><<<NN / 4, 256, 0, stream>>>(msg, dstOff, wD,
                                                             Os[enc], nullptr);
        }
    }

    // 5) readout + discriminator + classifier
    k_mean<<<256, 256, 0, stream>>>(x2o, part);
    k_csum<<<1, 64, 0, stream>>>(part, csum);
    k_disc<<<(NN + 255) / 256, 256, 0, stream>>>(x2o, x2a, x2aa, csum, discW, discb,
                                                 ret_os, ret_osa);
    k_clsg<<<BB / CLS_BM, 256, 0, stream>>>(h1o, x2o, feat, attt, idx, cwt, clsb, log_out);
}